// Round 1
// baseline (6491.915 us; speedup 1.0000x reference)
//
#include <hip/hip_runtime.h>
#include <math.h>

namespace {

constexpr int B = 16, T = 24, N = 207, C = 64, HOR = 12;
constexpr int BT = B * T;          // 384
constexpr int BN = B * N;          // 3312
constexpr int P = B * T * N;       // 79488
constexpr int NC = N * C;          // 13248
constexpr int FF = 256;            // 4*C
constexpr int G3 = 192;            // 3*C

// ws layout (floats)
constexpr size_t H_OFF = 0;                         // P*C = 5,087,232
constexpr size_t A_OFF = 5087232;                   // bufA: 5,087,232 (seq1)
constexpr size_t Q_OFF = A_OFF + 5087232;           // q: 635,904
constexpr size_t K_OFF = Q_OFF + 635904;            // k: 635,904
constexpr size_t B_OFF = K_OFF + 635904;            // bufB: 20,348,928 (v? no - hid / xp)
constexpr size_t WS_FLOATS = B_OFF + 20348928;      // 31,795,200

__device__ __forceinline__ float wsum(float v) {
#pragma unroll
  for (int off = 32; off; off >>= 1) v += __shfl_xor(v, off);
  return v;
}
__device__ __forceinline__ float wmax(float v) {
#pragma unroll
  for (int off = 32; off; off >>= 1) v = fmaxf(v, __shfl_xor(v, off));
  return v;
}

// H[b,t,n,c] layout. One block = 4 positions, 64 lanes = channels.
__global__ __launch_bounds__(256) void k_embed(
    const float* __restrict__ x, const float* __restrict__ nodee,
    const float* __restrict__ hw, const float* __restrict__ hb,
    const float* __restrict__ dw, const float* __restrict__ db,
    const float* __restrict__ ww, const float* __restrict__ wb,
    const float* __restrict__ inw, const float* __restrict__ inb,
    float* __restrict__ H) {
  int pos = blockIdx.x * 4 + (threadIdx.x >> 6);
  int c = threadIdx.x & 63;
  int n = pos % N;
  int t = (pos / N) % T;
  const float* xv = x + (size_t)pos * 4;
  float flow = xv[0], hour = xv[1], wkend = xv[2], day = xv[3];
  const float* w = inw + c * 65;
  float acc = inb[c] + w[0] * flow;
#pragma unroll
  for (int e = 0; e < 16; e++) {
    acc += w[1 + e] * nodee[n * 16 + e];
    acc += w[17 + e] * (hour * hw[e] + hb[e]);
    acc += w[33 + e] * (day * dw[e] + db[e]);
    acc += w[49 + e] * (wkend * ww[e] + wb[e]);
  }
  int i = c >> 1;
  float dv = expf((float)(2 * i) * (-9.210340371976184f / 64.0f));
  float ang = (float)t * dv;
  acc += (c & 1) ? cosf(ang) : sinf(ang);
  H[(size_t)pos * 64 + c] = acc;
}

// one block per g=(b,t). q,k: (B,8,T,N) flat; v: (B,64,T,N) flat.
__global__ __launch_bounds__(256) void k_spatial_qkv(
    const float* __restrict__ H, const float* __restrict__ qw,
    const float* __restrict__ qb, const float* __restrict__ kw,
    const float* __restrict__ kb, const float* __restrict__ vw,
    const float* __restrict__ vb, float* __restrict__ q, float* __restrict__ k,
    float* __restrict__ v, int l) {
  __shared__ float hs[N * 65];  // padded
  int g = blockIdx.x;
  int b = g / T, t = g % T;
  const float* Hbt = H + (size_t)g * NC;
  for (int e = threadIdx.x; e < NC; e += 256) {
    int n = e >> 6, c = e & 63;
    hs[n * 65 + c] = Hbt[e];
  }
  __syncthreads();
  qw += l * 8 * 64; qb += l * 8;
  kw += l * 8 * 64; kb += l * 8;
  vw += l * 64 * 64; vb += l * 64;
  for (int e = threadIdx.x; e < 16 * N; e += 256) {
    int o = e / N, n = e % N;
    int oo = o & 7;
    const float* W = (o < 8 ? qw : kw) + oo * 64;
    float acc = (o < 8 ? qb : kb)[oo];
#pragma unroll
    for (int c = 0; c < 64; c++) acc += W[c] * hs[n * 65 + c];
    size_t oidx = ((size_t)(b * 8 + oo) * T + t) * N + n;
    if (o < 8) q[oidx] = acc; else k[oidx] = acc;
  }
  for (int e = threadIdx.x; e < 64 * N; e += 256) {
    int o = e / N, n = e % N;
    const float* W = vw + o * 64;
    float acc = vb[o];
#pragma unroll
    for (int c = 0; c < 64; c++) acc += W[c] * hs[n * 65 + c];
    v[((size_t)(b * 64 + o) * T + t) * N + n] = acc;
  }
}

// one block per g. Double softmax with adjacency mask; writes attn to d_out slab.
__global__ __launch_bounds__(256) void k_spatial_attn(
    const float* __restrict__ q, const float* __restrict__ k,
    const float* __restrict__ adj, float* __restrict__ attn_out) {
  __shared__ float qs[8 * 208], ks[8 * 208];
  int g = blockIdx.x;
  const float* qg = q + (size_t)g * 1656;
  const float* kg = k + (size_t)g * 1656;
  for (int e = threadIdx.x; e < 1656; e += 256) {
    int c2 = e / N, n = e % N;
    qs[c2 * 208 + n] = qg[e];
    ks[c2 * 208 + n] = kg[e];
  }
  __syncthreads();
  int wave = threadIdx.x >> 6, lane = threadIdx.x & 63;
  for (int n = wave; n < N; n += 4) {
    float s[4];
    float mx = -INFINITY;
#pragma unroll
    for (int j = 0; j < 4; j++) {
      int m = lane + 64 * j;
      float acc = -INFINITY;
      if (m < N) {
        acc = 0.f;
#pragma unroll
        for (int c2 = 0; c2 < 8; c2++) acc += qs[c2 * 208 + n] * ks[c2 * 208 + m];
        acc *= 0.125f;  // 1/sqrt(C)
      }
      s[j] = acc;
      mx = fmaxf(mx, acc);
    }
    mx = wmax(mx);
    float sum = 0.f;
#pragma unroll
    for (int j = 0; j < 4; j++) {
      int m = lane + 64 * j;
      float e = (m < N) ? expf(s[j] - mx) : 0.f;
      s[j] = e;
      sum += e;
    }
    sum = wsum(sum);
    float inv = 1.f / sum;
    // second softmax over masked probabilities
    float mx2 = -INFINITY;
    bool ok[4];
#pragma unroll
    for (int j = 0; j < 4; j++) {
      int m = lane + 64 * j;
      float p = s[j] * inv;
      bool valid = (m < N) && (adj[n * N + m] != 0.0f);
      ok[j] = valid;
      s[j] = p;
      if (valid) mx2 = fmaxf(mx2, p);
    }
    mx2 = wmax(mx2);
    float sum2 = 0.f;
#pragma unroll
    for (int j = 0; j < 4; j++) {
      float e = ok[j] ? expf(s[j] - mx2) : 0.f;
      s[j] = e;
      sum2 += e;
    }
    sum2 = wsum(sum2);
    float inv2 = 1.f / sum2;
    float* orow = attn_out + ((size_t)g * N + n) * N;
#pragma unroll
    for (int j = 0; j < 4; j++) {
      int m = lane + 64 * j;
      if (m < N) orow[m] = s[j] * inv2;
    }
  }
}

// sp = v2 @ attn^T, residual into H. one block per g.
__global__ __launch_bounds__(256) void k_spatial_apply(
    const float* __restrict__ v, const float* __restrict__ attn,
    float* __restrict__ H) {
  __shared__ float vs[64 * 207];
  int g = blockIdx.x;
  const float* vg = v + (size_t)g * NC;
  for (int e = threadIdx.x; e < NC; e += 256) vs[e] = vg[e];  // vs[c*207+n]
  __syncthreads();
  int wave = threadIdx.x >> 6, lane = threadIdx.x & 63;
  const float* ag = attn + (size_t)g * N * N;
  float* Hg = H + (size_t)g * NC;
  for (int m = wave; m < N; m += 4) {
    const float* arow = ag + (size_t)m * N;
    float acc = 0.f;
#pragma unroll 4
    for (int n = 0; n < N; n++) acc += vs[lane * 207 + n] * arow[n];
    Hg[(size_t)m * 64 + lane] += acc;
  }
}

// LayerNorm over c, in place. wave per position.
__global__ __launch_bounds__(256) void k_ln1(float* __restrict__ H,
                                             const float* __restrict__ w,
                                             const float* __restrict__ b, int l) {
  int pos = blockIdx.x * 4 + (threadIdx.x >> 6);
  int c = threadIdx.x & 63;
  float xv = H[(size_t)pos * 64 + c];
  float mean = wsum(xv) * (1.f / 64.f);
  float d = xv - mean;
  float var = wsum(d * d) * (1.f / 64.f);
  H[(size_t)pos * 64 + c] = d / sqrtf(var + 1e-5f) * w[l * 64 + c] + b[l * 64 + c];
}

// temporal MHA fused per (b,n); residual into H.
__global__ __launch_bounds__(256) void k_temporal(
    float* __restrict__ H, const float* __restrict__ qw,
    const float* __restrict__ qb, const float* __restrict__ kw,
    const float* __restrict__ kb, const float* __restrict__ vw,
    const float* __restrict__ vb, const float* __restrict__ ow,
    const float* __restrict__ ob, int l) {
  __shared__ float xs[24 * 66], qs[24 * 66], ks[24 * 66], vs[24 * 66];
  __shared__ float ss[96 * 25];
  int bn = blockIdx.x;
  int b = bn / N, n = bn % N;
  size_t base = ((size_t)b * T * N + n) * 64;
  for (int e = threadIdx.x; e < 24 * 64; e += 256) {
    int t = e >> 6, c = e & 63;
    xs[t * 66 + c] = H[base + (size_t)t * NC + c];
  }
  __syncthreads();
  qw += l * 4096; kw += l * 4096; vw += l * 4096; ow += l * 4096;
  qb += l * 64; kb += l * 64; vb += l * 64; ob += l * 64;
  for (int e = threadIdx.x; e < 3 * 1536; e += 256) {
    int which = e / 1536;
    int r = e % 1536;
    int t = r >> 6, o = r & 63;
    const float* W = (which == 0 ? qw : which == 1 ? kw : vw) + o * 64;
    float acc = (which == 0 ? qb : which == 1 ? kb : vb)[o];
#pragma unroll
    for (int c = 0; c < 64; c++) acc += xs[t * 66 + c] * W[c];
    float* dst = which == 0 ? qs : which == 1 ? ks : vs;
    dst[t * 66 + o] = acc;
  }
  __syncthreads();
  for (int e = threadIdx.x; e < 2304; e += 256) {
    int u = e % 24;
    int t = (e / 24) % 24;
    int h4 = e / 576;
    float acc = 0.f;
#pragma unroll
    for (int d = 0; d < 16; d++) acc += qs[t * 66 + h4 * 16 + d] * ks[u * 66 + h4 * 16 + d];
    ss[(h4 * 24 + t) * 25 + u] = acc * 0.25f;  // 1/sqrt(HD)
  }
  __syncthreads();
  if (threadIdx.x < 96) {
    float* row = ss + threadIdx.x * 25;
    float mx = -INFINITY;
#pragma unroll
    for (int u = 0; u < 24; u++) mx = fmaxf(mx, row[u]);
    float sum = 0.f;
#pragma unroll
    for (int u = 0; u < 24; u++) {
      float e2 = expf(row[u] - mx);
      row[u] = e2;
      sum += e2;
    }
    float inv = 1.f / sum;
#pragma unroll
    for (int u = 0; u < 24; u++) row[u] *= inv;
  }
  __syncthreads();
  // ta -> reuse qs
  for (int e = threadIdx.x; e < 1536; e += 256) {
    int t = e >> 6, c = e & 63;
    int h4 = c >> 4;
    float acc = 0.f;
#pragma unroll
    for (int u = 0; u < 24; u++) acc += ss[(h4 * 24 + t) * 25 + u] * vs[u * 66 + c];
    __syncthreads();  // all reads of qs (as q) done before overwrite: ensured below
    qs[t * 66 + c] = acc;
  }
  __syncthreads();
  for (int e = threadIdx.x; e < 1536; e += 256) {
    int t = e >> 6, c = e & 63;
    float acc = ob[c];
#pragma unroll
    for (int cp = 0; cp < 64; cp++) acc += qs[t * 66 + cp] * ow[c * 64 + cp];
    H[base + (size_t)t * NC + c] += acc;
  }
}

// LN2 + FFN first GEMM (relu) -> hid. one block per (b,n).
__global__ __launch_bounds__(256) void k_ffn1(
    const float* __restrict__ H, const float* __restrict__ lnw,
    const float* __restrict__ lnb, const float* __restrict__ w1,
    const float* __restrict__ b1, float* __restrict__ hid, int l) {
  __shared__ float xs[24 * 66];
  __shared__ float w1s[256 * 65];
  int bn = blockIdx.x;
  int b = bn / N, n = bn % N;
  size_t base = ((size_t)b * T * N + n) * 64;
  int wave = threadIdx.x >> 6, lane = threadIdx.x & 63;
  for (int t = wave; t < 24; t += 4) {
    float xv = H[base + (size_t)t * NC + lane];
    float mean = wsum(xv) * (1.f / 64.f);
    float d = xv - mean;
    float var = wsum(d * d) * (1.f / 64.f);
    xs[t * 66 + lane] = d / sqrtf(var + 1e-5f) * lnw[l * 64 + lane] + lnb[l * 64 + lane];
  }
  for (int e = threadIdx.x; e < 16384; e += 256) {
    int j = e >> 6, c = e & 63;
    w1s[j * 65 + c] = w1[l * 16384 + e];
  }
  __syncthreads();
  int j = threadIdx.x;
  float bb = b1[l * 256 + j];
  for (int t = 0; t < 24; t++) {
    float acc = bb;
#pragma unroll
    for (int c = 0; c < 64; c++) acc += xs[t * 66 + c] * w1s[j * 65 + c];
    hid[((size_t)bn * 24 + t) * 256 + j] = fmaxf(acc, 0.f);
  }
}

// FFN second GEMM + (recomputed) LN2 residual; writes H = hl + ffn.
__global__ __launch_bounds__(256) void k_ffn2(
    float* __restrict__ H, const float* __restrict__ hid,
    const float* __restrict__ lnw, const float* __restrict__ lnb,
    const float* __restrict__ w2, const float* __restrict__ b2, int l) {
  __shared__ float w2s[64 * 257];
  int bn = blockIdx.x;
  int b = bn / N, n = bn % N;
  for (int e = threadIdx.x; e < 16384; e += 256) {
    int c = e >> 8, j = e & 255;
    w2s[c * 257 + j] = w2[l * 16384 + e];
  }
  __syncthreads();
  size_t base = ((size_t)b * T * N + n) * 64;
#pragma unroll 1
  for (int i = 0; i < 6; i++) {
    int e = threadIdx.x + 256 * i;
    int t = e >> 6, c = e & 63;
    float xv = H[base + (size_t)t * NC + c];
    float mean = wsum(xv) * (1.f / 64.f);
    float d = xv - mean;
    float var = wsum(d * d) * (1.f / 64.f);
    float hl = d / sqrtf(var + 1e-5f) * lnw[l * 64 + c] + lnb[l * 64 + c];
    const float* hrow = hid + ((size_t)bn * 24 + t) * 256;
    float acc = b2[l * 64 + c];
#pragma unroll 8
    for (int j = 0; j < 256; j++) acc += hrow[j] * w2s[c * 257 + j];
    H[base + (size_t)t * NC + c] = hl + acc;
  }
}

// GRU input projection: xp[t,bn,g] = bih + X . wih. 16 pairs per block.
__global__ __launch_bounds__(256) void k_gru_xp(
    const float* __restrict__ X, const float* __restrict__ wih,
    const float* __restrict__ bih, float* __restrict__ xp, int l) {
  __shared__ float ws_[192 * 65];
  __shared__ float xv[16 * 64];
  int p0 = blockIdx.x * 16;
  for (int e = threadIdx.x; e < 192 * 64; e += 256) {
    int gI = e >> 6, c = e & 63;
    ws_[gI * 65 + c] = wih[l * 12288 + e];
  }
  for (int e = threadIdx.x; e < 16 * 64; e += 256) {
    int s = e >> 6, c = e & 63;
    int p = p0 + s;
    int t = p / BN, bn = p % BN;
    float val;
    if (l == 0) {
      int b = bn / N, n = bn % N;
      val = X[(((size_t)b * T + t) * N + n) * 64 + c];
    } else {
      val = X[(size_t)p * 64 + c];  // seq1[t,bn,c]
    }
    xv[e] = val;
  }
  __syncthreads();
  for (int e = threadIdx.x; e < 16 * 192; e += 256) {
    int s = e / 192, gI = e % 192;
    float acc = bih[l * 192 + gI];
#pragma unroll
    for (int c = 0; c < 64; c++) acc += xv[s * 64 + c] * ws_[gI * 65 + c];
    xp[((size_t)(p0 + s)) * 192 + gI] = acc;
  }
}

// GRU recurrence: 16 samples per block, sequential over T.
__global__ __launch_bounds__(256) void k_gru_scan(
    const float* __restrict__ xp, const float* __restrict__ whh,
    const float* __restrict__ bhh, float* __restrict__ seq_out, int l) {
  __shared__ float ws_[192 * 65];
  __shared__ float hprev[16 * 64];
  int bn0 = blockIdx.x * 16;
  for (int e = threadIdx.x; e < 192 * 64; e += 256) {
    int gI = e >> 6, c = e & 63;
    ws_[gI * 65 + c] = whh[l * 12288 + e];
  }
  for (int e = threadIdx.x; e < 1024; e += 256) hprev[e] = 0.f;
  __syncthreads();
  for (int t = 0; t < T; t++) {
    float hnew[4];
#pragma unroll
    for (int i = 0; i < 4; i++) {
      int idx = threadIdx.x + 256 * i;
      int s = idx >> 6, c = idx & 63;
      const float* xr = xp + ((size_t)t * BN + bn0 + s) * 192;
      float hgr = bhh[l * 192 + c];
      float hgz = bhh[l * 192 + 64 + c];
      float hgn = bhh[l * 192 + 128 + c];
      const float* hp = hprev + s * 64;
#pragma unroll
      for (int cc = 0; cc < 64; cc++) {
        float hv = hp[cc];
        hgr += hv * ws_[c * 65 + cc];
        hgz += hv * ws_[(64 + c) * 65 + cc];
        hgn += hv * ws_[(128 + c) * 65 + cc];
      }
      float r = 1.f / (1.f + expf(-(xr[c] + hgr)));
      float z = 1.f / (1.f + expf(-(xr[64 + c] + hgz)));
      float nn = tanhf(xr[128 + c] + r * hgn);
      hnew[i] = (1.f - z) * nn + z * hp[c];
    }
    __syncthreads();
#pragma unroll
    for (int i = 0; i < 4; i++) {
      int idx = threadIdx.x + 256 * i;
      int s = idx >> 6, c = idx & 63;
      hprev[s * 64 + c] = hnew[i];
      seq_out[((size_t)t * BN + bn0 + s) * 64 + c] = hnew[i];
    }
    __syncthreads();
  }
}

// prediction head: one block per bn.
__global__ __launch_bounds__(256) void k_pred(
    const float* __restrict__ seq2, const float* __restrict__ pw,
    const float* __restrict__ pb, float* __restrict__ out) {
  __shared__ float s_[1536];
  int bn = blockIdx.x;
  int b = bn / N, n = bn % N;
  for (int e = threadIdx.x; e < 1536; e += 256) {
    int t = e >> 6, c = e & 63;
    s_[c * 24 + t] = seq2[((size_t)t * BN + bn) * 64 + c];
  }
  __syncthreads();
  int wave = threadIdx.x >> 6, lane = threadIdx.x & 63;
  for (int hor = wave; hor < 12; hor += 4) {
    const float* w = pw + hor * 1536;
    float acc = 0.f;
#pragma unroll 4
    for (int kk = lane; kk < 1536; kk += 64) acc += s_[kk] * w[kk];
    acc = wsum(acc);
    if (lane == 0) out[(size_t)b * (HOR * N) + hor * N + n] = acc + pb[hor];
  }
}

}  // namespace

extern "C" void kernel_launch(void* const* d_in, const int* in_sizes, int n_in,
                              void* d_out, int out_size, void* d_ws, size_t ws_size,
                              hipStream_t stream) {
  const float* x       = (const float*)d_in[0];
  const float* adj     = (const float*)d_in[1];
  const float* nodee   = (const float*)d_in[2];
  const float* hour_w  = (const float*)d_in[3];
  const float* hour_b  = (const float*)d_in[4];
  const float* day_w   = (const float*)d_in[5];
  const float* day_b   = (const float*)d_in[6];
  const float* wk_w    = (const float*)d_in[7];
  const float* wk_b    = (const float*)d_in[8];
  const float* in_w    = (const float*)d_in[9];
  const float* in_b    = (const float*)d_in[10];
  const float* sa_qw   = (const float*)d_in[11];
  const float* sa_qb   = (const float*)d_in[12];
  const float* sa_kw   = (const float*)d_in[13];
  const float* sa_kb   = (const float*)d_in[14];
  const float* sa_vw   = (const float*)d_in[15];
  const float* sa_vb   = (const float*)d_in[16];
  const float* ta_qw   = (const float*)d_in[17];
  const float* ta_qb   = (const float*)d_in[18];
  const float* ta_kw   = (const float*)d_in[19];
  const float* ta_kb   = (const float*)d_in[20];
  const float* ta_vw   = (const float*)d_in[21];
  const float* ta_vb   = (const float*)d_in[22];
  const float* ta_ow   = (const float*)d_in[23];
  const float* ta_ob   = (const float*)d_in[24];
  const float* ln1_w   = (const float*)d_in[25];
  const float* ln1_b   = (const float*)d_in[26];
  const float* ln2_w   = (const float*)d_in[27];
  const float* ln2_b   = (const float*)d_in[28];
  const float* ffn_w1  = (const float*)d_in[29];
  const float* ffn_b1  = (const float*)d_in[30];
  const float* ffn_w2  = (const float*)d_in[31];
  const float* ffn_b2  = (const float*)d_in[32];
  const float* gru_wih = (const float*)d_in[33];
  const float* gru_whh = (const float*)d_in[34];
  const float* gru_bih = (const float*)d_in[35];
  const float* gru_bhh = (const float*)d_in[36];
  const float* pred_w  = (const float*)d_in[37];
  const float* pred_b  = (const float*)d_in[38];

  if (ws_size < WS_FLOATS * sizeof(float)) return;  // loud failure: output stays poisoned

  float* ws   = (float*)d_ws;
  float* H    = ws + H_OFF;
  float* bufA = ws + A_OFF;   // seq1
  float* q    = ws + Q_OFF;
  float* k    = ws + K_OFF;
  float* bufB = ws + B_OFF;   // v | ffn hid | xp

  float* out       = (float*)d_out;
  float* attn_base = out + (size_t)B * HOR * N;  // 39744

  // v lives in the front of bufB during the spatial stage (needs 5,087,232 < bufB)
  float* v = bufB;
  // ffn hidden reuses all of bufB after spatial apply is done (disjoint in time)
  float* hid = bufB;
  float* xp  = bufB;

  k_embed<<<P / 4, 256, 0, stream>>>(x, nodee, hour_w, hour_b, day_w, day_b,
                                     wk_w, wk_b, in_w, in_b, H);

  for (int l = 0; l < 3; l++) {
    float* attn_l = attn_base + (size_t)l * BT * N * N;
    k_spatial_qkv<<<BT, 256, 0, stream>>>(H, sa_qw, sa_qb, sa_kw, sa_kb, sa_vw,
                                          sa_vb, q, k, v, l);
    k_spatial_attn<<<BT, 256, 0, stream>>>(q, k, adj, attn_l);
    k_spatial_apply<<<BT, 256, 0, stream>>>(v, attn_l, H);
    k_ln1<<<P / 4, 256, 0, stream>>>(H, ln1_w, ln1_b, l);
    k_temporal<<<BN, 256, 0, stream>>>(H, ta_qw, ta_qb, ta_kw, ta_kb, ta_vw,
                                       ta_vb, ta_ow, ta_ob, l);
    k_ffn1<<<BN, 256, 0, stream>>>(H, ln2_w, ln2_b, ffn_w1, ffn_b1, hid, l);
    k_ffn2<<<BN, 256, 0, stream>>>(H, hid, ln2_w, ln2_b, ffn_w2, ffn_b2, l);
  }

  // GRU stack: xp1(H->bufB) -> scan1(bufB->bufA) -> xp2(bufA->bufB) -> scan2(bufB->H)
  k_gru_xp<<<P / 16, 256, 0, stream>>>(H, gru_wih, gru_bih, xp, 0);
  k_gru_scan<<<BN / 16, 256, 0, stream>>>(xp, gru_whh, gru_bhh, bufA, 0);
  k_gru_xp<<<P / 16, 256, 0, stream>>>(bufA, gru_wih, gru_bih, xp, 1);
  k_gru_scan<<<BN / 16, 256, 0, stream>>>(xp, gru_whh, gru_bhh, H, 1);

  k_pred<<<BN, 256, 0, stream>>>(H, pred_w, pred_b, out);
}

// Round 2
// 4709.723 us; speedup vs baseline: 1.3784x; 1.3784x over previous
//
#include <hip/hip_runtime.h>
#include <math.h>

namespace {

constexpr int B = 16, T = 24, N = 207, C = 64, HOR = 12;
constexpr int BT = B * T;          // 384
constexpr int BN = B * N;          // 3312
constexpr int P = B * T * N;       // 79488
constexpr int NC = N * C;          // 13248
constexpr int FF = 256;            // 4*C
constexpr int G3 = 192;            // 3*C

// ws layout (floats)
constexpr size_t H_OFF = 0;                         // P*C = 5,087,232
constexpr size_t A_OFF = 5087232;                   // bufA: 5,087,232 (seq1)
constexpr size_t Q_OFF = A_OFF + 5087232;           // q: 635,904
constexpr size_t K_OFF = Q_OFF + 635904;            // k: 635,904
constexpr size_t B_OFF = K_OFF + 635904;            // bufB: 20,348,928 (v / hid / xp)
constexpr size_t WS_FLOATS = B_OFF + 20348928;      // 31,795,200

__device__ __forceinline__ float wsum(float v) {
#pragma unroll
  for (int off = 32; off; off >>= 1) v += __shfl_xor(v, off);
  return v;
}
__device__ __forceinline__ float wmax(float v) {
#pragma unroll
  for (int off = 32; off; off >>= 1) v = fmaxf(v, __shfl_xor(v, off));
  return v;
}

// H[b,t,n,c] layout. One block = 4 positions, 64 lanes = channels.
__global__ __launch_bounds__(256) void k_embed(
    const float* __restrict__ x, const float* __restrict__ nodee,
    const float* __restrict__ hw, const float* __restrict__ hb,
    const float* __restrict__ dw, const float* __restrict__ db,
    const float* __restrict__ ww, const float* __restrict__ wb,
    const float* __restrict__ inw, const float* __restrict__ inb,
    float* __restrict__ H) {
  int pos = blockIdx.x * 4 + (threadIdx.x >> 6);
  int c = threadIdx.x & 63;
  int n = pos % N;
  int t = (pos / N) % T;
  const float* xv = x + (size_t)pos * 4;
  float flow = xv[0], hour = xv[1], wkend = xv[2], day = xv[3];
  const float* w = inw + c * 65;
  float acc = inb[c] + w[0] * flow;
#pragma unroll
  for (int e = 0; e < 16; e++) {
    acc += w[1 + e] * nodee[n * 16 + e];
    acc += w[17 + e] * (hour * hw[e] + hb[e]);
    acc += w[33 + e] * (day * dw[e] + db[e]);
    acc += w[49 + e] * (wkend * ww[e] + wb[e]);
  }
  int i = c >> 1;
  float dv = expf((float)(2 * i) * (-9.210340371976184f / 64.0f));
  float ang = (float)t * dv;
  acc += (c & 1) ? cosf(ang) : sinf(ang);
  H[(size_t)pos * 64 + c] = acc;
}

// one block per g=(b,t). q,k: (B,8,T,N) flat; v: (B,64,T,N) flat.
__global__ __launch_bounds__(256) void k_spatial_qkv(
    const float* __restrict__ H, const float* __restrict__ qw,
    const float* __restrict__ qb, const float* __restrict__ kw,
    const float* __restrict__ kb, const float* __restrict__ vw,
    const float* __restrict__ vb, float* __restrict__ q, float* __restrict__ k,
    float* __restrict__ v, int l) {
  __shared__ float hs[N * 65];  // padded
  int g = blockIdx.x;
  int b = g / T, t = g % T;
  const float* Hbt = H + (size_t)g * NC;
  for (int e = threadIdx.x; e < NC; e += 256) {
    int n = e >> 6, c = e & 63;
    hs[n * 65 + c] = Hbt[e];
  }
  __syncthreads();
  qw += l * 8 * 64; qb += l * 8;
  kw += l * 8 * 64; kb += l * 8;
  vw += l * 64 * 64; vb += l * 64;
  for (int e = threadIdx.x; e < 16 * N; e += 256) {
    int o = e / N, n = e % N;
    int oo = o & 7;
    const float* W = (o < 8 ? qw : kw) + oo * 64;
    float acc = (o < 8 ? qb : kb)[oo];
#pragma unroll
    for (int c = 0; c < 64; c++) acc += W[c] * hs[n * 65 + c];
    size_t oidx = ((size_t)(b * 8 + oo) * T + t) * N + n;
    if (o < 8) q[oidx] = acc; else k[oidx] = acc;
  }
  for (int e = threadIdx.x; e < 64 * N; e += 256) {
    int o = e / N, n = e % N;
    const float* W = vw + o * 64;
    float acc = vb[o];
#pragma unroll
    for (int c = 0; c < 64; c++) acc += W[c] * hs[n * 65 + c];
    v[((size_t)(b * 64 + o) * T + t) * N + n] = acc;
  }
}

// one block per g. Double softmax with adjacency mask; writes attn to d_out slab.
__global__ __launch_bounds__(256) void k_spatial_attn(
    const float* __restrict__ q, const float* __restrict__ k,
    const float* __restrict__ adj, float* __restrict__ attn_out) {
  __shared__ float qs[8 * 208], ks[8 * 208];
  int g = blockIdx.x;
  const float* qg = q + (size_t)g * 1656;
  const float* kg = k + (size_t)g * 1656;
  for (int e = threadIdx.x; e < 1656; e += 256) {
    int c2 = e / N, n = e % N;
    qs[c2 * 208 + n] = qg[e];
    ks[c2 * 208 + n] = kg[e];
  }
  __syncthreads();
  int wave = threadIdx.x >> 6, lane = threadIdx.x & 63;
  for (int n = wave; n < N; n += 4) {
    float s[4];
    float mx = -INFINITY;
#pragma unroll
    for (int j = 0; j < 4; j++) {
      int m = lane + 64 * j;
      float acc = -INFINITY;
      if (m < N) {
        acc = 0.f;
#pragma unroll
        for (int c2 = 0; c2 < 8; c2++) acc += qs[c2 * 208 + n] * ks[c2 * 208 + m];
        acc *= 0.125f;  // 1/sqrt(C)
      }
      s[j] = acc;
      mx = fmaxf(mx, acc);
    }
    mx = wmax(mx);
    float sum = 0.f;
#pragma unroll
    for (int j = 0; j < 4; j++) {
      int m = lane + 64 * j;
      float e = (m < N) ? expf(s[j] - mx) : 0.f;
      s[j] = e;
      sum += e;
    }
    sum = wsum(sum);
    float inv = 1.f / sum;
    // second softmax over masked probabilities
    float mx2 = -INFINITY;
    bool ok[4];
#pragma unroll
    for (int j = 0; j < 4; j++) {
      int m = lane + 64 * j;
      float p = s[j] * inv;
      bool valid = (m < N) && (adj[n * N + m] != 0.0f);
      ok[j] = valid;
      s[j] = p;
      if (valid) mx2 = fmaxf(mx2, p);
    }
    mx2 = wmax(mx2);
    float sum2 = 0.f;
#pragma unroll
    for (int j = 0; j < 4; j++) {
      float e = ok[j] ? expf(s[j] - mx2) : 0.f;
      s[j] = e;
      sum2 += e;
    }
    sum2 = wsum(sum2);
    float inv2 = 1.f / sum2;
    float* orow = attn_out + ((size_t)g * N + n) * N;
#pragma unroll
    for (int j = 0; j < 4; j++) {
      int m = lane + 64 * j;
      if (m < N) orow[m] = s[j] * inv2;
    }
  }
}

// sp = v2 @ attn^T, residual into H. grid (g, m-chunk). 13-row register
// blocking per wave; rows stride-4 so all 13 share the same float4 phase.
__global__ __launch_bounds__(256, 3) void k_spatial_apply(
    const float* __restrict__ v, const float* __restrict__ attn,
    float* __restrict__ H) {
  __shared__ float vs[64 * 207];
  int g = blockIdx.x;
  int ms = blockIdx.y;  // 0..3
  const float* vg = v + (size_t)g * NC;
  for (int e = threadIdx.x; e < NC; e += 256) vs[e] = vg[e];  // vs[c*207+n]
  __syncthreads();
  int wave = threadIdx.x >> 6, lane = threadIdx.x & 63;
  const float* ag = attn + (size_t)g * (N * N);
  float* Hg = H + (size_t)g * NC;
  int mbeg = ms * 52;
  int mend = min(mbeg + 52, N);
  int m_w = mbeg + wave;  // first row of this wave; rows m_w+4k, k=0..12
  // attn is 16B-aligned at its base; phase of this wave's rows:
  size_t Dg = (size_t)g * (N * N);
  int p = (int)((4 - ((Dg + (size_t)m_w * N) & 3)) & 3);
  const float* ar[13];
  int mrow[13];
#pragma unroll
  for (int r = 0; r < 13; r++) {
    int m = m_w + 4 * r;
    mrow[r] = m;
    int msafe = (m < N) ? m : m - 4;  // phase-preserving clamp
    ar[r] = ag + (size_t)msafe * N;
  }
  float acc[13];
#pragma unroll
  for (int r = 0; r < 13; r++) acc[r] = 0.f;
  const float* vrow = vs + lane * 207;
  // scalar prefix [0, p)
  for (int n = 0; n < p; n++) {
    float vv = vrow[n];
#pragma unroll
    for (int r = 0; r < 13; r++) acc[r] += vv * ar[r][n];
  }
  // aligned float4 body: [p, p+204)
  for (int n4 = 0; n4 < 51; n4++) {
    int n = p + n4 * 4;
    float v0 = vrow[n], v1 = vrow[n + 1], v2 = vrow[n + 2], v3 = vrow[n + 3];
#pragma unroll
    for (int r = 0; r < 13; r++) {
      float4 a = *(const float4*)(ar[r] + n);
      acc[r] += v0 * a.x;
      acc[r] += v1 * a.y;
      acc[r] += v2 * a.z;
      acc[r] += v3 * a.w;
    }
  }
  // scalar suffix [p+204, 207)
  for (int n = p + 204; n < 207; n++) {
    float vv = vrow[n];
#pragma unroll
    for (int r = 0; r < 13; r++) acc[r] += vv * ar[r][n];
  }
#pragma unroll
  for (int r = 0; r < 13; r++) {
    int m = mrow[r];
    if (m < mend) Hg[(size_t)m * 64 + lane] += acc[r];
  }
}

// LayerNorm over c, in place. wave per position.
__global__ __launch_bounds__(256) void k_ln1(float* __restrict__ H,
                                             const float* __restrict__ w,
                                             const float* __restrict__ b, int l) {
  int pos = blockIdx.x * 4 + (threadIdx.x >> 6);
  int c = threadIdx.x & 63;
  float xv = H[(size_t)pos * 64 + c];
  float mean = wsum(xv) * (1.f / 64.f);
  float d = xv - mean;
  float var = wsum(d * d) * (1.f / 64.f);
  H[(size_t)pos * 64 + c] = d / sqrtf(var + 1e-5f) * w[l * 64 + c] + b[l * 64 + c];
}

// temporal MHA fused per (b,n); residual into H.
__global__ __launch_bounds__(256) void k_temporal(
    float* __restrict__ H, const float* __restrict__ qw,
    const float* __restrict__ qb, const float* __restrict__ kw,
    const float* __restrict__ kb, const float* __restrict__ vw,
    const float* __restrict__ vb, const float* __restrict__ ow,
    const float* __restrict__ ob, int l) {
  __shared__ float xs[24 * 66], qs[24 * 66], ks[24 * 66], vs[24 * 66];
  __shared__ float ss[96 * 25];
  int bn = blockIdx.x;
  int b = bn / N, n = bn % N;
  size_t base = ((size_t)b * T * N + n) * 64;
  for (int e = threadIdx.x; e < 24 * 64; e += 256) {
    int t = e >> 6, c = e & 63;
    xs[t * 66 + c] = H[base + (size_t)t * NC + c];
  }
  __syncthreads();
  qw += l * 4096; kw += l * 4096; vw += l * 4096; ow += l * 4096;
  qb += l * 64; kb += l * 64; vb += l * 64; ob += l * 64;
  for (int e = threadIdx.x; e < 3 * 1536; e += 256) {
    int which = e / 1536;
    int r = e % 1536;
    int t = r >> 6, o = r & 63;
    const float* W = (which == 0 ? qw : which == 1 ? kw : vw) + o * 64;
    float acc = (which == 0 ? qb : which == 1 ? kb : vb)[o];
#pragma unroll
    for (int c = 0; c < 64; c++) acc += xs[t * 66 + c] * W[c];
    float* dst = which == 0 ? qs : which == 1 ? ks : vs;
    dst[t * 66 + o] = acc;
  }
  __syncthreads();
  for (int e = threadIdx.x; e < 2304; e += 256) {
    int u = e % 24;
    int t = (e / 24) % 24;
    int h4 = e / 576;
    float acc = 0.f;
#pragma unroll
    for (int d = 0; d < 16; d++) acc += qs[t * 66 + h4 * 16 + d] * ks[u * 66 + h4 * 16 + d];
    ss[(h4 * 24 + t) * 25 + u] = acc * 0.25f;  // 1/sqrt(HD)
  }
  __syncthreads();
  if (threadIdx.x < 96) {
    float* row = ss + threadIdx.x * 25;
    float mx = -INFINITY;
#pragma unroll
    for (int u = 0; u < 24; u++) mx = fmaxf(mx, row[u]);
    float sum = 0.f;
#pragma unroll
    for (int u = 0; u < 24; u++) {
      float e2 = expf(row[u] - mx);
      row[u] = e2;
      sum += e2;
    }
    float inv = 1.f / sum;
#pragma unroll
    for (int u = 0; u < 24; u++) row[u] *= inv;
  }
  __syncthreads();
  // ta -> reuse qs
  for (int e = threadIdx.x; e < 1536; e += 256) {
    int t = e >> 6, c = e & 63;
    int h4 = c >> 4;
    float acc = 0.f;
#pragma unroll
    for (int u = 0; u < 24; u++) acc += ss[(h4 * 24 + t) * 25 + u] * vs[u * 66 + c];
    __syncthreads();
    qs[t * 66 + c] = acc;
  }
  __syncthreads();
  for (int e = threadIdx.x; e < 1536; e += 256) {
    int t = e >> 6, c = e & 63;
    float acc = ob[c];
#pragma unroll
    for (int cp = 0; cp < 64; cp++) acc += qs[t * 66 + cp] * ow[c * 64 + cp];
    H[base + (size_t)t * NC + c] += acc;
  }
}

// LN2 + FFN first GEMM (relu) -> hid. one block per (b,n).
__global__ __launch_bounds__(256) void k_ffn1(
    const float* __restrict__ H, const float* __restrict__ lnw,
    const float* __restrict__ lnb, const float* __restrict__ w1,
    const float* __restrict__ b1, float* __restrict__ hid, int l) {
  __shared__ float xs[24 * 66];
  __shared__ float w1s[256 * 65];
  int bn = blockIdx.x;
  int b = bn / N, n = bn % N;
  size_t base = ((size_t)b * T * N + n) * 64;
  int wave = threadIdx.x >> 6, lane = threadIdx.x & 63;
  for (int t = wave; t < 24; t += 4) {
    float xv = H[base + (size_t)t * NC + lane];
    float mean = wsum(xv) * (1.f / 64.f);
    float d = xv - mean;
    float var = wsum(d * d) * (1.f / 64.f);
    xs[t * 66 + lane] = d / sqrtf(var + 1e-5f) * lnw[l * 64 + lane] + lnb[l * 64 + lane];
  }
  for (int e = threadIdx.x; e < 16384; e += 256) {
    int j = e >> 6, c = e & 63;
    w1s[j * 65 + c] = w1[l * 16384 + e];
  }
  __syncthreads();
  int j = threadIdx.x;
  float bb = b1[l * 256 + j];
  for (int t = 0; t < 24; t++) {
    float acc = bb;
#pragma unroll
    for (int c = 0; c < 64; c++) acc += xs[t * 66 + c] * w1s[j * 65 + c];
    hid[((size_t)bn * 24 + t) * 256 + j] = fmaxf(acc, 0.f);
  }
}

// FFN second GEMM + (recomputed) LN2 residual; writes H = hl + ffn.
__global__ __launch_bounds__(256) void k_ffn2(
    float* __restrict__ H, const float* __restrict__ hid,
    const float* __restrict__ lnw, const float* __restrict__ lnb,
    const float* __restrict__ w2, const float* __restrict__ b2, int l) {
  __shared__ float w2s[64 * 257];
  int bn = blockIdx.x;
  int b = bn / N, n = bn % N;
  for (int e = threadIdx.x; e < 16384; e += 256) {
    int c = e >> 8, j = e & 255;
    w2s[c * 257 + j] = w2[l * 16384 + e];
  }
  __syncthreads();
  size_t base = ((size_t)b * T * N + n) * 64;
#pragma unroll 1
  for (int i = 0; i < 6; i++) {
    int e = threadIdx.x + 256 * i;
    int t = e >> 6, c = e & 63;
    float xv = H[base + (size_t)t * NC + c];
    float mean = wsum(xv) * (1.f / 64.f);
    float d = xv - mean;
    float var = wsum(d * d) * (1.f / 64.f);
    float hl = d / sqrtf(var + 1e-5f) * lnw[l * 64 + c] + lnb[l * 64 + c];
    const float* hrow = hid + ((size_t)bn * 24 + t) * 256;
    float acc = b2[l * 64 + c];
#pragma unroll 8
    for (int j = 0; j < 256; j++) acc += hrow[j] * w2s[c * 257 + j];
    H[base + (size_t)t * NC + c] = hl + acc;
  }
}

// GRU input projection: xp[t,bn,g] = bih + X . wih. 16 pairs per block.
__global__ __launch_bounds__(256) void k_gru_xp(
    const float* __restrict__ X, const float* __restrict__ wih,
    const float* __restrict__ bih, float* __restrict__ xp, int l) {
  __shared__ float ws_[192 * 65];
  __shared__ float xv[16 * 64];
  int p0 = blockIdx.x * 16;
  for (int e = threadIdx.x; e < 192 * 64; e += 256) {
    int gI = e >> 6, c = e & 63;
    ws_[gI * 65 + c] = wih[l * 12288 + e];
  }
  for (int e = threadIdx.x; e < 16 * 64; e += 256) {
    int s = e >> 6, c = e & 63;
    int p = p0 + s;
    int t = p / BN, bn = p % BN;
    float val;
    if (l == 0) {
      int b = bn / N, n = bn % N;
      val = X[(((size_t)b * T + t) * N + n) * 64 + c];
    } else {
      val = X[(size_t)p * 64 + c];  // seq1[t,bn,c]
    }
    xv[e] = val;
  }
  __syncthreads();
  for (int e = threadIdx.x; e < 16 * 192; e += 256) {
    int s = e / 192, gI = e % 192;
    float acc = bih[l * 192 + gI];
#pragma unroll
    for (int c = 0; c < 64; c++) acc += xv[s * 64 + c] * ws_[gI * 65 + c];
    xp[((size_t)(p0 + s)) * 192 + gI] = acc;
  }
}

// GRU recurrence: 16 samples per block, sequential over T.
__global__ __launch_bounds__(256) void k_gru_scan(
    const float* __restrict__ xp, const float* __restrict__ whh,
    const float* __restrict__ bhh, float* __restrict__ seq_out, int l) {
  __shared__ float ws_[192 * 65];
  __shared__ float hprev[16 * 64];
  int bn0 = blockIdx.x * 16;
  for (int e = threadIdx.x; e < 192 * 64; e += 256) {
    int gI = e >> 6, c = e & 63;
    ws_[gI * 65 + c] = whh[l * 12288 + e];
  }
  for (int e = threadIdx.x; e < 1024; e += 256) hprev[e] = 0.f;
  __syncthreads();
  for (int t = 0; t < T; t++) {
    float hnew[4];
#pragma unroll
    for (int i = 0; i < 4; i++) {
      int idx = threadIdx.x + 256 * i;
      int s = idx >> 6, c = idx & 63;
      const float* xr = xp + ((size_t)t * BN + bn0 + s) * 192;
      float hgr = bhh[l * 192 + c];
      float hgz = bhh[l * 192 + 64 + c];
      float hgn = bhh[l * 192 + 128 + c];
      const float* hp = hprev + s * 64;
#pragma unroll
      for (int cc = 0; cc < 64; cc++) {
        float hv = hp[cc];
        hgr += hv * ws_[c * 65 + cc];
        hgz += hv * ws_[(64 + c) * 65 + cc];
        hgn += hv * ws_[(128 + c) * 65 + cc];
      }
      float r = 1.f / (1.f + expf(-(xr[c] + hgr)));
      float z = 1.f / (1.f + expf(-(xr[64 + c] + hgz)));
      float nn = tanhf(xr[128 + c] + r * hgn);
      hnew[i] = (1.f - z) * nn + z * hp[c];
    }
    __syncthreads();
#pragma unroll
    for (int i = 0; i < 4; i++) {
      int idx = threadIdx.x + 256 * i;
      int s = idx >> 6, c = idx & 63;
      hprev[s * 64 + c] = hnew[i];
      seq_out[((size_t)t * BN + bn0 + s) * 64 + c] = hnew[i];
    }
    __syncthreads();
  }
}

// prediction head: one block per bn.
__global__ __launch_bounds__(256) void k_pred(
    const float* __restrict__ seq2, const float* __restrict__ pw,
    const float* __restrict__ pb, float* __restrict__ out) {
  __shared__ float s_[1536];
  int bn = blockIdx.x;
  int b = bn / N, n = bn % N;
  for (int e = threadIdx.x; e < 1536; e += 256) {
    int t = e >> 6, c = e & 63;
    s_[c * 24 + t] = seq2[((size_t)t * BN + bn) * 64 + c];
  }
  __syncthreads();
  int wave = threadIdx.x >> 6, lane = threadIdx.x & 63;
  for (int hor = wave; hor < 12; hor += 4) {
    const float* w = pw + hor * 1536;
    float acc = 0.f;
#pragma unroll 4
    for (int kk = lane; kk < 1536; kk += 64) acc += s_[kk] * w[kk];
    acc = wsum(acc);
    if (lane == 0) out[(size_t)b * (HOR * N) + hor * N + n] = acc + pb[hor];
  }
}

}  // namespace

extern "C" void kernel_launch(void* const* d_in, const int* in_sizes, int n_in,
                              void* d_out, int out_size, void* d_ws, size_t ws_size,
                              hipStream_t stream) {
  const float* x       = (const float*)d_in[0];
  const float* adj     = (const float*)d_in[1];
  const float* nodee   = (const float*)d_in[2];
  const float* hour_w  = (const float*)d_in[3];
  const float* hour_b  = (const float*)d_in[4];
  const float* day_w   = (const float*)d_in[5];
  const float* day_b   = (const float*)d_in[6];
  const float* wk_w    = (const float*)d_in[7];
  const float* wk_b    = (const float*)d_in[8];
  const float* in_w    = (const float*)d_in[9];
  const float* in_b    = (const float*)d_in[10];
  const float* sa_qw   = (const float*)d_in[11];
  const float* sa_qb   = (const float*)d_in[12];
  const float* sa_kw   = (const float*)d_in[13];
  const float* sa_kb   = (const float*)d_in[14];
  const float* sa_vw   = (const float*)d_in[15];
  const float* sa_vb   = (const float*)d_in[16];
  const float* ta_qw   = (const float*)d_in[17];
  const float* ta_qb   = (const float*)d_in[18];
  const float* ta_kw   = (const float*)d_in[19];
  const float* ta_kb   = (const float*)d_in[20];
  const float* ta_vw   = (const float*)d_in[21];
  const float* ta_vb   = (const float*)d_in[22];
  const float* ta_ow   = (const float*)d_in[23];
  const float* ta_ob   = (const float*)d_in[24];
  const float* ln1_w   = (const float*)d_in[25];
  const float* ln1_b   = (const float*)d_in[26];
  const float* ln2_w   = (const float*)d_in[27];
  const float* ln2_b   = (const float*)d_in[28];
  const float* ffn_w1  = (const float*)d_in[29];
  const float* ffn_b1  = (const float*)d_in[30];
  const float* ffn_w2  = (const float*)d_in[31];
  const float* ffn_b2  = (const float*)d_in[32];
  const float* gru_wih = (const float*)d_in[33];
  const float* gru_whh = (const float*)d_in[34];
  const float* gru_bih = (const float*)d_in[35];
  const float* gru_bhh = (const float*)d_in[36];
  const float* pred_w  = (const float*)d_in[37];
  const float* pred_b  = (const float*)d_in[38];

  if (ws_size < WS_FLOATS * sizeof(float)) return;  // loud failure: output stays poisoned

  float* ws   = (float*)d_ws;
  float* H    = ws + H_OFF;
  float* bufA = ws + A_OFF;   // seq1
  float* q    = ws + Q_OFF;
  float* k    = ws + K_OFF;
  float* bufB = ws + B_OFF;   // v | ffn hid | xp

  float* out       = (float*)d_out;
  float* attn_base = out + (size_t)B * HOR * N;  // 39744 (16B aligned)

  float* v   = bufB;
  float* hid = bufB;
  float* xp  = bufB;

  k_embed<<<P / 4, 256, 0, stream>>>(x, nodee, hour_w, hour_b, day_w, day_b,
                                     wk_w, wk_b, in_w, in_b, H);

  for (int l = 0; l < 3; l++) {
    float* attn_l = attn_base + (size_t)l * BT * N * N;
    k_spatial_qkv<<<BT, 256, 0, stream>>>(H, sa_qw, sa_qb, sa_kw, sa_kb, sa_vw,
                                          sa_vb, q, k, v, l);
    k_spatial_attn<<<BT, 256, 0, stream>>>(q, k, adj, attn_l);
    k_spatial_apply<<<dim3(BT, 4), 256, 0, stream>>>(v, attn_l, H);
    k_ln1<<<P / 4, 256, 0, stream>>>(H, ln1_w, ln1_b, l);
    k_temporal<<<BN, 256, 0, stream>>>(H, ta_qw, ta_qb, ta_kw, ta_kb, ta_vw,
                                       ta_vb, ta_ow, ta_ob, l);
    k_ffn1<<<BN, 256, 0, stream>>>(H, ln2_w, ln2_b, ffn_w1, ffn_b1, hid, l);
    k_ffn2<<<BN, 256, 0, stream>>>(H, hid, ln2_w, ln2_b, ffn_w2, ffn_b2, l);
  }

  k_gru_xp<<<P / 16, 256, 0, stream>>>(H, gru_wih, gru_bih, xp, 0);
  k_gru_scan<<<BN / 16, 256, 0, stream>>>(xp, gru_whh, gru_bhh, bufA, 0);
  k_gru_xp<<<P / 16, 256, 0, stream>>>(bufA, gru_wih, gru_bih, xp, 1);
  k_gru_scan<<<BN / 16, 256, 0, stream>>>(xp, gru_whh, gru_bhh, H, 1);

  k_pred<<<BN, 256, 0, stream>>>(H, pred_w, pred_b, out);
}

// Round 3
// 3187.664 us; speedup vs baseline: 2.0366x; 1.4775x over previous
//
#include <hip/hip_runtime.h>
#include <math.h>

namespace {

constexpr int B = 16, T = 24, N = 207, C = 64, HOR = 12;
constexpr int BT = B * T;          // 384
constexpr int BN = B * N;          // 3312
constexpr int P = B * T * N;       // 79488
constexpr int NC = N * C;          // 13248

// ws layout (floats)
constexpr size_t H_OFF = 0;                         // P*C = 5,087,232
constexpr size_t A_OFF = 5087232;                   // bufA: 5,087,232 (seq1)
constexpr size_t Q_OFF = A_OFF + 5087232;           // q: 635,904 (also reused as w1t)
constexpr size_t K_OFF = Q_OFF + 635904;            // k: 635,904
constexpr size_t B_OFF = K_OFF + 635904;            // bufB: 20,348,928 (v / hid / xp)
constexpr size_t WS_FLOATS = B_OFF + 20348928;      // 31,795,200

__device__ __forceinline__ float wsum(float v) {
#pragma unroll
  for (int off = 32; off; off >>= 1) v += __shfl_xor(v, off);
  return v;
}
__device__ __forceinline__ float wmax(float v) {
#pragma unroll
  for (int off = 32; off; off >>= 1) v = fmaxf(v, __shfl_xor(v, off));
  return v;
}

// H[b,t,n,c] layout. One block = 4 positions, 64 lanes = channels.
__global__ __launch_bounds__(256) void k_embed(
    const float* __restrict__ x, const float* __restrict__ nodee,
    const float* __restrict__ hw, const float* __restrict__ hb,
    const float* __restrict__ dw, const float* __restrict__ db,
    const float* __restrict__ ww, const float* __restrict__ wb,
    const float* __restrict__ inw, const float* __restrict__ inb,
    float* __restrict__ H) {
  int pos = blockIdx.x * 4 + (threadIdx.x >> 6);
  int c = threadIdx.x & 63;
  int n = pos % N;
  int t = (pos / N) % T;
  const float* xv = x + (size_t)pos * 4;
  float flow = xv[0], hour = xv[1], wkend = xv[2], day = xv[3];
  const float* w = inw + c * 65;
  float acc = inb[c] + w[0] * flow;
#pragma unroll
  for (int e = 0; e < 16; e++) {
    acc += w[1 + e] * nodee[n * 16 + e];
    acc += w[17 + e] * (hour * hw[e] + hb[e]);
    acc += w[33 + e] * (day * dw[e] + db[e]);
    acc += w[49 + e] * (wkend * ww[e] + wb[e]);
  }
  int i = c >> 1;
  float dv = expf((float)(2 * i) * (-9.210340371976184f / 64.0f));
  float ang = (float)t * dv;
  acc += (c & 1) ? cosf(ang) : sinf(ang);
  H[(size_t)pos * 64 + c] = acc;
}

// one block per g=(b,t). q,k: (B,8,T,N) flat; v: (B,64,T,N) flat.
__global__ __launch_bounds__(256) void k_spatial_qkv(
    const float* __restrict__ H, const float* __restrict__ qw,
    const float* __restrict__ qb, const float* __restrict__ kw,
    const float* __restrict__ kb, const float* __restrict__ vw,
    const float* __restrict__ vb, float* __restrict__ q, float* __restrict__ k,
    float* __restrict__ v, int l) {
  __shared__ float hs[N * 65];  // padded
  int g = blockIdx.x;
  int b = g / T, t = g % T;
  const float* Hbt = H + (size_t)g * NC;
  for (int e = threadIdx.x; e < NC; e += 256) {
    int n = e >> 6, c = e & 63;
    hs[n * 65 + c] = Hbt[e];
  }
  __syncthreads();
  qw += l * 8 * 64; qb += l * 8;
  kw += l * 8 * 64; kb += l * 8;
  vw += l * 64 * 64; vb += l * 64;
  for (int e = threadIdx.x; e < 16 * N; e += 256) {
    int o = e / N, n = e % N;
    int oo = o & 7;
    const float* W = (o < 8 ? qw : kw) + oo * 64;
    float acc = (o < 8 ? qb : kb)[oo];
#pragma unroll
    for (int c = 0; c < 64; c++) acc += W[c] * hs[n * 65 + c];
    size_t oidx = ((size_t)(b * 8 + oo) * T + t) * N + n;
    if (o < 8) q[oidx] = acc; else k[oidx] = acc;
  }
  for (int e = threadIdx.x; e < 64 * N; e += 256) {
    int o = e / N, n = e % N;
    const float* W = vw + o * 64;
    float acc = vb[o];
#pragma unroll
    for (int c = 0; c < 64; c++) acc += W[c] * hs[n * 65 + c];
    v[((size_t)(b * 64 + o) * T + t) * N + n] = acc;
  }
}

// one block per g. Double softmax with adjacency mask; writes attn to d_out slab.
__global__ __launch_bounds__(256) void k_spatial_attn(
    const float* __restrict__ q, const float* __restrict__ k,
    const float* __restrict__ adj, float* __restrict__ attn_out) {
  __shared__ float qs[8 * 208], ks[8 * 208];
  int g = blockIdx.x;
  const float* qg = q + (size_t)g * 1656;
  const float* kg = k + (size_t)g * 1656;
  for (int e = threadIdx.x; e < 1656; e += 256) {
    int c2 = e / N, n = e % N;
    qs[c2 * 208 + n] = qg[e];
    ks[c2 * 208 + n] = kg[e];
  }
  __syncthreads();
  int wave = threadIdx.x >> 6, lane = threadIdx.x & 63;
  for (int n = wave; n < N; n += 4) {
    float s[4];
    float mx = -INFINITY;
#pragma unroll
    for (int j = 0; j < 4; j++) {
      int m = lane + 64 * j;
      float acc = -INFINITY;
      if (m < N) {
        acc = 0.f;
#pragma unroll
        for (int c2 = 0; c2 < 8; c2++) acc += qs[c2 * 208 + n] * ks[c2 * 208 + m];
        acc *= 0.125f;  // 1/sqrt(C)
      }
      s[j] = acc;
      mx = fmaxf(mx, acc);
    }
    mx = wmax(mx);
    float sum = 0.f;
#pragma unroll
    for (int j = 0; j < 4; j++) {
      int m = lane + 64 * j;
      float e = (m < N) ? expf(s[j] - mx) : 0.f;
      s[j] = e;
      sum += e;
    }
    sum = wsum(sum);
    float inv = 1.f / sum;
    // second softmax over masked probabilities
    float mx2 = -INFINITY;
    bool ok[4];
#pragma unroll
    for (int j = 0; j < 4; j++) {
      int m = lane + 64 * j;
      float p = s[j] * inv;
      bool valid = (m < N) && (adj[n * N + m] != 0.0f);
      ok[j] = valid;
      s[j] = p;
      if (valid) mx2 = fmaxf(mx2, p);
    }
    mx2 = wmax(mx2);
    float sum2 = 0.f;
#pragma unroll
    for (int j = 0; j < 4; j++) {
      float e = ok[j] ? expf(s[j] - mx2) : 0.f;
      s[j] = e;
      sum2 += e;
    }
    sum2 = wsum(sum2);
    float inv2 = 1.f / sum2;
    float* orow = attn_out + ((size_t)g * N + n) * N;
#pragma unroll
    for (int j = 0; j < 4; j++) {
      int m = lane + 64 * j;
      if (m < N) orow[m] = s[j] * inv2;
    }
  }
}

// sp = v2 @ attn^T, residual into H. grid (g, m-chunk). 13-row register
// blocking per wave; rows stride-4 so all 13 share the same float4 phase.
__global__ __launch_bounds__(256, 3) void k_spatial_apply(
    const float* __restrict__ v, const float* __restrict__ attn,
    float* __restrict__ H) {
  __shared__ float vs[64 * 207];
  int g = blockIdx.x;
  int ms = blockIdx.y;  // 0..3
  const float* vg = v + (size_t)g * NC;
  for (int e = threadIdx.x; e < NC; e += 256) vs[e] = vg[e];  // vs[c*207+n]
  __syncthreads();
  int wave = threadIdx.x >> 6, lane = threadIdx.x & 63;
  const float* ag = attn + (size_t)g * (N * N);
  float* Hg = H + (size_t)g * NC;
  int mbeg = ms * 52;
  int mend = min(mbeg + 52, N);
  int m_w = mbeg + wave;  // first row of this wave; rows m_w+4k, k=0..12
  size_t Dg = (size_t)g * (N * N);
  int p = (int)((4 - ((Dg + (size_t)m_w * N) & 3)) & 3);
  const float* ar[13];
  int mrow[13];
#pragma unroll
  for (int r = 0; r < 13; r++) {
    int m = m_w + 4 * r;
    mrow[r] = m;
    int msafe = (m < N) ? m : m - 4;  // phase-preserving clamp
    ar[r] = ag + (size_t)msafe * N;
  }
  float acc[13];
#pragma unroll
  for (int r = 0; r < 13; r++) acc[r] = 0.f;
  const float* vrow = vs + lane * 207;
  for (int n = 0; n < p; n++) {
    float vv = vrow[n];
#pragma unroll
    for (int r = 0; r < 13; r++) acc[r] += vv * ar[r][n];
  }
  for (int n4 = 0; n4 < 51; n4++) {
    int n = p + n4 * 4;
    float v0 = vrow[n], v1 = vrow[n + 1], v2 = vrow[n + 2], v3 = vrow[n + 3];
#pragma unroll
    for (int r = 0; r < 13; r++) {
      float4 a = *(const float4*)(ar[r] + n);
      acc[r] += v0 * a.x;
      acc[r] += v1 * a.y;
      acc[r] += v2 * a.z;
      acc[r] += v3 * a.w;
    }
  }
  for (int n = p + 204; n < 207; n++) {
    float vv = vrow[n];
#pragma unroll
    for (int r = 0; r < 13; r++) acc[r] += vv * ar[r][n];
  }
#pragma unroll
  for (int r = 0; r < 13; r++) {
    int m = mrow[r];
    if (m < mend) Hg[(size_t)m * 64 + lane] += acc[r];
  }
}

// LayerNorm over c, in place. wave per position.
__global__ __launch_bounds__(256) void k_ln1(float* __restrict__ H,
                                             const float* __restrict__ w,
                                             const float* __restrict__ b, int l) {
  int pos = blockIdx.x * 4 + (threadIdx.x >> 6);
  int c = threadIdx.x & 63;
  float xv = H[(size_t)pos * 64 + c];
  float mean = wsum(xv) * (1.f / 64.f);
  float d = xv - mean;
  float var = wsum(d * d) * (1.f / 64.f);
  H[(size_t)pos * 64 + c] = d / sqrtf(var + 1e-5f) * w[l * 64 + c] + b[l * 64 + c];
}

// temporal MHA fused per (b,n); residual into H.
// Weights staged per-phase into LDS [o][65] (conflict-free); thread = (o=lane,
// 6-t accumulator block); xs reads are wave-uniform broadcasts.
__global__ __launch_bounds__(256) void k_temporal(
    float* __restrict__ H, const float* __restrict__ qw,
    const float* __restrict__ qb, const float* __restrict__ kw,
    const float* __restrict__ kb, const float* __restrict__ vw,
    const float* __restrict__ vb, const float* __restrict__ ow,
    const float* __restrict__ ob, int l) {
  __shared__ float xs[24 * 66], qs[24 * 66], ks[24 * 66], vs[24 * 66];
  __shared__ float ss[96 * 25];
  __shared__ float wbuf[64 * 65];
  int bn = blockIdx.x;
  int b = bn / N, n = bn % N;
  size_t base = ((size_t)b * T * N + n) * 64;
  int lane = threadIdx.x & 63, tg = threadIdx.x >> 6;
  for (int t = tg; t < 24; t += 4) xs[t * 66 + lane] = H[base + (size_t)t * NC + lane];
  const float* Wm[4] = {qw + l * 4096, kw + l * 4096, vw + l * 4096, ow + l * 4096};
  const float* Bm[4] = {qb + l * 64, kb + l * 64, vb + l * 64, ob + l * 64};
  float* Dm[3] = {qs, ks, vs};
#pragma unroll
  for (int ph = 0; ph < 3; ph++) {
    for (int e = threadIdx.x; e < 4096; e += 256)
      wbuf[(e >> 6) * 65 + (e & 63)] = Wm[ph][e];
    __syncthreads();
    float acc[6];
    float bv = Bm[ph][lane];
#pragma unroll
    for (int i = 0; i < 6; i++) acc[i] = bv;
    for (int c = 0; c < 64; c++) {
      float wv = wbuf[lane * 65 + c];
#pragma unroll
      for (int i = 0; i < 6; i++) acc[i] += wv * xs[(tg * 6 + i) * 66 + c];
    }
    float* dst = Dm[ph];
#pragma unroll
    for (int i = 0; i < 6; i++) dst[(tg * 6 + i) * 66 + lane] = acc[i];
    __syncthreads();
  }
  // scores: 4 heads x 24 x 24
  for (int e = threadIdx.x; e < 2304; e += 256) {
    int u = e % 24, t = (e / 24) % 24, h = e / 576;
    float a = 0.f;
#pragma unroll
    for (int d = 0; d < 16; d++)
      a += qs[t * 66 + h * 16 + d] * ks[u * 66 + h * 16 + d];
    ss[(h * 24 + t) * 25 + u] = a * 0.25f;  // 1/sqrt(HD)
  }
  __syncthreads();
  if (threadIdx.x < 96) {
    float* row = ss + threadIdx.x * 25;
    float mx = -INFINITY;
#pragma unroll
    for (int u = 0; u < 24; u++) mx = fmaxf(mx, row[u]);
    float sum = 0.f;
#pragma unroll
    for (int u = 0; u < 24; u++) {
      float e2 = expf(row[u] - mx);
      row[u] = e2;
      sum += e2;
    }
    float inv = 1.f / sum;
#pragma unroll
    for (int u = 0; u < 24; u++) row[u] *= inv;
  }
  __syncthreads();
  // apply: att -> xs (xs dead after projections)
  for (int e = threadIdx.x; e < 1536; e += 256) {
    int t = e >> 6, c = e & 63, h = c >> 4;
    float a = 0.f;
#pragma unroll
    for (int u = 0; u < 24; u++) a += ss[(h * 24 + t) * 25 + u] * vs[u * 66 + c];
    xs[t * 66 + c] = a;
  }
  __syncthreads();
  // output projection + residual
  for (int e = threadIdx.x; e < 4096; e += 256)
    wbuf[(e >> 6) * 65 + (e & 63)] = Wm[3][e];
  __syncthreads();
  float acc[6];
  float bv = Bm[3][lane];
#pragma unroll
  for (int i = 0; i < 6; i++) acc[i] = bv;
  for (int cp = 0; cp < 64; cp++) {
    float wv = wbuf[lane * 65 + cp];
#pragma unroll
    for (int i = 0; i < 6; i++) acc[i] += wv * xs[(tg * 6 + i) * 66 + cp];
  }
#pragma unroll
  for (int i = 0; i < 6; i++)
    H[base + (size_t)(tg * 6 + i) * NC + lane] += acc[i];
}

// per-layer transpose: w1t[c][j] = w1[l][j][c]. grid 64 x 256.
__global__ __launch_bounds__(256) void k_transpose_w1(
    const float* __restrict__ w1, float* __restrict__ w1t, int l) {
  int e = blockIdx.x * 256 + threadIdx.x;  // 0..16383
  int c = e >> 8, j = e & 255;
  w1t[e] = w1[l * 16384 + j * 64 + c];
}

// LN2 + FFN first GEMM (relu) -> hid. one block per (b,n).
// w1t is pre-transposed [c][j]: float4 loads are perfectly coalesced.
__global__ __launch_bounds__(256) void k_ffn1(
    const float* __restrict__ H, const float* __restrict__ lnw,
    const float* __restrict__ lnb, const float* __restrict__ w1t,
    const float* __restrict__ b1, float* __restrict__ hid, int l) {
  __shared__ float xs[24 * 66];
  int bn = blockIdx.x;
  int b = bn / N, n = bn % N;
  size_t base = ((size_t)b * T * N + n) * 64;
  int lane = threadIdx.x & 63, tg = threadIdx.x >> 6;
  for (int t = tg; t < 24; t += 4) {
    float xv = H[base + (size_t)t * NC + lane];
    float mean = wsum(xv) * (1.f / 64.f);
    float d = xv - mean;
    float var = wsum(d * d) * (1.f / 64.f);
    xs[t * 66 + lane] = d / sqrtf(var + 1e-5f) * lnw[l * 64 + lane] + lnb[l * 64 + lane];
  }
  __syncthreads();
  int j0 = lane * 4;
  float4 b4 = *(const float4*)(b1 + l * 256 + j0);
  float a0[6], a1[6], a2[6], a3[6];
#pragma unroll
  for (int i = 0; i < 6; i++) { a0[i] = b4.x; a1[i] = b4.y; a2[i] = b4.z; a3[i] = b4.w; }
  for (int c = 0; c < 64; c++) {
    float4 w4 = *(const float4*)(w1t + c * 256 + j0);
#pragma unroll
    for (int i = 0; i < 6; i++) {
      float xv = xs[(tg * 6 + i) * 66 + c];
      a0[i] += xv * w4.x;
      a1[i] += xv * w4.y;
      a2[i] += xv * w4.z;
      a3[i] += xv * w4.w;
    }
  }
#pragma unroll
  for (int i = 0; i < 6; i++) {
    int t = tg * 6 + i;
    float4 r = make_float4(fmaxf(a0[i], 0.f), fmaxf(a1[i], 0.f),
                           fmaxf(a2[i], 0.f), fmaxf(a3[i], 0.f));
    *(float4*)(hid + ((size_t)bn * 24 + t) * 256 + j0) = r;
  }
}

// FFN second GEMM + (recomputed) LN2 residual; writes H = hl + ffn.
// w2 staged LDS [c][258] (bank = 2c+j -> 2-way, free); hid read as
// wave-uniform float4 broadcasts with 6-way ILP.
__global__ __launch_bounds__(256) void k_ffn2(
    float* __restrict__ H, const float* __restrict__ hid,
    const float* __restrict__ lnw, const float* __restrict__ lnb,
    const float* __restrict__ w2, const float* __restrict__ b2, int l) {
  __shared__ float w2s[64 * 258];
  int bn = blockIdx.x;
  int b = bn / N, n = bn % N;
  for (int e = threadIdx.x; e < 16384; e += 256) {
    int c = e >> 8, j = e & 255;
    w2s[c * 258 + j] = w2[l * 16384 + e];
  }
  __syncthreads();
  int lane = threadIdx.x & 63, tg = threadIdx.x >> 6;
  size_t base = ((size_t)b * T * N + n) * 64;
  const float* hid_bn = hid + (size_t)bn * 24 * 256;
  float acc[6];
#pragma unroll
  for (int i = 0; i < 6; i++) acc[i] = 0.f;
  const float* wrow = w2s + lane * 258;
  for (int j = 0; j < 256; j += 4) {
    float2 wa = *(const float2*)(wrow + j);
    float2 wb2 = *(const float2*)(wrow + j + 2);
#pragma unroll
    for (int i = 0; i < 6; i++) {
      float4 hv = *(const float4*)(hid_bn + (size_t)(tg * 6 + i) * 256 + j);
      acc[i] += hv.x * wa.x + hv.y * wa.y + hv.z * wb2.x + hv.w * wb2.y;
    }
  }
  float bias = b2[l * 64 + lane];
#pragma unroll
  for (int i = 0; i < 6; i++) {
    int t = tg * 6 + i;
    float xv = H[base + (size_t)t * NC + lane];
    float mean = wsum(xv) * (1.f / 64.f);
    float d = xv - mean;
    float var = wsum(d * d) * (1.f / 64.f);
    float hl = d / sqrtf(var + 1e-5f) * lnw[l * 64 + lane] + lnb[l * 64 + lane];
    H[base + (size_t)t * NC + lane] = hl + bias + acc[i];
  }
}

// GRU input projection: xp[t,bn,g] = bih + X . wih. 16 pairs per block.
__global__ __launch_bounds__(256) void k_gru_xp(
    const float* __restrict__ X, const float* __restrict__ wih,
    const float* __restrict__ bih, float* __restrict__ xp, int l) {
  __shared__ float ws_[192 * 65];
  __shared__ float xv[16 * 64];
  int p0 = blockIdx.x * 16;
  for (int e = threadIdx.x; e < 192 * 64; e += 256) {
    int gI = e >> 6, c = e & 63;
    ws_[gI * 65 + c] = wih[l * 12288 + e];
  }
  for (int e = threadIdx.x; e < 16 * 64; e += 256) {
    int s = e >> 6, c = e & 63;
    int p = p0 + s;
    int t = p / BN, bn = p % BN;
    float val;
    if (l == 0) {
      int b = bn / N, n = bn % N;
      val = X[(((size_t)b * T + t) * N + n) * 64 + c];
    } else {
      val = X[(size_t)p * 64 + c];  // seq1[t,bn,c]
    }
    xv[e] = val;
  }
  __syncthreads();
  for (int e = threadIdx.x; e < 16 * 192; e += 256) {
    int s = e / 192, gI = e % 192;
    float acc = bih[l * 192 + gI];
#pragma unroll
    for (int c = 0; c < 64; c++) acc += xv[s * 64 + c] * ws_[gI * 65 + c];
    xp[((size_t)(p0 + s)) * 192 + gI] = acc;
  }
}

// GRU recurrence: 16 samples per block, sequential over T.
__global__ __launch_bounds__(256) void k_gru_scan(
    const float* __restrict__ xp, const float* __restrict__ whh,
    const float* __restrict__ bhh, float* __restrict__ seq_out, int l) {
  __shared__ float ws_[192 * 65];
  __shared__ float hprev[16 * 64];
  int bn0 = blockIdx.x * 16;
  for (int e = threadIdx.x; e < 192 * 64; e += 256) {
    int gI = e >> 6, c = e & 63;
    ws_[gI * 65 + c] = whh[l * 12288 + e];
  }
  for (int e = threadIdx.x; e < 1024; e += 256) hprev[e] = 0.f;
  __syncthreads();
  for (int t = 0; t < T; t++) {
    float hnew[4];
#pragma unroll
    for (int i = 0; i < 4; i++) {
      int idx = threadIdx.x + 256 * i;
      int s = idx >> 6, c = idx & 63;
      const float* xr = xp + ((size_t)t * BN + bn0 + s) * 192;
      float hgr = bhh[l * 192 + c];
      float hgz = bhh[l * 192 + 64 + c];
      float hgn = bhh[l * 192 + 128 + c];
      const float* hp = hprev + s * 64;
#pragma unroll
      for (int cc = 0; cc < 64; cc++) {
        float hv = hp[cc];
        hgr += hv * ws_[c * 65 + cc];
        hgz += hv * ws_[(64 + c) * 65 + cc];
        hgn += hv * ws_[(128 + c) * 65 + cc];
      }
      float r = 1.f / (1.f + expf(-(xr[c] + hgr)));
      float z = 1.f / (1.f + expf(-(xr[64 + c] + hgz)));
      float nn = tanhf(xr[128 + c] + r * hgn);
      hnew[i] = (1.f - z) * nn + z * hp[c];
    }
    __syncthreads();
#pragma unroll
    for (int i = 0; i < 4; i++) {
      int idx = threadIdx.x + 256 * i;
      int s = idx >> 6, c = idx & 63;
      hprev[s * 64 + c] = hnew[i];
      seq_out[((size_t)t * BN + bn0 + s) * 64 + c] = hnew[i];
    }
    __syncthreads();
  }
}

// prediction head: one block per bn.
__global__ __launch_bounds__(256) void k_pred(
    const float* __restrict__ seq2, const float* __restrict__ pw,
    const float* __restrict__ pb, float* __restrict__ out) {
  __shared__ float s_[1536];
  int bn = blockIdx.x;
  int b = bn / N, n = bn % N;
  for (int e = threadIdx.x; e < 1536; e += 256) {
    int t = e >> 6, c = e & 63;
    s_[c * 24 + t] = seq2[((size_t)t * BN + bn) * 64 + c];
  }
  __syncthreads();
  int wave = threadIdx.x >> 6, lane = threadIdx.x & 63;
  for (int hor = wave; hor < 12; hor += 4) {
    const float* w = pw + hor * 1536;
    float acc = 0.f;
#pragma unroll 4
    for (int kk = lane; kk < 1536; kk += 64) acc += s_[kk] * w[kk];
    acc = wsum(acc);
    if (lane == 0) out[(size_t)b * (HOR * N) + hor * N + n] = acc + pb[hor];
  }
}

}  // namespace

extern "C" void kernel_launch(void* const* d_in, const int* in_sizes, int n_in,
                              void* d_out, int out_size, void* d_ws, size_t ws_size,
                              hipStream_t stream) {
  const float* x       = (const float*)d_in[0];
  const float* adj     = (const float*)d_in[1];
  const float* nodee   = (const float*)d_in[2];
  const float* hour_w  = (const float*)d_in[3];
  const float* hour_b  = (const float*)d_in[4];
  const float* day_w   = (const float*)d_in[5];
  const float* day_b   = (const float*)d_in[6];
  const float* wk_w    = (const float*)d_in[7];
  const float* wk_b    = (const float*)d_in[8];
  const float* in_w    = (const float*)d_in[9];
  const float* in_b    = (const float*)d_in[10];
  const float* sa_qw   = (const float*)d_in[11];
  const float* sa_qb   = (const float*)d_in[12];
  const float* sa_kw   = (const float*)d_in[13];
  const float* sa_kb   = (const float*)d_in[14];
  const float* sa_vw   = (const float*)d_in[15];
  const float* sa_vb   = (const float*)d_in[16];
  const float* ta_qw   = (const float*)d_in[17];
  const float* ta_qb   = (const float*)d_in[18];
  const float* ta_kw   = (const float*)d_in[19];
  const float* ta_kb   = (const float*)d_in[20];
  const float* ta_vw   = (const float*)d_in[21];
  const float* ta_vb   = (const float*)d_in[22];
  const float* ta_ow   = (const float*)d_in[23];
  const float* ta_ob   = (const float*)d_in[24];
  const float* ln1_w   = (const float*)d_in[25];
  const float* ln1_b   = (const float*)d_in[26];
  const float* ln2_w   = (const float*)d_in[27];
  const float* ln2_b   = (const float*)d_in[28];
  const float* ffn_w1  = (const float*)d_in[29];
  const float* ffn_b1  = (const float*)d_in[30];
  const float* ffn_w2  = (const float*)d_in[31];
  const float* ffn_b2  = (const float*)d_in[32];
  const float* gru_wih = (const float*)d_in[33];
  const float* gru_whh = (const float*)d_in[34];
  const float* gru_bih = (const float*)d_in[35];
  const float* gru_bhh = (const float*)d_in[36];
  const float* pred_w  = (const float*)d_in[37];
  const float* pred_b  = (const float*)d_in[38];

  if (ws_size < WS_FLOATS * sizeof(float)) return;  // loud failure: output stays poisoned

  float* ws   = (float*)d_ws;
  float* H    = ws + H_OFF;
  float* bufA = ws + A_OFF;   // seq1
  float* q    = ws + Q_OFF;   // q during spatial stage; w1t during FFN stage
  float* k    = ws + K_OFF;
  float* bufB = ws + B_OFF;   // v | ffn hid | xp

  float* out       = (float*)d_out;
  float* attn_base = out + (size_t)B * HOR * N;  // 39744 (16B aligned)

  float* v   = bufB;
  float* hid = bufB;
  float* xp  = bufB;
  float* w1t = q;  // q is dead after k_spatial_attn; reused before next qkv

  k_embed<<<P / 4, 256, 0, stream>>>(x, nodee, hour_w, hour_b, day_w, day_b,
                                     wk_w, wk_b, in_w, in_b, H);

  for (int l = 0; l < 3; l++) {
    float* attn_l = attn_base + (size_t)l * BT * N * N;
    k_spatial_qkv<<<BT, 256, 0, stream>>>(H, sa_qw, sa_qb, sa_kw, sa_kb, sa_vw,
                                          sa_vb, q, k, v, l);
    k_spatial_attn<<<BT, 256, 0, stream>>>(q, k, adj, attn_l);
    k_spatial_apply<<<dim3(BT, 4), 256, 0, stream>>>(v, attn_l, H);
    k_ln1<<<P / 4, 256, 0, stream>>>(H, ln1_w, ln1_b, l);
    k_temporal<<<BN, 256, 0, stream>>>(H, ta_qw, ta_qb, ta_kw, ta_kb, ta_vw,
                                       ta_vb, ta_ow, ta_ob, l);
    k_transpose_w1<<<64, 256, 0, stream>>>(ffn_w1, w1t, l);
    k_ffn1<<<BN, 256, 0, stream>>>(H, ln2_w, ln2_b, w1t, ffn_b1, hid, l);
    k_ffn2<<<BN, 256, 0, stream>>>(H, hid, ln2_w, ln2_b, ffn_w2, ffn_b2, l);
  }

  k_gru_xp<<<P / 16, 256, 0, stream>>>(H, gru_wih, gru_bih, xp, 0);
  k_gru_scan<<<BN / 16, 256, 0, stream>>>(xp, gru_whh, gru_bhh, bufA, 0);
  k_gru_xp<<<P / 16, 256, 0, stream>>>(bufA, gru_wih, gru_bih, xp, 1);
  k_gru_scan<<<BN / 16, 256, 0, stream>>>(xp, gru_whh, gru_bhh, H, 1);

  k_pred<<<BN, 256, 0, stream>>>(H, pred_w, pred_b, out);
}

// Round 4
// 2767.356 us; speedup vs baseline: 2.3459x; 1.1519x over previous
//
#include <hip/hip_runtime.h>
#include <math.h>

namespace {

constexpr int B = 16, T = 24, N = 207, C = 64, HOR = 12;
constexpr int BT = B * T;          // 384
constexpr int BN = B * N;          // 3312
constexpr int P = B * T * N;       // 79488
constexpr int NC = N * C;          // 13248

// ws layout (floats)
constexpr size_t H_OFF = 0;                         // P*C = 5,087,232
constexpr size_t A_OFF = 5087232;                   // bufA: 5,087,232 (seq1)
constexpr size_t Q_OFF = A_OFF + 5087232;           // q: 635,904 (also reused as w1t)
constexpr size_t K_OFF = Q_OFF + 635904;            // k: 635,904
constexpr size_t B_OFF = K_OFF + 635904;            // bufB: 20,348,928 (v / hid / xp)
constexpr size_t WS_FLOATS = B_OFF + 20348928;      // 31,795,200

__device__ __forceinline__ float wsum(float v) {
#pragma unroll
  for (int off = 32; off; off >>= 1) v += __shfl_xor(v, off);
  return v;
}
__device__ __forceinline__ float wmax(float v) {
#pragma unroll
  for (int off = 32; off; off >>= 1) v = fmaxf(v, __shfl_xor(v, off));
  return v;
}

// H[b,t,n,c] layout. One block = 4 positions, 64 lanes = channels.
__global__ __launch_bounds__(256) void k_embed(
    const float* __restrict__ x, const float* __restrict__ nodee,
    const float* __restrict__ hw, const float* __restrict__ hb,
    const float* __restrict__ dw, const float* __restrict__ db,
    const float* __restrict__ ww, const float* __restrict__ wb,
    const float* __restrict__ inw, const float* __restrict__ inb,
    float* __restrict__ H) {
  int pos = blockIdx.x * 4 + (threadIdx.x >> 6);
  int c = threadIdx.x & 63;
  int n = pos % N;
  int t = (pos / N) % T;
  const float* xv = x + (size_t)pos * 4;
  float flow = xv[0], hour = xv[1], wkend = xv[2], day = xv[3];
  const float* w = inw + c * 65;
  float acc = inb[c] + w[0] * flow;
#pragma unroll
  for (int e = 0; e < 16; e++) {
    acc += w[1 + e] * nodee[n * 16 + e];
    acc += w[17 + e] * (hour * hw[e] + hb[e]);
    acc += w[33 + e] * (day * dw[e] + db[e]);
    acc += w[49 + e] * (wkend * ww[e] + wb[e]);
  }
  int i = c >> 1;
  float dv = expf((float)(2 * i) * (-9.210340371976184f / 64.0f));
  float ang = (float)t * dv;
  acc += (c & 1) ? cosf(ang) : sinf(ang);
  H[(size_t)pos * 64 + c] = acc;
}

// one block per g=(b,t). q,k: (B,8,T,N) flat; v: (B,64,T,N) flat.
__global__ __launch_bounds__(256) void k_spatial_qkv(
    const float* __restrict__ H, const float* __restrict__ qw,
    const float* __restrict__ qb, const float* __restrict__ kw,
    const float* __restrict__ kb, const float* __restrict__ vw,
    const float* __restrict__ vb, float* __restrict__ q, float* __restrict__ k,
    float* __restrict__ v, int l) {
  __shared__ float hs[N * 65];  // padded
  int g = blockIdx.x;
  int b = g / T, t = g % T;
  const float* Hbt = H + (size_t)g * NC;
  for (int e = threadIdx.x; e < NC; e += 256) {
    int n = e >> 6, c = e & 63;
    hs[n * 65 + c] = Hbt[e];
  }
  __syncthreads();
  qw += l * 8 * 64; qb += l * 8;
  kw += l * 8 * 64; kb += l * 8;
  vw += l * 64 * 64; vb += l * 64;
  for (int e = threadIdx.x; e < 16 * N; e += 256) {
    int o = e / N, n = e % N;
    int oo = o & 7;
    const float* W = (o < 8 ? qw : kw) + oo * 64;
    float acc = (o < 8 ? qb : kb)[oo];
#pragma unroll
    for (int c = 0; c < 64; c++) acc += W[c] * hs[n * 65 + c];
    size_t oidx = ((size_t)(b * 8 + oo) * T + t) * N + n;
    if (o < 8) q[oidx] = acc; else k[oidx] = acc;
  }
  for (int e = threadIdx.x; e < 64 * N; e += 256) {
    int o = e / N, n = e % N;
    const float* W = vw + o * 64;
    float acc = vb[o];
#pragma unroll
    for (int c = 0; c < 64; c++) acc += W[c] * hs[n * 65 + c];
    v[((size_t)(b * 64 + o) * T + t) * N + n] = acc;
  }
}

// one block per g. Double softmax with adjacency mask; writes attn to d_out slab.
__global__ __launch_bounds__(256) void k_spatial_attn(
    const float* __restrict__ q, const float* __restrict__ k,
    const float* __restrict__ adj, float* __restrict__ attn_out) {
  __shared__ float qs[8 * 208], ks[8 * 208];
  int g = blockIdx.x;
  const float* qg = q + (size_t)g * 1656;
  const float* kg = k + (size_t)g * 1656;
  for (int e = threadIdx.x; e < 1656; e += 256) {
    int c2 = e / N, n = e % N;
    qs[c2 * 208 + n] = qg[e];
    ks[c2 * 208 + n] = kg[e];
  }
  __syncthreads();
  int wave = threadIdx.x >> 6, lane = threadIdx.x & 63;
  for (int n = wave; n < N; n += 4) {
    float s[4];
    float mx = -INFINITY;
#pragma unroll
    for (int j = 0; j < 4; j++) {
      int m = lane + 64 * j;
      float acc = -INFINITY;
      if (m < N) {
        acc = 0.f;
#pragma unroll
        for (int c2 = 0; c2 < 8; c2++) acc += qs[c2 * 208 + n] * ks[c2 * 208 + m];
        acc *= 0.125f;  // 1/sqrt(C)
      }
      s[j] = acc;
      mx = fmaxf(mx, acc);
    }
    mx = wmax(mx);
    float sum = 0.f;
#pragma unroll
    for (int j = 0; j < 4; j++) {
      int m = lane + 64 * j;
      float e = (m < N) ? expf(s[j] - mx) : 0.f;
      s[j] = e;
      sum += e;
    }
    sum = wsum(sum);
    float inv = 1.f / sum;
    // second softmax over masked probabilities
    float mx2 = -INFINITY;
    bool ok[4];
#pragma unroll
    for (int j = 0; j < 4; j++) {
      int m = lane + 64 * j;
      float p = s[j] * inv;
      bool valid = (m < N) && (adj[n * N + m] != 0.0f);
      ok[j] = valid;
      s[j] = p;
      if (valid) mx2 = fmaxf(mx2, p);
    }
    mx2 = wmax(mx2);
    float sum2 = 0.f;
#pragma unroll
    for (int j = 0; j < 4; j++) {
      float e = ok[j] ? expf(s[j] - mx2) : 0.f;
      s[j] = e;
      sum2 += e;
    }
    sum2 = wsum(sum2);
    float inv2 = 1.f / sum2;
    float* orow = attn_out + ((size_t)g * N + n) * N;
#pragma unroll
    for (int j = 0; j < 4; j++) {
      int m = lane + 64 * j;
      if (m < N) orow[m] = s[j] * inv2;
    }
  }
}

// sp = v2 @ attn^T, residual into H. grid (g, m-chunk). 13-row register
// blocking per wave; rows stride-4 so all 13 share the same float4 phase.
__global__ __launch_bounds__(256, 3) void k_spatial_apply(
    const float* __restrict__ v, const float* __restrict__ attn,
    float* __restrict__ H) {
  __shared__ float vs[64 * 207];
  int g = blockIdx.x;
  int ms = blockIdx.y;  // 0..3
  const float* vg = v + (size_t)g * NC;
  for (int e = threadIdx.x; e < NC; e += 256) vs[e] = vg[e];  // vs[c*207+n]
  __syncthreads();
  int wave = threadIdx.x >> 6, lane = threadIdx.x & 63;
  const float* ag = attn + (size_t)g * (N * N);
  float* Hg = H + (size_t)g * NC;
  int mbeg = ms * 52;
  int mend = min(mbeg + 52, N);
  int m_w = mbeg + wave;  // first row of this wave; rows m_w+4k, k=0..12
  size_t Dg = (size_t)g * (N * N);
  int p = (int)((4 - ((Dg + (size_t)m_w * N) & 3)) & 3);
  const float* ar[13];
  int mrow[13];
#pragma unroll
  for (int r = 0; r < 13; r++) {
    int m = m_w + 4 * r;
    mrow[r] = m;
    int msafe = (m < N) ? m : m - 4;  // phase-preserving clamp
    ar[r] = ag + (size_t)msafe * N;
  }
  float acc[13];
#pragma unroll
  for (int r = 0; r < 13; r++) acc[r] = 0.f;
  const float* vrow = vs + lane * 207;
  for (int n = 0; n < p; n++) {
    float vv = vrow[n];
#pragma unroll
    for (int r = 0; r < 13; r++) acc[r] += vv * ar[r][n];
  }
  for (int n4 = 0; n4 < 51; n4++) {
    int n = p + n4 * 4;
    float v0 = vrow[n], v1 = vrow[n + 1], v2 = vrow[n + 2], v3 = vrow[n + 3];
#pragma unroll
    for (int r = 0; r < 13; r++) {
      float4 a = *(const float4*)(ar[r] + n);
      acc[r] += v0 * a.x;
      acc[r] += v1 * a.y;
      acc[r] += v2 * a.z;
      acc[r] += v3 * a.w;
    }
  }
  for (int n = p + 204; n < 207; n++) {
    float vv = vrow[n];
#pragma unroll
    for (int r = 0; r < 13; r++) acc[r] += vv * ar[r][n];
  }
#pragma unroll
  for (int r = 0; r < 13; r++) {
    int m = mrow[r];
    if (m < mend) Hg[(size_t)m * 64 + lane] += acc[r];
  }
}

// LayerNorm over c, in place. wave per position.
__global__ __launch_bounds__(256) void k_ln1(float* __restrict__ H,
                                             const float* __restrict__ w,
                                             const float* __restrict__ b, int l) {
  int pos = blockIdx.x * 4 + (threadIdx.x >> 6);
  int c = threadIdx.x & 63;
  float xv = H[(size_t)pos * 64 + c];
  float mean = wsum(xv) * (1.f / 64.f);
  float d = xv - mean;
  float var = wsum(d * d) * (1.f / 64.f);
  H[(size_t)pos * 64 + c] = d / sqrtf(var + 1e-5f) * w[l * 64 + c] + b[l * 64 + c];
}

// temporal MHA fused per (b,n); residual into H.
__global__ __launch_bounds__(256) void k_temporal(
    float* __restrict__ H, const float* __restrict__ qw,
    const float* __restrict__ qb, const float* __restrict__ kw,
    const float* __restrict__ kb, const float* __restrict__ vw,
    const float* __restrict__ vb, const float* __restrict__ ow,
    const float* __restrict__ ob, int l) {
  __shared__ float xs[24 * 66], qs[24 * 66], ks[24 * 66], vs[24 * 66];
  __shared__ float ss[96 * 25];
  __shared__ float wbuf[64 * 65];
  int bn = blockIdx.x;
  int b = bn / N, n = bn % N;
  size_t base = ((size_t)b * T * N + n) * 64;
  int lane = threadIdx.x & 63, tg = threadIdx.x >> 6;
  for (int t = tg; t < 24; t += 4) xs[t * 66 + lane] = H[base + (size_t)t * NC + lane];
  const float* Wm[4] = {qw + l * 4096, kw + l * 4096, vw + l * 4096, ow + l * 4096};
  const float* Bm[4] = {qb + l * 64, kb + l * 64, vb + l * 64, ob + l * 64};
  float* Dm[3] = {qs, ks, vs};
#pragma unroll
  for (int ph = 0; ph < 3; ph++) {
    for (int e = threadIdx.x; e < 4096; e += 256)
      wbuf[(e >> 6) * 65 + (e & 63)] = Wm[ph][e];
    __syncthreads();
    float acc[6];
    float bv = Bm[ph][lane];
#pragma unroll
    for (int i = 0; i < 6; i++) acc[i] = bv;
    for (int c = 0; c < 64; c++) {
      float wv = wbuf[lane * 65 + c];
#pragma unroll
      for (int i = 0; i < 6; i++) acc[i] += wv * xs[(tg * 6 + i) * 66 + c];
    }
    float* dst = Dm[ph];
#pragma unroll
    for (int i = 0; i < 6; i++) dst[(tg * 6 + i) * 66 + lane] = acc[i];
    __syncthreads();
  }
  // scores: 4 heads x 24 x 24
  for (int e = threadIdx.x; e < 2304; e += 256) {
    int u = e % 24, t = (e / 24) % 24, h = e / 576;
    float a = 0.f;
#pragma unroll
    for (int d = 0; d < 16; d++)
      a += qs[t * 66 + h * 16 + d] * ks[u * 66 + h * 16 + d];
    ss[(h * 24 + t) * 25 + u] = a * 0.25f;  // 1/sqrt(HD)
  }
  __syncthreads();
  if (threadIdx.x < 96) {
    float* row = ss + threadIdx.x * 25;
    float mx = -INFINITY;
#pragma unroll
    for (int u = 0; u < 24; u++) mx = fmaxf(mx, row[u]);
    float sum = 0.f;
#pragma unroll
    for (int u = 0; u < 24; u++) {
      float e2 = expf(row[u] - mx);
      row[u] = e2;
      sum += e2;
    }
    float inv = 1.f / sum;
#pragma unroll
    for (int u = 0; u < 24; u++) row[u] *= inv;
  }
  __syncthreads();
  // apply: att -> xs (xs dead after projections)
  for (int e = threadIdx.x; e < 1536; e += 256) {
    int t = e >> 6, c = e & 63, h = c >> 4;
    float a = 0.f;
#pragma unroll
    for (int u = 0; u < 24; u++) a += ss[(h * 24 + t) * 25 + u] * vs[u * 66 + c];
    xs[t * 66 + c] = a;
  }
  __syncthreads();
  // output projection + residual
  for (int e = threadIdx.x; e < 4096; e += 256)
    wbuf[(e >> 6) * 65 + (e & 63)] = Wm[3][e];
  __syncthreads();
  float acc[6];
  float bv = Bm[3][lane];
#pragma unroll
  for (int i = 0; i < 6; i++) acc[i] = bv;
  for (int cp = 0; cp < 64; cp++) {
    float wv = wbuf[lane * 65 + cp];
#pragma unroll
    for (int i = 0; i < 6; i++) acc[i] += wv * xs[(tg * 6 + i) * 66 + cp];
  }
#pragma unroll
  for (int i = 0; i < 6; i++)
    H[base + (size_t)(tg * 6 + i) * NC + lane] += acc[i];
}

// per-layer transpose: w1t[c][j] = w1[l][j][c]. grid 64 x 256.
__global__ __launch_bounds__(256) void k_transpose_w1(
    const float* __restrict__ w1, float* __restrict__ w1t, int l) {
  int e = blockIdx.x * 256 + threadIdx.x;  // 0..16383
  int c = e >> 8, j = e & 255;
  w1t[e] = w1[l * 16384 + j * 64 + c];
}

// LN2 + FFN first GEMM (relu) -> hid. one block per (b,n).
// w1t is pre-transposed [c][j]: float4 loads are perfectly coalesced.
__global__ __launch_bounds__(256) void k_ffn1(
    const float* __restrict__ H, const float* __restrict__ lnw,
    const float* __restrict__ lnb, const float* __restrict__ w1t,
    const float* __restrict__ b1, float* __restrict__ hid, int l) {
  __shared__ float xs[24 * 66];
  int bn = blockIdx.x;
  int b = bn / N, n = bn % N;
  size_t base = ((size_t)b * T * N + n) * 64;
  int lane = threadIdx.x & 63, tg = threadIdx.x >> 6;
  for (int t = tg; t < 24; t += 4) {
    float xv = H[base + (size_t)t * NC + lane];
    float mean = wsum(xv) * (1.f / 64.f);
    float d = xv - mean;
    float var = wsum(d * d) * (1.f / 64.f);
    xs[t * 66 + lane] = d / sqrtf(var + 1e-5f) * lnw[l * 64 + lane] + lnb[l * 64 + lane];
  }
  __syncthreads();
  int j0 = lane * 4;
  float4 b4 = *(const float4*)(b1 + l * 256 + j0);
  float a0[6], a1[6], a2[6], a3[6];
#pragma unroll
  for (int i = 0; i < 6; i++) { a0[i] = b4.x; a1[i] = b4.y; a2[i] = b4.z; a3[i] = b4.w; }
  for (int c = 0; c < 64; c++) {
    float4 w4 = *(const float4*)(w1t + c * 256 + j0);
#pragma unroll
    for (int i = 0; i < 6; i++) {
      float xv = xs[(tg * 6 + i) * 66 + c];
      a0[i] += xv * w4.x;
      a1[i] += xv * w4.y;
      a2[i] += xv * w4.z;
      a3[i] += xv * w4.w;
    }
  }
#pragma unroll
  for (int i = 0; i < 6; i++) {
    int t = tg * 6 + i;
    float4 r = make_float4(fmaxf(a0[i], 0.f), fmaxf(a1[i], 0.f),
                           fmaxf(a2[i], 0.f), fmaxf(a3[i], 0.f));
    *(float4*)(hid + ((size_t)bn * 24 + t) * 256 + j0) = r;
  }
}

// FFN second GEMM + (recomputed) LN2 residual; writes H = hl + ffn.
__global__ __launch_bounds__(256) void k_ffn2(
    float* __restrict__ H, const float* __restrict__ hid,
    const float* __restrict__ lnw, const float* __restrict__ lnb,
    const float* __restrict__ w2, const float* __restrict__ b2, int l) {
  __shared__ float w2s[64 * 258];
  int bn = blockIdx.x;
  int b = bn / N, n = bn % N;
  for (int e = threadIdx.x; e < 16384; e += 256) {
    int c = e >> 8, j = e & 255;
    w2s[c * 258 + j] = w2[l * 16384 + e];
  }
  __syncthreads();
  int lane = threadIdx.x & 63, tg = threadIdx.x >> 6;
  size_t base = ((size_t)b * T * N + n) * 64;
  const float* hid_bn = hid + (size_t)bn * 24 * 256;
  float acc[6];
#pragma unroll
  for (int i = 0; i < 6; i++) acc[i] = 0.f;
  const float* wrow = w2s + lane * 258;
  for (int j = 0; j < 256; j += 4) {
    float2 wa = *(const float2*)(wrow + j);
    float2 wb2 = *(const float2*)(wrow + j + 2);
#pragma unroll
    for (int i = 0; i < 6; i++) {
      float4 hv = *(const float4*)(hid_bn + (size_t)(tg * 6 + i) * 256 + j);
      acc[i] += hv.x * wa.x + hv.y * wa.y + hv.z * wb2.x + hv.w * wb2.y;
    }
  }
  float bias = b2[l * 64 + lane];
#pragma unroll
  for (int i = 0; i < 6; i++) {
    int t = tg * 6 + i;
    float xv = H[base + (size_t)t * NC + lane];
    float mean = wsum(xv) * (1.f / 64.f);
    float d = xv - mean;
    float var = wsum(d * d) * (1.f / 64.f);
    float hl = d / sqrtf(var + 1e-5f) * lnw[l * 64 + lane] + lnb[l * 64 + lane];
    H[base + (size_t)t * NC + lane] = hl + bias + acc[i];
  }
}

// GRU input projection: xp[t,bn,g] = bih + X . wih. 16 pairs per block.
__global__ __launch_bounds__(256) void k_gru_xp(
    const float* __restrict__ X, const float* __restrict__ wih,
    const float* __restrict__ bih, float* __restrict__ xp, int l) {
  __shared__ float ws_[192 * 65];
  __shared__ float xv[16 * 64];
  int p0 = blockIdx.x * 16;
  for (int e = threadIdx.x; e < 192 * 64; e += 256) {
    int gI = e >> 6, c = e & 63;
    ws_[gI * 65 + c] = wih[l * 12288 + e];
  }
  for (int e = threadIdx.x; e < 16 * 64; e += 256) {
    int s = e >> 6, c = e & 63;
    int p = p0 + s;
    int t = p / BN, bn = p % BN;
    float val;
    if (l == 0) {
      int b = bn / N, n = bn % N;
      val = X[(((size_t)b * T + t) * N + n) * 64 + c];
    } else {
      val = X[(size_t)p * 64 + c];  // seq1[t,bn,c]
    }
    xv[e] = val;
  }
  __syncthreads();
  for (int e = threadIdx.x; e < 16 * 192; e += 256) {
    int s = e / 192, gI = e % 192;
    float acc = bih[l * 192 + gI];
#pragma unroll
    for (int c = 0; c < 64; c++) acc += xv[s * 64 + c] * ws_[gI * 65 + c];
    xp[((size_t)(p0 + s)) * 192 + gI] = acc;
  }
}

// GRU recurrence v2: 8 samples/block -> 414 blocks. Waves 0-2 hold one gate's
// 64x64 weights in registers (lane c = row g*64+c); hprev read as float4
// LDS broadcasts. Wave 3 prefetches next step's xp (double-buffered).
__global__ __launch_bounds__(256) void k_gru_scan(
    const float* __restrict__ xp, const float* __restrict__ whh,
    const float* __restrict__ bhh, float* __restrict__ seq_out, int l) {
  constexpr int S = 8;
  __shared__ float hprev[S][64];
  __shared__ float hg[3][S][64];
  __shared__ float xpbuf[2][S * 192];
  int bn0 = blockIdx.x * S;
  int lane = threadIdx.x & 63;
  int wv = threadIdx.x >> 6;

  // gate-wave weights -> registers (once)
  float4 w4[16];
  if (wv < 3) {
    const float* wr = whh + l * 12288 + (wv * 64 + lane) * 64;
#pragma unroll
    for (int j = 0; j < 16; j++) w4[j] = *(const float4*)(wr + j * 4);
  }
  // combine-phase biases (c = lane for both items)
  float b_r = bhh[l * 192 + lane];
  float b_z = bhh[l * 192 + 64 + lane];
  float b_n = bhh[l * 192 + 128 + lane];

  // init hprev = 0; preload xp for t=0
  for (int e = threadIdx.x; e < S * 64; e += 256) ((float*)hprev)[e] = 0.f;
  {
    const float* src = xp + (size_t)bn0 * 192;
    for (int e = threadIdx.x; e < S * 192; e += 256) xpbuf[0][e] = src[e];
  }
  __syncthreads();

  for (int t = 0; t < T; t++) {
    int cur = t & 1;
    if (wv < 3) {
      float acc[S];
#pragma unroll
      for (int s = 0; s < S; s++) acc[s] = 0.f;
#pragma unroll
      for (int j = 0; j < 16; j++) {
        float4 w = w4[j];
#pragma unroll
        for (int s = 0; s < S; s++) {
          float4 hb = *(const float4*)(&hprev[s][j * 4]);
          acc[s] += w.x * hb.x + w.y * hb.y + w.z * hb.z + w.w * hb.w;
        }
      }
#pragma unroll
      for (int s = 0; s < S; s++) hg[wv][s][lane] = acc[s];
    } else {
      // prefetch next step's xp into the other buffer
      if (t + 1 < T) {
        const float* src = xp + ((size_t)(t + 1) * BN + bn0) * 192;
        float* dst = xpbuf[(t + 1) & 1];
        for (int e = lane * 4; e < S * 192; e += 256) {
          *(float4*)(dst + e) = *(const float4*)(src + e);
        }
      }
    }
    __syncthreads();
    // combine: 512 items over 256 threads (item = s*64 + c; c = lane)
#pragma unroll
    for (int ii = 0; ii < 2; ii++) {
      int s = wv + 4 * ii;
      const float* xr = &xpbuf[cur][s * 192];
      float r = 1.f / (1.f + expf(-(xr[lane] + hg[0][s][lane] + b_r)));
      float z = 1.f / (1.f + expf(-(xr[64 + lane] + hg[1][s][lane] + b_z)));
      float nn = tanhf(xr[128 + lane] + r * (hg[2][s][lane] + b_n));
      float hp = hprev[s][lane];
      float hnew = (1.f - z) * nn + z * hp;
      hprev[s][lane] = hnew;
      seq_out[((size_t)t * BN + bn0 + s) * 64 + lane] = hnew;
    }
    __syncthreads();
  }
}

// prediction head: one block per bn.
__global__ __launch_bounds__(256) void k_pred(
    const float* __restrict__ seq2, const float* __restrict__ pw,
    const float* __restrict__ pb, float* __restrict__ out) {
  __shared__ float s_[1536];
  int bn = blockIdx.x;
  int b = bn / N, n = bn % N;
  for (int e = threadIdx.x; e < 1536; e += 256) {
    int t = e >> 6, c = e & 63;
    s_[c * 24 + t] = seq2[((size_t)t * BN + bn) * 64 + c];
  }
  __syncthreads();
  int wave = threadIdx.x >> 6, lane = threadIdx.x & 63;
  for (int hor = wave; hor < 12; hor += 4) {
    const float* w = pw + hor * 1536;
    float acc = 0.f;
#pragma unroll 4
    for (int kk = lane; kk < 1536; kk += 64) acc += s_[kk] * w[kk];
    acc = wsum(acc);
    if (lane == 0) out[(size_t)b * (HOR * N) + hor * N + n] = acc + pb[hor];
  }
}

}  // namespace

extern "C" void kernel_launch(void* const* d_in, const int* in_sizes, int n_in,
                              void* d_out, int out_size, void* d_ws, size_t ws_size,
                              hipStream_t stream) {
  const float* x       = (const float*)d_in[0];
  const float* adj     = (const float*)d_in[1];
  const float* nodee   = (const float*)d_in[2];
  const float* hour_w  = (const float*)d_in[3];
  const float* hour_b  = (const float*)d_in[4];
  const float* day_w   = (const float*)d_in[5];
  const float* day_b   = (const float*)d_in[6];
  const float* wk_w    = (const float*)d_in[7];
  const float* wk_b    = (const float*)d_in[8];
  const float* in_w    = (const float*)d_in[9];
  const float* in_b    = (const float*)d_in[10];
  const float* sa_qw   = (const float*)d_in[11];
  const float* sa_qb   = (const float*)d_in[12];
  const float* sa_kw   = (const float*)d_in[13];
  const float* sa_kb   = (const float*)d_in[14];
  const float* sa_vw   = (const float*)d_in[15];
  const float* sa_vb   = (const float*)d_in[16];
  const float* ta_qw   = (const float*)d_in[17];
  const float* ta_qb   = (const float*)d_in[18];
  const float* ta_kw   = (const float*)d_in[19];
  const float* ta_kb   = (const float*)d_in[20];
  const float* ta_vw   = (const float*)d_in[21];
  const float* ta_vb   = (const float*)d_in[22];
  const float* ta_ow   = (const float*)d_in[23];
  const float* ta_ob   = (const float*)d_in[24];
  const float* ln1_w   = (const float*)d_in[25];
  const float* ln1_b   = (const float*)d_in[26];
  const float* ln2_w   = (const float*)d_in[27];
  const float* ln2_b   = (const float*)d_in[28];
  const float* ffn_w1  = (const float*)d_in[29];
  const float* ffn_b1  = (const float*)d_in[30];
  const float* ffn_w2  = (const float*)d_in[31];
  const float* ffn_b2  = (const float*)d_in[32];
  const float* gru_wih = (const float*)d_in[33];
  const float* gru_whh = (const float*)d_in[34];
  const float* gru_bih = (const float*)d_in[35];
  const float* gru_bhh = (const float*)d_in[36];
  const float* pred_w  = (const float*)d_in[37];
  const float* pred_b  = (const float*)d_in[38];

  if (ws_size < WS_FLOATS * sizeof(float)) return;  // loud failure: output stays poisoned

  float* ws   = (float*)d_ws;
  float* H    = ws + H_OFF;
  float* bufA = ws + A_OFF;   // seq1
  float* q    = ws + Q_OFF;   // q during spatial stage; w1t during FFN stage
  float* k    = ws + K_OFF;
  float* bufB = ws + B_OFF;   // v | ffn hid | xp

  float* out       = (float*)d_out;
  float* attn_base = out + (size_t)B * HOR * N;  // 39744 (16B aligned)

  float* v   = bufB;
  float* hid = bufB;
  float* xp  = bufB;
  float* w1t = q;  // q is dead after k_spatial_attn; reused before next qkv

  k_embed<<<P / 4, 256, 0, stream>>>(x, nodee, hour_w, hour_b, day_w, day_b,
                                     wk_w, wk_b, in_w, in_b, H);

  for (int l = 0; l < 3; l++) {
    float* attn_l = attn_base + (size_t)l * BT * N * N;
    k_spatial_qkv<<<BT, 256, 0, stream>>>(H, sa_qw, sa_qb, sa_kw, sa_kb, sa_vw,
                                          sa_vb, q, k, v, l);
    k_spatial_attn<<<BT, 256, 0, stream>>>(q, k, adj, attn_l);
    k_spatial_apply<<<dim3(BT, 4), 256, 0, stream>>>(v, attn_l, H);
    k_ln1<<<P / 4, 256, 0, stream>>>(H, ln1_w, ln1_b, l);
    k_temporal<<<BN, 256, 0, stream>>>(H, ta_qw, ta_qb, ta_kw, ta_kb, ta_vw,
                                       ta_vb, ta_ow, ta_ob, l);
    k_transpose_w1<<<64, 256, 0, stream>>>(ffn_w1, w1t, l);
    k_ffn1<<<BN, 256, 0, stream>>>(H, ln2_w, ln2_b, w1t, ffn_b1, hid, l);
    k_ffn2<<<BN, 256, 0, stream>>>(H, hid, ln2_w, ln2_b, ffn_w2, ffn_b2, l);
  }

  k_gru_xp<<<P / 16, 256, 0, stream>>>(H, gru_wih, gru_bih, xp, 0);
  k_gru_scan<<<BN / 8, 256, 0, stream>>>(xp, gru_whh, gru_bhh, bufA, 0);
  k_gru_xp<<<P / 16, 256, 0, stream>>>(bufA, gru_wih, gru_bih, xp, 1);
  k_gru_scan<<<BN / 8, 256, 0, stream>>>(xp, gru_whh, gru_bhh, H, 1);

  k_pred<<<BN, 256, 0, stream>>>(H, pred_w, pred_b, out);
}

// Round 5
// 2397.368 us; speedup vs baseline: 2.7079x; 1.1543x over previous
//
#include <hip/hip_runtime.h>
#include <math.h>

namespace {

constexpr int B = 16, T = 24, N = 207, C = 64, HOR = 12;
constexpr int BT = B * T;          // 384
constexpr int BN = B * N;          // 3312
constexpr int P = B * T * N;       // 79488
constexpr int NC = N * C;          // 13248

// ws layout (floats)
constexpr size_t H_OFF = 0;                         // P*C = 5,087,232
constexpr size_t A_OFF = 5087232;                   // bufA: 5,087,232 (seq1)
constexpr size_t Q_OFF = A_OFF + 5087232;           // q: 635,904 (reused as w1t)
constexpr size_t K_OFF = Q_OFF + 635904;            // k: 635,904 (reused as w2q)
constexpr size_t B_OFF = K_OFF + 635904;            // bufB: 20,348,928 (v / xp)
constexpr size_t WS_FLOATS = B_OFF + 20348928;      // 31,795,200

__device__ __forceinline__ float wsum(float v) {
#pragma unroll
  for (int off = 32; off; off >>= 1) v += __shfl_xor(v, off);
  return v;
}
__device__ __forceinline__ float wmax(float v) {
#pragma unroll
  for (int off = 32; off; off >>= 1) v = fmaxf(v, __shfl_xor(v, off));
  return v;
}

// H[b,t,n,c] layout. One block = 4 positions, 64 lanes = channels.
__global__ __launch_bounds__(256) void k_embed(
    const float* __restrict__ x, const float* __restrict__ nodee,
    const float* __restrict__ hw, const float* __restrict__ hb,
    const float* __restrict__ dw, const float* __restrict__ db,
    const float* __restrict__ ww, const float* __restrict__ wb,
    const float* __restrict__ inw, const float* __restrict__ inb,
    float* __restrict__ H) {
  int pos = blockIdx.x * 4 + (threadIdx.x >> 6);
  int c = threadIdx.x & 63;
  int n = pos % N;
  int t = (pos / N) % T;
  const float* xv = x + (size_t)pos * 4;
  float flow = xv[0], hour = xv[1], wkend = xv[2], day = xv[3];
  const float* w = inw + c * 65;
  float acc = inb[c] + w[0] * flow;
#pragma unroll
  for (int e = 0; e < 16; e++) {
    acc += w[1 + e] * nodee[n * 16 + e];
    acc += w[17 + e] * (hour * hw[e] + hb[e]);
    acc += w[33 + e] * (day * dw[e] + db[e]);
    acc += w[49 + e] * (wkend * ww[e] + wb[e]);
  }
  int i = c >> 1;
  float dv = expf((float)(2 * i) * (-9.210340371976184f / 64.0f));
  float ang = (float)t * dv;
  acc += (c & 1) ? cosf(ang) : sinf(ang);
  H[(size_t)pos * 64 + c] = acc;
}

// one block per g=(b,t). q,k: (B,8,T,N) flat; v: (B,64,T,N) flat.
__global__ __launch_bounds__(256) void k_spatial_qkv(
    const float* __restrict__ H, const float* __restrict__ qw,
    const float* __restrict__ qb, const float* __restrict__ kw,
    const float* __restrict__ kb, const float* __restrict__ vw,
    const float* __restrict__ vb, float* __restrict__ q, float* __restrict__ k,
    float* __restrict__ v, int l) {
  __shared__ float hs[N * 65];  // padded
  int g = blockIdx.x;
  int b = g / T, t = g % T;
  const float* Hbt = H + (size_t)g * NC;
  for (int e = threadIdx.x; e < NC; e += 256) {
    int n = e >> 6, c = e & 63;
    hs[n * 65 + c] = Hbt[e];
  }
  __syncthreads();
  qw += l * 8 * 64; qb += l * 8;
  kw += l * 8 * 64; kb += l * 8;
  vw += l * 64 * 64; vb += l * 64;
  for (int e = threadIdx.x; e < 16 * N; e += 256) {
    int o = e / N, n = e % N;
    int oo = o & 7;
    const float* W = (o < 8 ? qw : kw) + oo * 64;
    float acc = (o < 8 ? qb : kb)[oo];
#pragma unroll
    for (int c = 0; c < 64; c++) acc += W[c] * hs[n * 65 + c];
    size_t oidx = ((size_t)(b * 8 + oo) * T + t) * N + n;
    if (o < 8) q[oidx] = acc; else k[oidx] = acc;
  }
  for (int e = threadIdx.x; e < 64 * N; e += 256) {
    int o = e / N, n = e % N;
    const float* W = vw + o * 64;
    float acc = vb[o];
#pragma unroll
    for (int c = 0; c < 64; c++) acc += W[c] * hs[n * 65 + c];
    v[((size_t)(b * 64 + o) * T + t) * N + n] = acc;
  }
}

// one block per g. Double softmax with adjacency mask; writes attn to d_out slab.
__global__ __launch_bounds__(256) void k_spatial_attn(
    const float* __restrict__ q, const float* __restrict__ k,
    const float* __restrict__ adj, float* __restrict__ attn_out) {
  __shared__ float qs[8 * 208], ks[8 * 208];
  int g = blockIdx.x;
  const float* qg = q + (size_t)g * 1656;
  const float* kg = k + (size_t)g * 1656;
  for (int e = threadIdx.x; e < 1656; e += 256) {
    int c2 = e / N, n = e % N;
    qs[c2 * 208 + n] = qg[e];
    ks[c2 * 208 + n] = kg[e];
  }
  __syncthreads();
  int wave = threadIdx.x >> 6, lane = threadIdx.x & 63;
  for (int n = wave; n < N; n += 4) {
    float s[4];
    float mx = -INFINITY;
#pragma unroll
    for (int j = 0; j < 4; j++) {
      int m = lane + 64 * j;
      float acc = -INFINITY;
      if (m < N) {
        acc = 0.f;
#pragma unroll
        for (int c2 = 0; c2 < 8; c2++) acc += qs[c2 * 208 + n] * ks[c2 * 208 + m];
        acc *= 0.125f;  // 1/sqrt(C)
      }
      s[j] = acc;
      mx = fmaxf(mx, acc);
    }
    mx = wmax(mx);
    float sum = 0.f;
#pragma unroll
    for (int j = 0; j < 4; j++) {
      int m = lane + 64 * j;
      float e = (m < N) ? expf(s[j] - mx) : 0.f;
      s[j] = e;
      sum += e;
    }
    sum = wsum(sum);
    float inv = 1.f / sum;
    // second softmax over masked probabilities
    float mx2 = -INFINITY;
    bool ok[4];
#pragma unroll
    for (int j = 0; j < 4; j++) {
      int m = lane + 64 * j;
      float p = s[j] * inv;
      bool valid = (m < N) && (adj[n * N + m] != 0.0f);
      ok[j] = valid;
      s[j] = p;
      if (valid) mx2 = fmaxf(mx2, p);
    }
    mx2 = wmax(mx2);
    float sum2 = 0.f;
#pragma unroll
    for (int j = 0; j < 4; j++) {
      float e = ok[j] ? expf(s[j] - mx2) : 0.f;
      s[j] = e;
      sum2 += e;
    }
    sum2 = wsum(sum2);
    float inv2 = 1.f / sum2;
    float* orow = attn_out + ((size_t)g * N + n) * N;
#pragma unroll
    for (int j = 0; j < 4; j++) {
      int m = lane + 64 * j;
      if (m < N) orow[m] = s[j] * inv2;
    }
  }
}

// sp = v2 @ attn^T, residual into H. grid (g, m-chunk). 13-row register
// blocking per wave; rows stride-4 so all 13 share the same float4 phase.
__global__ __launch_bounds__(256, 3) void k_spatial_apply(
    const float* __restrict__ v, const float* __restrict__ attn,
    float* __restrict__ H) {
  __shared__ float vs[64 * 207];
  int g = blockIdx.x;
  int ms = blockIdx.y;  // 0..3
  const float* vg = v + (size_t)g * NC;
  for (int e = threadIdx.x; e < NC; e += 256) vs[e] = vg[e];  // vs[c*207+n]
  __syncthreads();
  int wave = threadIdx.x >> 6, lane = threadIdx.x & 63;
  const float* ag = attn + (size_t)g * (N * N);
  float* Hg = H + (size_t)g * NC;
  int mbeg = ms * 52;
  int mend = min(mbeg + 52, N);
  int m_w = mbeg + wave;  // first row of this wave; rows m_w+4k, k=0..12
  size_t Dg = (size_t)g * (N * N);
  int p = (int)((4 - ((Dg + (size_t)m_w * N) & 3)) & 3);
  const float* ar[13];
  int mrow[13];
#pragma unroll
  for (int r = 0; r < 13; r++) {
    int m = m_w + 4 * r;
    mrow[r] = m;
    int msafe = (m < N) ? m : m - 4;  // phase-preserving clamp
    ar[r] = ag + (size_t)msafe * N;
  }
  float acc[13];
#pragma unroll
  for (int r = 0; r < 13; r++) acc[r] = 0.f;
  const float* vrow = vs + lane * 207;
  for (int n = 0; n < p; n++) {
    float vv = vrow[n];
#pragma unroll
    for (int r = 0; r < 13; r++) acc[r] += vv * ar[r][n];
  }
  for (int n4 = 0; n4 < 51; n4++) {
    int n = p + n4 * 4;
    float v0 = vrow[n], v1 = vrow[n + 1], v2 = vrow[n + 2], v3 = vrow[n + 3];
#pragma unroll
    for (int r = 0; r < 13; r++) {
      float4 a = *(const float4*)(ar[r] + n);
      acc[r] += v0 * a.x;
      acc[r] += v1 * a.y;
      acc[r] += v2 * a.z;
      acc[r] += v3 * a.w;
    }
  }
  for (int n = p + 204; n < 207; n++) {
    float vv = vrow[n];
#pragma unroll
    for (int r = 0; r < 13; r++) acc[r] += vv * ar[r][n];
  }
#pragma unroll
  for (int r = 0; r < 13; r++) {
    int m = mrow[r];
    if (m < mend) Hg[(size_t)m * 64 + lane] += acc[r];
  }
}

// LayerNorm over c, in place. wave per position.
__global__ __launch_bounds__(256) void k_ln1(float* __restrict__ H,
                                             const float* __restrict__ w,
                                             const float* __restrict__ b, int l) {
  int pos = blockIdx.x * 4 + (threadIdx.x >> 6);
  int c = threadIdx.x & 63;
  float xv = H[(size_t)pos * 64 + c];
  float mean = wsum(xv) * (1.f / 64.f);
  float d = xv - mean;
  float var = wsum(d * d) * (1.f / 64.f);
  H[(size_t)pos * 64 + c] = d / sqrtf(var + 1e-5f) * w[l * 64 + c] + b[l * 64 + c];
}

// temporal MHA fused per (b,n); residual into H.
__global__ __launch_bounds__(256) void k_temporal(
    float* __restrict__ H, const float* __restrict__ qw,
    const float* __restrict__ qb, const float* __restrict__ kw,
    const float* __restrict__ kb, const float* __restrict__ vw,
    const float* __restrict__ vb, const float* __restrict__ ow,
    const float* __restrict__ ob, int l) {
  __shared__ float xs[24 * 66], qs[24 * 66], ks[24 * 66], vs[24 * 66];
  __shared__ float ss[96 * 25];
  __shared__ float wbuf[64 * 65];
  int bn = blockIdx.x;
  int b = bn / N, n = bn % N;
  size_t base = ((size_t)b * T * N + n) * 64;
  int lane = threadIdx.x & 63, tg = threadIdx.x >> 6;
  for (int t = tg; t < 24; t += 4) xs[t * 66 + lane] = H[base + (size_t)t * NC + lane];
  const float* Wm[4] = {qw + l * 4096, kw + l * 4096, vw + l * 4096, ow + l * 4096};
  const float* Bm[4] = {qb + l * 64, kb + l * 64, vb + l * 64, ob + l * 64};
  float* Dm[3] = {qs, ks, vs};
#pragma unroll
  for (int ph = 0; ph < 3; ph++) {
    for (int e = threadIdx.x; e < 4096; e += 256)
      wbuf[(e >> 6) * 65 + (e & 63)] = Wm[ph][e];
    __syncthreads();
    float acc[6];
    float bv = Bm[ph][lane];
#pragma unroll
    for (int i = 0; i < 6; i++) acc[i] = bv;
    for (int c = 0; c < 64; c++) {
      float wv = wbuf[lane * 65 + c];
#pragma unroll
      for (int i = 0; i < 6; i++) acc[i] += wv * xs[(tg * 6 + i) * 66 + c];
    }
    float* dst = Dm[ph];
#pragma unroll
    for (int i = 0; i < 6; i++) dst[(tg * 6 + i) * 66 + lane] = acc[i];
    __syncthreads();
  }
  // scores: 4 heads x 24 x 24
  for (int e = threadIdx.x; e < 2304; e += 256) {
    int u = e % 24, t = (e / 24) % 24, h = e / 576;
    float a = 0.f;
#pragma unroll
    for (int d = 0; d < 16; d++)
      a += qs[t * 66 + h * 16 + d] * ks[u * 66 + h * 16 + d];
    ss[(h * 24 + t) * 25 + u] = a * 0.25f;  // 1/sqrt(HD)
  }
  __syncthreads();
  if (threadIdx.x < 96) {
    float* row = ss + threadIdx.x * 25;
    float mx = -INFINITY;
#pragma unroll
    for (int u = 0; u < 24; u++) mx = fmaxf(mx, row[u]);
    float sum = 0.f;
#pragma unroll
    for (int u = 0; u < 24; u++) {
      float e2 = expf(row[u] - mx);
      row[u] = e2;
      sum += e2;
    }
    float inv = 1.f / sum;
#pragma unroll
    for (int u = 0; u < 24; u++) row[u] *= inv;
  }
  __syncthreads();
  // apply: att -> xs (xs dead after projections)
  for (int e = threadIdx.x; e < 1536; e += 256) {
    int t = e >> 6, c = e & 63, h = c >> 4;
    float a = 0.f;
#pragma unroll
    for (int u = 0; u < 24; u++) a += ss[(h * 24 + t) * 25 + u] * vs[u * 66 + c];
    xs[t * 66 + c] = a;
  }
  __syncthreads();
  // output projection + residual
  for (int e = threadIdx.x; e < 4096; e += 256)
    wbuf[(e >> 6) * 65 + (e & 63)] = Wm[3][e];
  __syncthreads();
  float acc[6];
  float bv = Bm[3][lane];
#pragma unroll
  for (int i = 0; i < 6; i++) acc[i] = bv;
  for (int cp = 0; cp < 64; cp++) {
    float wv = wbuf[lane * 65 + cp];
#pragma unroll
    for (int i = 0; i < 6; i++) acc[i] += wv * xs[(tg * 6 + i) * 66 + cp];
  }
#pragma unroll
  for (int i = 0; i < 6; i++)
    H[base + (size_t)(tg * 6 + i) * NC + lane] += acc[i];
}

// per-layer weight repack: w1t[c][j] = w1[l][j][c]; w2q4[jq*64+c] = w2[l][c][4jq..4jq+3]
__global__ __launch_bounds__(256) void k_transpose_ffn(
    const float* __restrict__ w1, const float* __restrict__ w2,
    float* __restrict__ w1t, float* __restrict__ w2q, int l) {
  int e = blockIdx.x * 256 + threadIdx.x;  // 0..32767
  if (e < 16384) {
    int c = e >> 8, j = e & 255;
    w1t[e] = w1[l * 16384 + j * 64 + c];
  } else {
    int m = e - 16384;
    int jq = m >> 8, c = (m & 255) >> 2, kk = m & 3;
    w2q[m] = w2[l * 16384 + c * 256 + jq * 4 + kk];
  }
}

// Fused LN2 + FFN1(relu) + FFN2 + residual; hid lives in LDS.
// w1t: [c][j] coalesced float4 streams; w2q: quad-packed [jq][c] float4.
__global__ __launch_bounds__(256) void k_ffn(
    float* __restrict__ H, const float* __restrict__ lnw,
    const float* __restrict__ lnb, const float* __restrict__ w1t,
    const float* __restrict__ b1, const float* __restrict__ w2q,
    const float* __restrict__ b2, int l) {
  __shared__ float xs[24 * 66];
  __shared__ float hids[24 * 260];  // row stride 260 (1040B, 16B-aligned)
  int bn = blockIdx.x;
  int b = bn / N, n = bn % N;
  size_t base = ((size_t)b * T * N + n) * 64;
  int lane = threadIdx.x & 63, tg = threadIdx.x >> 6;
  for (int t = tg; t < 24; t += 4) {
    float xv = H[base + (size_t)t * NC + lane];
    float mean = wsum(xv) * (1.f / 64.f);
    float d = xv - mean;
    float var = wsum(d * d) * (1.f / 64.f);
    xs[t * 66 + lane] = d / sqrtf(var + 1e-5f) * lnw[l * 64 + lane] + lnb[l * 64 + lane];
  }
  __syncthreads();
  // GEMM1: thread covers j-quad j0=lane*4 for 6 t's
  int j0 = lane * 4;
  float4 b4 = *(const float4*)(b1 + l * 256 + j0);
  float a0[6], a1[6], a2[6], a3[6];
#pragma unroll
  for (int i = 0; i < 6; i++) { a0[i] = b4.x; a1[i] = b4.y; a2[i] = b4.z; a3[i] = b4.w; }
  for (int c = 0; c < 64; c++) {
    float4 w4 = *(const float4*)(w1t + c * 256 + j0);
#pragma unroll
    for (int i = 0; i < 6; i++) {
      float xv = xs[(tg * 6 + i) * 66 + c];
      a0[i] += xv * w4.x;
      a1[i] += xv * w4.y;
      a2[i] += xv * w4.z;
      a3[i] += xv * w4.w;
    }
  }
#pragma unroll
  for (int i = 0; i < 6; i++) {
    int t = tg * 6 + i;
    float4 r = make_float4(fmaxf(a0[i], 0.f), fmaxf(a1[i], 0.f),
                           fmaxf(a2[i], 0.f), fmaxf(a3[i], 0.f));
    *(float4*)(&hids[t * 260 + j0]) = r;
  }
  __syncthreads();
  // GEMM2: thread covers c=lane for 6 t's; w2q4 coalesced, hids broadcast
  const float4* w2q4 = (const float4*)w2q;
  float acc[6];
#pragma unroll
  for (int i = 0; i < 6; i++) acc[i] = 0.f;
  for (int jq = 0; jq < 64; jq++) {
    float4 w = w2q4[jq * 64 + lane];
#pragma unroll
    for (int i = 0; i < 6; i++) {
      float4 hv = *(const float4*)(&hids[(tg * 6 + i) * 260 + jq * 4]);
      acc[i] += hv.x * w.x + hv.y * w.y + hv.z * w.z + hv.w * w.w;
    }
  }
  float bias = b2[l * 64 + lane];
#pragma unroll
  for (int i = 0; i < 6; i++) {
    int t = tg * 6 + i;
    H[base + (size_t)t * NC + lane] = xs[t * 66 + lane] + bias + acc[i];
  }
}

// GRU input projection: xp[t,bn,g] = bih + X . wih. 16 pairs per block.
__global__ __launch_bounds__(256) void k_gru_xp(
    const float* __restrict__ X, const float* __restrict__ wih,
    const float* __restrict__ bih, float* __restrict__ xp, int l) {
  __shared__ float ws_[192 * 65];
  __shared__ float xv[16 * 64];
  int p0 = blockIdx.x * 16;
  for (int e = threadIdx.x; e < 192 * 64; e += 256) {
    int gI = e >> 6, c = e & 63;
    ws_[gI * 65 + c] = wih[l * 12288 + e];
  }
  for (int e = threadIdx.x; e < 16 * 64; e += 256) {
    int s = e >> 6, c = e & 63;
    int p = p0 + s;
    int t = p / BN, bn = p % BN;
    float val;
    if (l == 0) {
      int b = bn / N, n = bn % N;
      val = X[(((size_t)b * T + t) * N + n) * 64 + c];
    } else {
      val = X[(size_t)p * 64 + c];  // seq1[t,bn,c]
    }
    xv[e] = val;
  }
  __syncthreads();
  for (int e = threadIdx.x; e < 16 * 192; e += 256) {
    int s = e / 192, gI = e % 192;
    float acc = bih[l * 192 + gI];
#pragma unroll
    for (int c = 0; c < 64; c++) acc += xv[s * 64 + c] * ws_[gI * 65 + c];
    xp[((size_t)(p0 + s)) * 192 + gI] = acc;
  }
}

// GRU recurrence: 8 samples/block; waves 0-2 hold gate weights in registers.
__global__ __launch_bounds__(256) void k_gru_scan(
    const float* __restrict__ xp, const float* __restrict__ whh,
    const float* __restrict__ bhh, float* __restrict__ seq_out, int l) {
  constexpr int S = 8;
  __shared__ float hprev[S][64];
  __shared__ float hg[3][S][64];
  __shared__ float xpbuf[2][S * 192];
  int bn0 = blockIdx.x * S;
  int lane = threadIdx.x & 63;
  int wv = threadIdx.x >> 6;

  float4 w4[16];
  if (wv < 3) {
    const float* wr = whh + l * 12288 + (wv * 64 + lane) * 64;
#pragma unroll
    for (int j = 0; j < 16; j++) w4[j] = *(const float4*)(wr + j * 4);
  }
  float b_r = bhh[l * 192 + lane];
  float b_z = bhh[l * 192 + 64 + lane];
  float b_n = bhh[l * 192 + 128 + lane];

  for (int e = threadIdx.x; e < S * 64; e += 256) ((float*)hprev)[e] = 0.f;
  {
    const float* src = xp + (size_t)bn0 * 192;
    for (int e = threadIdx.x; e < S * 192; e += 256) xpbuf[0][e] = src[e];
  }
  __syncthreads();

  for (int t = 0; t < T; t++) {
    int cur = t & 1;
    if (wv < 3) {
      float acc[S];
#pragma unroll
      for (int s = 0; s < S; s++) acc[s] = 0.f;
#pragma unroll
      for (int j = 0; j < 16; j++) {
        float4 w = w4[j];
#pragma unroll
        for (int s = 0; s < S; s++) {
          float4 hb = *(const float4*)(&hprev[s][j * 4]);
          acc[s] += w.x * hb.x + w.y * hb.y + w.z * hb.z + w.w * hb.w;
        }
      }
#pragma unroll
      for (int s = 0; s < S; s++) hg[wv][s][lane] = acc[s];
    } else {
      if (t + 1 < T) {
        const float* src = xp + ((size_t)(t + 1) * BN + bn0) * 192;
        float* dst = xpbuf[(t + 1) & 1];
        for (int e = lane * 4; e < S * 192; e += 256) {
          *(float4*)(dst + e) = *(const float4*)(src + e);
        }
      }
    }
    __syncthreads();
#pragma unroll
    for (int ii = 0; ii < 2; ii++) {
      int s = wv + 4 * ii;
      const float* xr = &xpbuf[cur][s * 192];
      float r = 1.f / (1.f + expf(-(xr[lane] + hg[0][s][lane] + b_r)));
      float z = 1.f / (1.f + expf(-(xr[64 + lane] + hg[1][s][lane] + b_z)));
      float nn = tanhf(xr[128 + lane] + r * (hg[2][s][lane] + b_n));
      float hp = hprev[s][lane];
      float hnew = (1.f - z) * nn + z * hp;
      hprev[s][lane] = hnew;
      seq_out[((size_t)t * BN + bn0 + s) * 64 + lane] = hnew;
    }
    __syncthreads();
  }
}

// prediction head: one block per bn.
__global__ __launch_bounds__(256) void k_pred(
    const float* __restrict__ seq2, const float* __restrict__ pw,
    const float* __restrict__ pb, float* __restrict__ out) {
  __shared__ float s_[1536];
  int bn = blockIdx.x;
  int b = bn / N, n = bn % N;
  for (int e = threadIdx.x; e < 1536; e += 256) {
    int t = e >> 6, c = e & 63;
    s_[c * 24 + t] = seq2[((size_t)t * BN + bn) * 64 + c];
  }
  __syncthreads();
  int wave = threadIdx.x >> 6, lane = threadIdx.x & 63;
  for (int hor = wave; hor < 12; hor += 4) {
    const float* w = pw + hor * 1536;
    float acc = 0.f;
#pragma unroll 4
    for (int kk = lane; kk < 1536; kk += 64) acc += s_[kk] * w[kk];
    acc = wsum(acc);
    if (lane == 0) out[(size_t)b * (HOR * N) + hor * N + n] = acc + pb[hor];
  }
}

}  // namespace

extern "C" void kernel_launch(void* const* d_in, const int* in_sizes, int n_in,
                              void* d_out, int out_size, void* d_ws, size_t ws_size,
                              hipStream_t stream) {
  const float* x       = (const float*)d_in[0];
  const float* adj     = (const float*)d_in[1];
  const float* nodee   = (const float*)d_in[2];
  const float* hour_w  = (const float*)d_in[3];
  const float* hour_b  = (const float*)d_in[4];
  const float* day_w   = (const float*)d_in[5];
  const float* day_b   = (const float*)d_in[6];
  const float* wk_w    = (const float*)d_in[7];
  const float* wk_b    = (const float*)d_in[8];
  const float* in_w    = (const float*)d_in[9];
  const float* in_b    = (const float*)d_in[10];
  const float* sa_qw   = (const float*)d_in[11];
  const float* sa_qb   = (const float*)d_in[12];
  const float* sa_kw   = (const float*)d_in[13];
  const float* sa_kb   = (const float*)d_in[14];
  const float* sa_vw   = (const float*)d_in[15];
  const float* sa_vb   = (const float*)d_in[16];
  const float* ta_qw   = (const float*)d_in[17];
  const float* ta_qb   = (const float*)d_in[18];
  const float* ta_kw   = (const float*)d_in[19];
  const float* ta_kb   = (const float*)d_in[20];
  const float* ta_vw   = (const float*)d_in[21];
  const float* ta_vb   = (const float*)d_in[22];
  const float* ta_ow   = (const float*)d_in[23];
  const float* ta_ob   = (const float*)d_in[24];
  const float* ln1_w   = (const float*)d_in[25];
  const float* ln1_b   = (const float*)d_in[26];
  const float* ln2_w   = (const float*)d_in[27];
  const float* ln2_b   = (const float*)d_in[28];
  const float* ffn_w1  = (const float*)d_in[29];
  const float* ffn_b1  = (const float*)d_in[30];
  const float* ffn_w2  = (const float*)d_in[31];
  const float* ffn_b2  = (const float*)d_in[32];
  const float* gru_wih = (const float*)d_in[33];
  const float* gru_whh = (const float*)d_in[34];
  const float* gru_bih = (const float*)d_in[35];
  const float* gru_bhh = (const float*)d_in[36];
  const float* pred_w  = (const float*)d_in[37];
  const float* pred_b  = (const float*)d_in[38];

  if (ws_size < WS_FLOATS * sizeof(float)) return;  // loud failure: output stays poisoned

  float* ws   = (float*)d_ws;
  float* H    = ws + H_OFF;
  float* bufA = ws + A_OFF;   // seq1
  float* q    = ws + Q_OFF;   // q during spatial stage; w1t during FFN stage
  float* k    = ws + K_OFF;   // k during spatial stage; w2q during FFN stage
  float* bufB = ws + B_OFF;   // v | xp

  float* out       = (float*)d_out;
  float* attn_base = out + (size_t)B * HOR * N;  // 39744 (16B aligned)

  float* v   = bufB;
  float* xp  = bufB;
  float* w1t = q;
  float* w2q = k;

  k_embed<<<P / 4, 256, 0, stream>>>(x, nodee, hour_w, hour_b, day_w, day_b,
                                     wk_w, wk_b, in_w, in_b, H);

  for (int l = 0; l < 3; l++) {
    float* attn_l = attn_base + (size_t)l * BT * N * N;
    k_spatial_qkv<<<BT, 256, 0, stream>>>(H, sa_qw, sa_qb, sa_kw, sa_kb, sa_vw,
                                          sa_vb, q, k, v, l);
    k_spatial_attn<<<BT, 256, 0, stream>>>(q, k, adj, attn_l);
    k_spatial_apply<<<dim3(BT, 4), 256, 0, stream>>>(v, attn_l, H);
    k_ln1<<<P / 4, 256, 0, stream>>>(H, ln1_w, ln1_b, l);
    k_temporal<<<BN, 256, 0, stream>>>(H, ta_qw, ta_qb, ta_kw, ta_kb, ta_vw,
                                       ta_vb, ta_ow, ta_ob, l);
    k_transpose_ffn<<<128, 256, 0, stream>>>(ffn_w1, ffn_w2, w1t, w2q, l);
    k_ffn<<<BN, 256, 0, stream>>>(H, ln2_w, ln2_b, w1t, ffn_b1, w2q, ffn_b2, l);
  }

  k_gru_xp<<<P / 16, 256, 0, stream>>>(H, gru_wih, gru_bih, xp, 0);
  k_gru_scan<<<BN / 8, 256, 0, stream>>>(xp, gru_whh, gru_bhh, bufA, 0);
  k_gru_xp<<<P / 16, 256, 0, stream>>>(bufA, gru_wih, gru_bih, xp, 1);
  k_gru_scan<<<BN / 8, 256, 0, stream>>>(xp, gru_whh, gru_bhh, H, 1);

  k_pred<<<BN, 256, 0, stream>>>(H, pred_w, pred_b, out);
}

// Round 6
// 2276.588 us; speedup vs baseline: 2.8516x; 1.0531x over previous
//
#include <hip/hip_runtime.h>
#include <math.h>

namespace {

constexpr int B = 16, T = 24, N = 207, C = 64, HOR = 12;
constexpr int BT = B * T;          // 384
constexpr int BN = B * N;          // 3312
constexpr int P = B * T * N;       // 79488
constexpr int NC = N * C;          // 13248

// ws layout (floats)
constexpr size_t H_OFF = 0;                         // P*C = 5,087,232
constexpr size_t A_OFF = 5087232;                   // bufA: seq1 / taq pack
constexpr size_t Q_OFF = A_OFF + 5087232;           // q: 635,904 (reused as w1t)
constexpr size_t K_OFF = Q_OFF + 635904;            // k: 635,904 (reused as w2q)
constexpr size_t B_OFF = K_OFF + 635904;            // bufB: 20,348,928 (v / xp)
constexpr size_t WS_FLOATS = B_OFF + 20348928;      // 31,795,200

__device__ __forceinline__ float wsum(float v) {
#pragma unroll
  for (int off = 32; off; off >>= 1) v += __shfl_xor(v, off);
  return v;
}
__device__ __forceinline__ float wmax(float v) {
#pragma unroll
  for (int off = 32; off; off >>= 1) v = fmaxf(v, __shfl_xor(v, off));
  return v;
}

// H[b,t,n,c] layout. One block = 4 positions, 64 lanes = channels.
__global__ __launch_bounds__(256) void k_embed(
    const float* __restrict__ x, const float* __restrict__ nodee,
    const float* __restrict__ hw, const float* __restrict__ hb,
    const float* __restrict__ dw, const float* __restrict__ db,
    const float* __restrict__ ww, const float* __restrict__ wb,
    const float* __restrict__ inw, const float* __restrict__ inb,
    float* __restrict__ H) {
  int pos = blockIdx.x * 4 + (threadIdx.x >> 6);
  int c = threadIdx.x & 63;
  int n = pos % N;
  int t = (pos / N) % T;
  const float* xv = x + (size_t)pos * 4;
  float flow = xv[0], hour = xv[1], wkend = xv[2], day = xv[3];
  const float* w = inw + c * 65;
  float acc = inb[c] + w[0] * flow;
#pragma unroll
  for (int e = 0; e < 16; e++) {
    acc += w[1 + e] * nodee[n * 16 + e];
    acc += w[17 + e] * (hour * hw[e] + hb[e]);
    acc += w[33 + e] * (day * dw[e] + db[e]);
    acc += w[49 + e] * (wkend * ww[e] + wb[e]);
  }
  int i = c >> 1;
  float dv = expf((float)(2 * i) * (-9.210340371976184f / 64.0f));
  float ang = (float)t * dv;
  acc += (c & 1) ? cosf(ang) : sinf(ang);
  H[(size_t)pos * 64 + c] = acc;
}

// one block per g=(b,t). q,k: (B,8,T,N) flat; v: (B,64,T,N) flat.
__global__ __launch_bounds__(256) void k_spatial_qkv(
    const float* __restrict__ H, const float* __restrict__ qw,
    const float* __restrict__ qb, const float* __restrict__ kw,
    const float* __restrict__ kb, const float* __restrict__ vw,
    const float* __restrict__ vb, float* __restrict__ q, float* __restrict__ k,
    float* __restrict__ v, int l) {
  __shared__ float hs[N * 65];  // padded
  int g = blockIdx.x;
  int b = g / T, t = g % T;
  const float* Hbt = H + (size_t)g * NC;
  for (int e = threadIdx.x; e < NC; e += 256) {
    int n = e >> 6, c = e & 63;
    hs[n * 65 + c] = Hbt[e];
  }
  __syncthreads();
  qw += l * 8 * 64; qb += l * 8;
  kw += l * 8 * 64; kb += l * 8;
  vw += l * 64 * 64; vb += l * 64;
  for (int e = threadIdx.x; e < 16 * N; e += 256) {
    int o = e / N, n = e % N;
    int oo = o & 7;
    const float* W = (o < 8 ? qw : kw) + oo * 64;
    float acc = (o < 8 ? qb : kb)[oo];
#pragma unroll
    for (int c = 0; c < 64; c++) acc += W[c] * hs[n * 65 + c];
    size_t oidx = ((size_t)(b * 8 + oo) * T + t) * N + n;
    if (o < 8) q[oidx] = acc; else k[oidx] = acc;
  }
  for (int e = threadIdx.x; e < 64 * N; e += 256) {
    int o = e / N, n = e % N;
    const float* W = vw + o * 64;
    float acc = vb[o];
#pragma unroll
    for (int c = 0; c < 64; c++) acc += W[c] * hs[n * 65 + c];
    v[((size_t)(b * 64 + o) * T + t) * N + n] = acc;
  }
}

// one block per g. Double softmax with adjacency mask; writes attn to d_out slab.
__global__ __launch_bounds__(256) void k_spatial_attn(
    const float* __restrict__ q, const float* __restrict__ k,
    const float* __restrict__ adj, float* __restrict__ attn_out) {
  __shared__ float qs[8 * 208], ks[8 * 208];
  int g = blockIdx.x;
  const float* qg = q + (size_t)g * 1656;
  const float* kg = k + (size_t)g * 1656;
  for (int e = threadIdx.x; e < 1656; e += 256) {
    int c2 = e / N, n = e % N;
    qs[c2 * 208 + n] = qg[e];
    ks[c2 * 208 + n] = kg[e];
  }
  __syncthreads();
  int wave = threadIdx.x >> 6, lane = threadIdx.x & 63;
  for (int n = wave; n < N; n += 4) {
    float s[4];
    float mx = -INFINITY;
#pragma unroll
    for (int j = 0; j < 4; j++) {
      int m = lane + 64 * j;
      float acc = -INFINITY;
      if (m < N) {
        acc = 0.f;
#pragma unroll
        for (int c2 = 0; c2 < 8; c2++) acc += qs[c2 * 208 + n] * ks[c2 * 208 + m];
        acc *= 0.125f;  // 1/sqrt(C)
      }
      s[j] = acc;
      mx = fmaxf(mx, acc);
    }
    mx = wmax(mx);
    float sum = 0.f;
#pragma unroll
    for (int j = 0; j < 4; j++) {
      int m = lane + 64 * j;
      float e = (m < N) ? expf(s[j] - mx) : 0.f;
      s[j] = e;
      sum += e;
    }
    sum = wsum(sum);
    float inv = 1.f / sum;
    // second softmax over masked probabilities
    float mx2 = -INFINITY;
    bool ok[4];
#pragma unroll
    for (int j = 0; j < 4; j++) {
      int m = lane + 64 * j;
      float p = s[j] * inv;
      bool valid = (m < N) && (adj[n * N + m] != 0.0f);
      ok[j] = valid;
      s[j] = p;
      if (valid) mx2 = fmaxf(mx2, p);
    }
    mx2 = wmax(mx2);
    float sum2 = 0.f;
#pragma unroll
    for (int j = 0; j < 4; j++) {
      float e = ok[j] ? expf(s[j] - mx2) : 0.f;
      s[j] = e;
      sum2 += e;
    }
    sum2 = wsum(sum2);
    float inv2 = 1.f / sum2;
    float* orow = attn_out + ((size_t)g * N + n) * N;
#pragma unroll
    for (int j = 0; j < 4; j++) {
      int m = lane + 64 * j;
      if (m < N) orow[m] = s[j] * inv2;
    }
  }
}

// sp = v2 @ attn^T, residual into H. grid (g, m-chunk). 13-row register
// blocking per wave; rows stride-4 so all 13 share the same float4 phase.
__global__ __launch_bounds__(256, 3) void k_spatial_apply(
    const float* __restrict__ v, const float* __restrict__ attn,
    float* __restrict__ H) {
  __shared__ float vs[64 * 207];
  int g = blockIdx.x;
  int ms = blockIdx.y;  // 0..3
  const float* vg = v + (size_t)g * NC;
  for (int e = threadIdx.x; e < NC; e += 256) vs[e] = vg[e];  // vs[c*207+n]
  __syncthreads();
  int wave = threadIdx.x >> 6, lane = threadIdx.x & 63;
  const float* ag = attn + (size_t)g * (N * N);
  float* Hg = H + (size_t)g * NC;
  int mbeg = ms * 52;
  int mend = min(mbeg + 52, N);
  int m_w = mbeg + wave;  // first row of this wave; rows m_w+4k, k=0..12
  size_t Dg = (size_t)g * (N * N);
  int p = (int)((4 - ((Dg + (size_t)m_w * N) & 3)) & 3);
  const float* ar[13];
  int mrow[13];
#pragma unroll
  for (int r = 0; r < 13; r++) {
    int m = m_w + 4 * r;
    mrow[r] = m;
    int msafe = (m < N) ? m : m - 4;  // phase-preserving clamp
    ar[r] = ag + (size_t)msafe * N;
  }
  float acc[13];
#pragma unroll
  for (int r = 0; r < 13; r++) acc[r] = 0.f;
  const float* vrow = vs + lane * 207;
  for (int n = 0; n < p; n++) {
    float vv = vrow[n];
#pragma unroll
    for (int r = 0; r < 13; r++) acc[r] += vv * ar[r][n];
  }
  for (int n4 = 0; n4 < 51; n4++) {
    int n = p + n4 * 4;
    float v0 = vrow[n], v1 = vrow[n + 1], v2 = vrow[n + 2], v3 = vrow[n + 3];
#pragma unroll
    for (int r = 0; r < 13; r++) {
      float4 a = *(const float4*)(ar[r] + n);
      acc[r] += v0 * a.x;
      acc[r] += v1 * a.y;
      acc[r] += v2 * a.z;
      acc[r] += v3 * a.w;
    }
  }
  for (int n = p + 204; n < 207; n++) {
    float vv = vrow[n];
#pragma unroll
    for (int r = 0; r < 13; r++) acc[r] += vv * ar[r][n];
  }
#pragma unroll
  for (int r = 0; r < 13; r++) {
    int m = mrow[r];
    if (m < mend) Hg[(size_t)m * 64 + lane] += acc[r];
  }
}

// temporal MHA fused per (b,n), LN1 fused at load; residual into H.
// Weights pre-quad-packed in taq (global, L1/L2-hot): taq4[ph*1024+cq*64+o].
__global__ __launch_bounds__(256) void k_temporal(
    float* __restrict__ H, const float* __restrict__ taq,
    const float* __restrict__ qb, const float* __restrict__ kb,
    const float* __restrict__ vb, const float* __restrict__ ob,
    const float* __restrict__ lnw, const float* __restrict__ lnb, int l) {
  __shared__ float xs[24 * 68], qs[24 * 68], ks[24 * 68], vs[24 * 68];
  __shared__ float ss[96 * 25];
  int bn = blockIdx.x;
  int b = bn / N, n = bn % N;
  size_t base = ((size_t)b * T * N + n) * 64;
  int lane = threadIdx.x & 63, tg = threadIdx.x >> 6;
  // load + LN1 (h = LN1(h + sp)): xs holds hl
  float lw = lnw[l * 64 + lane], lb = lnb[l * 64 + lane];
  for (int t = tg; t < 24; t += 4) {
    float xv = H[base + (size_t)t * NC + lane];
    float mean = wsum(xv) * (1.f / 64.f);
    float d = xv - mean;
    float var = wsum(d * d) * (1.f / 64.f);
    xs[t * 68 + lane] = d / sqrtf(var + 1e-5f) * lw + lb;
  }
  __syncthreads();
  const float4* wq_all = (const float4*)taq;
  const float* Bm[3] = {qb + l * 64, kb + l * 64, vb + l * 64};
  float* Dm[3] = {qs, ks, vs};
#pragma unroll
  for (int ph = 0; ph < 3; ph++) {
    const float4* wq = wq_all + ph * 1024;
    float acc[6];
    float bv = Bm[ph][lane];
#pragma unroll
    for (int i = 0; i < 6; i++) acc[i] = bv;
#pragma unroll 4
    for (int cq = 0; cq < 16; cq++) {
      float4 w = wq[cq * 64 + lane];
#pragma unroll
      for (int i = 0; i < 6; i++) {
        float4 xv = *(const float4*)(&xs[(tg * 6 + i) * 68 + cq * 4]);
        acc[i] += xv.x * w.x + xv.y * w.y + xv.z * w.z + xv.w * w.w;
      }
    }
    float* dst = Dm[ph];
#pragma unroll
    for (int i = 0; i < 6; i++) dst[(tg * 6 + i) * 68 + lane] = acc[i];
  }
  __syncthreads();
  // scores: 4 heads x 24 x 24 (float4 fragments)
  for (int e = threadIdx.x; e < 2304; e += 256) {
    int u = e % 24, t = (e / 24) % 24, h = e / 576;
    float a = 0.f;
#pragma unroll
    for (int dq = 0; dq < 4; dq++) {
      float4 qv = *(const float4*)(&qs[t * 68 + h * 16 + dq * 4]);
      float4 kv = *(const float4*)(&ks[u * 68 + h * 16 + dq * 4]);
      a += qv.x * kv.x + qv.y * kv.y + qv.z * kv.z + qv.w * kv.w;
    }
    ss[(h * 24 + t) * 25 + u] = a * 0.25f;  // 1/sqrt(HD)
  }
  __syncthreads();
  if (threadIdx.x < 96) {
    float* row = ss + threadIdx.x * 25;
    float mx = -INFINITY;
#pragma unroll
    for (int u = 0; u < 24; u++) mx = fmaxf(mx, row[u]);
    float sum = 0.f;
#pragma unroll
    for (int u = 0; u < 24; u++) {
      float e2 = expf(row[u] - mx);
      row[u] = e2;
      sum += e2;
    }
    float inv = 1.f / sum;
#pragma unroll
    for (int u = 0; u < 24; u++) row[u] *= inv;
  }
  __syncthreads();
  // apply: att -> qs (qs dead after scores)
  {
    int h = lane >> 4;
    float acc2[6];
#pragma unroll
    for (int i = 0; i < 6; i++) acc2[i] = 0.f;
    for (int u = 0; u < 24; u++) {
      float vsv = vs[u * 68 + lane];
#pragma unroll
      for (int i = 0; i < 6; i++)
        acc2[i] += ss[(h * 24 + (tg * 6 + i)) * 25 + u] * vsv;
    }
#pragma unroll
    for (int i = 0; i < 6; i++) qs[(tg * 6 + i) * 68 + lane] = acc2[i];
  }
  __syncthreads();
  // output projection + residual
  {
    const float4* wo = wq_all + 3 * 1024;
    float acc[6];
    float bv = ob[l * 64 + lane];
#pragma unroll
    for (int i = 0; i < 6; i++) acc[i] = bv;
#pragma unroll 4
    for (int cq = 0; cq < 16; cq++) {
      float4 w = wo[cq * 64 + lane];
#pragma unroll
      for (int i = 0; i < 6; i++) {
        float4 xv = *(const float4*)(&qs[(tg * 6 + i) * 68 + cq * 4]);
        acc[i] += xv.x * w.x + xv.y * w.y + xv.z * w.z + xv.w * w.w;
      }
    }
#pragma unroll
    for (int i = 0; i < 6; i++)
      H[base + (size_t)(tg * 6 + i) * NC + lane] =
          xs[(tg * 6 + i) * 68 + lane] + acc[i];
  }
}

// per-layer weight repack: w1t[c][j]=w1[j][c]; w2q quad-pack; taq quad-pack x4.
__global__ __launch_bounds__(256) void k_pack(
    const float* __restrict__ w1, const float* __restrict__ w2,
    const float* __restrict__ tqw, const float* __restrict__ tkw,
    const float* __restrict__ tvw, const float* __restrict__ tow,
    float* __restrict__ w1t, float* __restrict__ w2q, float* __restrict__ taq,
    int l) {
  int e = blockIdx.x * 256 + threadIdx.x;  // 0..49151
  if (e < 16384) {
    int c = e >> 8, j = e & 255;
    w1t[e] = w1[l * 16384 + j * 64 + c];
  } else if (e < 32768) {
    int m = e - 16384;
    int jq = m >> 8, c = (m & 255) >> 2, kk = m & 3;
    w2q[m] = w2[l * 16384 + c * 256 + jq * 4 + kk];
  } else {
    int m2 = e - 32768;  // 0..16383
    int ph = m2 >> 12;
    int m = m2 & 4095;   // = cq*256 + o*4 + j
    int cq = m >> 8, o = (m & 255) >> 2, j = m & 3;
    const float* src =
        (ph == 0 ? tqw : ph == 1 ? tkw : ph == 2 ? tvw : tow) + l * 4096;
    taq[ph * 4096 + m] = src[o * 64 + 4 * cq + j];
  }
}

// Fused LN2 + FFN1(relu) + FFN2 + residual; hid lives in LDS.
// w1t: [c][j] coalesced float4 streams; w2q: quad-packed [jq][c] float4.
__global__ __launch_bounds__(256) void k_ffn(
    float* __restrict__ H, const float* __restrict__ lnw,
    const float* __restrict__ lnb, const float* __restrict__ w1t,
    const float* __restrict__ b1, const float* __restrict__ w2q,
    const float* __restrict__ b2, int l) {
  __shared__ float xs[24 * 66];
  __shared__ float hids[24 * 260];  // row stride 260 (1040B, 16B-aligned)
  int bn = blockIdx.x;
  int b = bn / N, n = bn % N;
  size_t base = ((size_t)b * T * N + n) * 64;
  int lane = threadIdx.x & 63, tg = threadIdx.x >> 6;
  for (int t = tg; t < 24; t += 4) {
    float xv = H[base + (size_t)t * NC + lane];
    float mean = wsum(xv) * (1.f / 64.f);
    float d = xv - mean;
    float var = wsum(d * d) * (1.f / 64.f);
    xs[t * 66 + lane] = d / sqrtf(var + 1e-5f) * lnw[l * 64 + lane] + lnb[l * 64 + lane];
  }
  __syncthreads();
  // GEMM1: thread covers j-quad j0=lane*4 for 6 t's
  int j0 = lane * 4;
  float4 b4 = *(const float4*)(b1 + l * 256 + j0);
  float a0[6], a1[6], a2[6], a3[6];
#pragma unroll
  for (int i = 0; i < 6; i++) { a0[i] = b4.x; a1[i] = b4.y; a2[i] = b4.z; a3[i] = b4.w; }
  for (int c = 0; c < 64; c++) {
    float4 w4 = *(const float4*)(w1t + c * 256 + j0);
#pragma unroll
    for (int i = 0; i < 6; i++) {
      float xv = xs[(tg * 6 + i) * 66 + c];
      a0[i] += xv * w4.x;
      a1[i] += xv * w4.y;
      a2[i] += xv * w4.z;
      a3[i] += xv * w4.w;
    }
  }
#pragma unroll
  for (int i = 0; i < 6; i++) {
    int t = tg * 6 + i;
    float4 r = make_float4(fmaxf(a0[i], 0.f), fmaxf(a1[i], 0.f),
                           fmaxf(a2[i], 0.f), fmaxf(a3[i], 0.f));
    *(float4*)(&hids[t * 260 + j0]) = r;
  }
  __syncthreads();
  // GEMM2: thread covers c=lane for 6 t's; w2q4 coalesced, hids broadcast
  const float4* w2q4 = (const float4*)w2q;
  float acc[6];
#pragma unroll
  for (int i = 0; i < 6; i++) acc[i] = 0.f;
  for (int jq = 0; jq < 64; jq++) {
    float4 w = w2q4[jq * 64 + lane];
#pragma unroll
    for (int i = 0; i < 6; i++) {
      float4 hv = *(const float4*)(&hids[(tg * 6 + i) * 260 + jq * 4]);
      acc[i] += hv.x * w.x + hv.y * w.y + hv.z * w.z + hv.w * w.w;
    }
  }
  float bias = b2[l * 64 + lane];
#pragma unroll
  for (int i = 0; i < 6; i++) {
    int t = tg * 6 + i;
    H[base + (size_t)t * NC + lane] = xs[t * 66 + lane] + bias + acc[i];
  }
}

// GRU input projection: xp[t,bn,g] = bih + X . wih. 16 pairs per block.
__global__ __launch_bounds__(256) void k_gru_xp(
    const float* __restrict__ X, const float* __restrict__ wih,
    const float* __restrict__ bih, float* __restrict__ xp, int l) {
  __shared__ float ws_[192 * 65];
  __shared__ float xv[16 * 64];
  int p0 = blockIdx.x * 16;
  for (int e = threadIdx.x; e < 192 * 64; e += 256) {
    int gI = e >> 6, c = e & 63;
    ws_[gI * 65 + c] = wih[l * 12288 + e];
  }
  for (int e = threadIdx.x; e < 16 * 64; e += 256) {
    int s = e >> 6, c = e & 63;
    int p = p0 + s;
    int t = p / BN, bn = p % BN;
    float val;
    if (l == 0) {
      int b = bn / N, n = bn % N;
      val = X[(((size_t)b * T + t) * N + n) * 64 + c];
    } else {
      val = X[(size_t)p * 64 + c];  // seq1[t,bn,c]
    }
    xv[e] = val;
  }
  __syncthreads();
  for (int e = threadIdx.x; e < 16 * 192; e += 256) {
    int s = e / 192, gI = e % 192;
    float acc = bih[l * 192 + gI];
#pragma unroll
    for (int c = 0; c < 64; c++) acc += xv[s * 64 + c] * ws_[gI * 65 + c];
    xp[((size_t)(p0 + s)) * 192 + gI] = acc;
  }
}

// GRU recurrence: 8 samples/block; waves 0-2 hold gate weights in registers.
__global__ __launch_bounds__(256) void k_gru_scan(
    const float* __restrict__ xp, const float* __restrict__ whh,
    const float* __restrict__ bhh, float* __restrict__ seq_out, int l) {
  constexpr int S = 8;
  __shared__ float hprev[S][64];
  __shared__ float hg[3][S][64];
  __shared__ float xpbuf[2][S * 192];
  int bn0 = blockIdx.x * S;
  int lane = threadIdx.x & 63;
  int wv = threadIdx.x >> 6;

  float4 w4[16];
  if (wv < 3) {
    const float* wr = whh + l * 12288 + (wv * 64 + lane) * 64;
#pragma unroll
    for (int j = 0; j < 16; j++) w4[j] = *(const float4*)(wr + j * 4);
  }
  float b_r = bhh[l * 192 + lane];
  float b_z = bhh[l * 192 + 64 + lane];
  float b_n = bhh[l * 192 + 128 + lane];

  for (int e = threadIdx.x; e < S * 64; e += 256) ((float*)hprev)[e] = 0.f;
  {
    const float* src = xp + (size_t)bn0 * 192;
    for (int e = threadIdx.x; e < S * 192; e += 256) xpbuf[0][e] = src[e];
  }
  __syncthreads();

  for (int t = 0; t < T; t++) {
    int cur = t & 1;
    if (wv < 3) {
      float acc[S];
#pragma unroll
      for (int s = 0; s < S; s++) acc[s] = 0.f;
#pragma unroll
      for (int j = 0; j < 16; j++) {
        float4 w = w4[j];
#pragma unroll
        for (int s = 0; s < S; s++) {
          float4 hb = *(const float4*)(&hprev[s][j * 4]);
          acc[s] += w.x * hb.x + w.y * hb.y + w.z * hb.z + w.w * hb.w;
        }
      }
#pragma unroll
      for (int s = 0; s < S; s++) hg[wv][s][lane] = acc[s];
    } else {
      if (t + 1 < T) {
        const float* src = xp + ((size_t)(t + 1) * BN + bn0) * 192;
        float* dst = xpbuf[(t + 1) & 1];
        for (int e = lane * 4; e < S * 192; e += 256) {
          *(float4*)(dst + e) = *(const float4*)(src + e);
        }
      }
    }
    __syncthreads();
#pragma unroll
    for (int ii = 0; ii < 2; ii++) {
      int s = wv + 4 * ii;
      const float* xr = &xpbuf[cur][s * 192];
      float r = 1.f / (1.f + expf(-(xr[lane] + hg[0][s][lane] + b_r)));
      float z = 1.f / (1.f + expf(-(xr[64 + lane] + hg[1][s][lane] + b_z)));
      float nn = tanhf(xr[128 + lane] + r * (hg[2][s][lane] + b_n));
      float hp = hprev[s][lane];
      float hnew = (1.f - z) * nn + z * hp;
      hprev[s][lane] = hnew;
      seq_out[((size_t)t * BN + bn0 + s) * 64 + lane] = hnew;
    }
    __syncthreads();
  }
}

// prediction head: one block per bn.
__global__ __launch_bounds__(256) void k_pred(
    const float* __restrict__ seq2, const float* __restrict__ pw,
    const float* __restrict__ pb, float* __restrict__ out) {
  __shared__ float s_[1536];
  int bn = blockIdx.x;
  int b = bn / N, n = bn % N;
  for (int e = threadIdx.x; e < 1536; e += 256) {
    int t = e >> 6, c = e & 63;
    s_[c * 24 + t] = seq2[((size_t)t * BN + bn) * 64 + c];
  }
  __syncthreads();
  int wave = threadIdx.x >> 6, lane = threadIdx.x & 63;
  for (int hor = wave; hor < 12; hor += 4) {
    const float* w = pw + hor * 1536;
    float acc = 0.f;
#pragma unroll 4
    for (int kk = lane; kk < 1536; kk += 64) acc += s_[kk] * w[kk];
    acc = wsum(acc);
    if (lane == 0) out[(size_t)b * (HOR * N) + hor * N + n] = acc + pb[hor];
  }
}

}  // namespace

extern "C" void kernel_launch(void* const* d_in, const int* in_sizes, int n_in,
                              void* d_out, int out_size, void* d_ws, size_t ws_size,
                              hipStream_t stream) {
  const float* x       = (const float*)d_in[0];
  const float* adj     = (const float*)d_in[1];
  const float* nodee   = (const float*)d_in[2];
  const float* hour_w  = (const float*)d_in[3];
  const float* hour_b  = (const float*)d_in[4];
  const float* day_w   = (const float*)d_in[5];
  const float* day_b   = (const float*)d_in[6];
  const float* wk_w    = (const float*)d_in[7];
  const float* wk_b    = (const float*)d_in[8];
  const float* in_w    = (const float*)d_in[9];
  const float* in_b    = (const float*)d_in[10];
  const float* sa_qw   = (const float*)d_in[11];
  const float* sa_qb   = (const float*)d_in[12];
  const float* sa_kw   = (const float*)d_in[13];
  const float* sa_kb   = (const float*)d_in[14];
  const float* sa_vw   = (const float*)d_in[15];
  const float* sa_vb   = (const float*)d_in[16];
  const float* ta_qw   = (const float*)d_in[17];
  const float* ta_qb   = (const float*)d_in[18];
  const float* ta_kw   = (const float*)d_in[19];
  const float* ta_kb   = (const float*)d_in[20];
  const float* ta_vw   = (const float*)d_in[21];
  const float* ta_vb   = (const float*)d_in[22];
  const float* ta_ow   = (const float*)d_in[23];
  const float* ta_ob   = (const float*)d_in[24];
  const float* ln1_w   = (const float*)d_in[25];
  const float* ln1_b   = (const float*)d_in[26];
  const float* ln2_w   = (const float*)d_in[27];
  const float* ln2_b   = (const float*)d_in[28];
  const float* ffn_w1  = (const float*)d_in[29];
  const float* ffn_b1  = (const float*)d_in[30];
  const float* ffn_w2  = (const float*)d_in[31];
  const float* ffn_b2  = (const float*)d_in[32];
  const float* gru_wih = (const float*)d_in[33];
  const float* gru_whh = (const float*)d_in[34];
  const float* gru_bih = (const float*)d_in[35];
  const float* gru_bhh = (const float*)d_in[36];
  const float* pred_w  = (const float*)d_in[37];
  const float* pred_b  = (const float*)d_in[38];

  if (ws_size < WS_FLOATS * sizeof(float)) return;  // loud failure: output stays poisoned

  float* ws   = (float*)d_ws;
  float* H    = ws + H_OFF;
  float* bufA = ws + A_OFF;   // taq pack during layers; seq1 during GRU
  float* q    = ws + Q_OFF;   // q during spatial stage; w1t during FFN stage
  float* k    = ws + K_OFF;   // k during spatial stage; w2q during FFN stage
  float* bufB = ws + B_OFF;   // v | xp

  float* out       = (float*)d_out;
  float* attn_base = out + (size_t)B * HOR * N;  // 39744 (16B aligned)

  float* v   = bufB;
  float* xp  = bufB;
  float* w1t = q;
  float* w2q = k;
  float* taq = bufA;

  k_embed<<<P / 4, 256, 0, stream>>>(x, nodee, hour_w, hour_b, day_w, day_b,
                                     wk_w, wk_b, in_w, in_b, H);

  for (int l = 0; l < 3; l++) {
    float* attn_l = attn_base + (size_t)l * BT * N * N;
    k_spatial_qkv<<<BT, 256, 0, stream>>>(H, sa_qw, sa_qb, sa_kw, sa_kb, sa_vw,
                                          sa_vb, q, k, v, l);
    k_spatial_attn<<<BT, 256, 0, stream>>>(q, k, adj, attn_l);
    k_pack<<<192, 256, 0, stream>>>(ffn_w1, ffn_w2, ta_qw, ta_kw, ta_vw, ta_ow,
                                    w1t, w2q, taq, l);
    k_spatial_apply<<<dim3(BT, 4), 256, 0, stream>>>(v, attn_l, H);
    k_temporal<<<BN, 256, 0, stream>>>(H, taq, ta_qb, ta_kb, ta_vb, ta_ob,
                                       ln1_w, ln1_b, l);
    k_ffn<<<BN, 256, 0, stream>>>(H, ln2_w, ln2_b, w1t, ffn_b1, w2q, ffn_b2, l);
  }

  k_gru_xp<<<P / 16, 256, 0, stream>>>(H, gru_wih, gru_bih, xp, 0);
  k_gru_scan<<<BN / 8, 256, 0, stream>>>(xp, gru_whh, gru_bhh, bufA, 0);
  k_gru_xp<<<P / 16, 256, 0, stream>>>(bufA, gru_wih, gru_bih, xp, 1);
  k_gru_scan<<<BN / 8, 256, 0, stream>>>(xp, gru_whh, gru_bhh, H, 1);

  k_pred<<<BN, 256, 0, stream>>>(H, pred_w, pred_b, out);
}

// Round 7
// 2142.269 us; speedup vs baseline: 3.0304x; 1.0627x over previous
//
#include <hip/hip_runtime.h>
#include <math.h>

namespace {

constexpr int B = 16, T = 24, N = 207, C = 64, HOR = 12;
constexpr int BT = B * T;          // 384
constexpr int BN = B * N;          // 3312
constexpr int P = B * T * N;       // 79488
constexpr int NC = N * C;          // 13248

// ws layout (floats)
constexpr size_t H_OFF = 0;                         // P*C = 5,087,232
constexpr size_t A_OFF = 5087232;                   // bufA: seq1
constexpr size_t Q_OFF = A_OFF + 5087232;           // q: 635,904
constexpr size_t K_OFF = Q_OFF + 635904;            // k: 635,904
constexpr size_t B_OFF = K_OFF + 635904;            // bufB: 20,348,928 (v / xp / packs)
constexpr size_t WS_FLOATS = B_OFF + 20348928;      // 31,795,200

// offsets within bufB
constexpr size_t EP_OFF = 17000000;                 // embed pack: 15,104 floats
constexpr size_t PK_OFF = 18000000;                 // weight packs: 147,456 floats

__device__ __forceinline__ float wsum(float v) {
#pragma unroll
  for (int off = 32; off; off >>= 1) v += __shfl_xor(v, off);
  return v;
}
__device__ __forceinline__ float wmax(float v) {
#pragma unroll
  for (int off = 32; off; off >>= 1) v = fmaxf(v, __shfl_xor(v, off));
  return v;
}

// One-time embed precompute:
// ep[0..13247]        A[n][c] = sum_e inw[c][1+e]*nodee[n][e]
// ep[13248+c]         w0[c]   = inw[c][0]
// ep[13312+c]         hc[c]   = sum_e inw[c][17+e]*hw[e]
// ep[13376+c]         dc[c]   = sum_e inw[c][33+e]*dw[e]
// ep[13440+c]         wc[c]   = sum_e inw[c][49+e]*ww[e]
// ep[13504+c]         bias*   = inb[c] + sum_e inw[c][17+e]*hb[e]+inw[c][33+e]*db[e]+inw[c][49+e]*wb[e]
// ep[13568+t*64+c]    pe[t][c]
__global__ __launch_bounds__(256) void k_embed_pack(
    const float* __restrict__ nodee, const float* __restrict__ hw,
    const float* __restrict__ hb, const float* __restrict__ dw,
    const float* __restrict__ db, const float* __restrict__ ww,
    const float* __restrict__ wb, const float* __restrict__ inw,
    const float* __restrict__ inb, float* __restrict__ ep) {
  int e = blockIdx.x * 256 + threadIdx.x;
  if (e < 13248) {
    int n = e >> 6, c = e & 63;
    const float* w = inw + c * 65 + 1;
    float a = 0.f;
#pragma unroll
    for (int i = 0; i < 16; i++) a += w[i] * nodee[n * 16 + i];
    ep[e] = a;
  } else if (e < 13568) {
    int m = e - 13248;
    int which = m >> 6, c = m & 63;
    const float* w = inw + c * 65;
    float r = 0.f;
    if (which == 0) {
      r = w[0];
    } else if (which == 1) {
#pragma unroll
      for (int i = 0; i < 16; i++) r += w[17 + i] * hw[i];
    } else if (which == 2) {
#pragma unroll
      for (int i = 0; i < 16; i++) r += w[33 + i] * dw[i];
    } else if (which == 3) {
#pragma unroll
      for (int i = 0; i < 16; i++) r += w[49 + i] * ww[i];
    } else {
      r = inb[c];
#pragma unroll
      for (int i = 0; i < 16; i++)
        r += w[17 + i] * hb[i] + w[33 + i] * db[i] + w[49 + i] * wb[i];
    }
    ep[e] = r;
  } else if (e < 15104) {
    int m = e - 13568;
    int t = m >> 6, c = m & 63;
    float dv = expf((float)(c & ~1) * (-9.210340371976184f / 64.0f));
    float ang = (float)t * dv;
    ep[e] = (c & 1) ? cosf(ang) : sinf(ang);
  }
}

// H[b,t,n,c]: 7-term FMA from the pack. One block = 4 positions.
__global__ __launch_bounds__(256) void k_embed(
    const float* __restrict__ x, const float* __restrict__ ep,
    float* __restrict__ H) {
  int pos = blockIdx.x * 4 + (threadIdx.x >> 6);
  int c = threadIdx.x & 63;
  int n = pos % N;
  int t = (pos / N) % T;
  const float* xv = x + (size_t)pos * 4;
  float flow = xv[0], hour = xv[1], wkend = xv[2], day = xv[3];
  float acc = ep[13504 + c] + ep[13248 + c] * flow + ep[13312 + c] * hour +
              ep[13376 + c] * day + ep[13440 + c] * wkend + ep[n * 64 + c] +
              ep[13568 + t * 64 + c];
  H[(size_t)pos * 64 + c] = acc;
}

// All-layer weight repack: per l: w1t[c][j]=w1[j][c]; w2q quad-pack; taq quad-pack x4.
__global__ __launch_bounds__(256) void k_pack_all(
    const float* __restrict__ w1, const float* __restrict__ w2,
    const float* __restrict__ tqw, const float* __restrict__ tkw,
    const float* __restrict__ tvw, const float* __restrict__ tow,
    float* __restrict__ pk) {
  int e = blockIdx.x * 256 + threadIdx.x;  // 0..147455
  int l = e / 49152;
  int m = e % 49152;
  float* w1t = pk + l * 49152;
  float* w2q = w1t + 16384;
  float* taq = w2q + 16384;
  if (m < 16384) {
    int c = m >> 8, j = m & 255;
    w1t[m] = w1[l * 16384 + j * 64 + c];
  } else if (m < 32768) {
    int mm = m - 16384;
    int jq = mm >> 8, c = (mm & 255) >> 2, kk = mm & 3;
    w2q[mm] = w2[l * 16384 + c * 256 + jq * 4 + kk];
  } else {
    int m2 = m - 32768;
    int ph = m2 >> 12;
    int mm = m2 & 4095;
    int cq = mm >> 8, o = (mm & 255) >> 2, j = mm & 3;
    const float* src =
        (ph == 0 ? tqw : ph == 1 ? tkw : ph == 2 ? tvw : tow) + l * 4096;
    taq[ph * 4096 + mm] = src[o * 64 + 4 * cq + j];
  }
}

// one block per g=(b,t). q,k: (B,8,T,N) flat; v: (B,64,T,N) flat.
__global__ __launch_bounds__(256) void k_spatial_qkv(
    const float* __restrict__ H, const float* __restrict__ qw,
    const float* __restrict__ qb, const float* __restrict__ kw,
    const float* __restrict__ kb, const float* __restrict__ vw,
    const float* __restrict__ vb, float* __restrict__ q, float* __restrict__ k,
    float* __restrict__ v, int l) {
  __shared__ float hs[N * 65];  // padded
  int g = blockIdx.x;
  int b = g / T, t = g % T;
  const float* Hbt = H + (size_t)g * NC;
  for (int e = threadIdx.x; e < NC; e += 256) {
    int n = e >> 6, c = e & 63;
    hs[n * 65 + c] = Hbt[e];
  }
  __syncthreads();
  qw += l * 8 * 64; qb += l * 8;
  kw += l * 8 * 64; kb += l * 8;
  vw += l * 64 * 64; vb += l * 64;
  for (int e = threadIdx.x; e < 16 * N; e += 256) {
    int o = e / N, n = e % N;
    int oo = o & 7;
    const float* W = (o < 8 ? qw : kw) + oo * 64;
    float acc = (o < 8 ? qb : kb)[oo];
#pragma unroll
    for (int c = 0; c < 64; c++) acc += W[c] * hs[n * 65 + c];
    size_t oidx = ((size_t)(b * 8 + oo) * T + t) * N + n;
    if (o < 8) q[oidx] = acc; else k[oidx] = acc;
  }
  for (int e = threadIdx.x; e < 64 * N; e += 256) {
    int o = e / N, n = e % N;
    const float* W = vw + o * 64;
    float acc = vb[o];
#pragma unroll
    for (int c = 0; c < 64; c++) acc += W[c] * hs[n * 65 + c];
    v[((size_t)(b * 64 + o) * T + t) * N + n] = acc;
  }
}

// one block per g. Double softmax with adjacency mask; writes attn to d_out slab.
__global__ __launch_bounds__(256) void k_spatial_attn(
    const float* __restrict__ q, const float* __restrict__ k,
    const float* __restrict__ adj, float* __restrict__ attn_out) {
  __shared__ float qs[8 * 208], ks[8 * 208];
  int g = blockIdx.x;
  const float* qg = q + (size_t)g * 1656;
  const float* kg = k + (size_t)g * 1656;
  for (int e = threadIdx.x; e < 1656; e += 256) {
    int c2 = e / N, n = e % N;
    qs[c2 * 208 + n] = qg[e];
    ks[c2 * 208 + n] = kg[e];
  }
  __syncthreads();
  int wave = threadIdx.x >> 6, lane = threadIdx.x & 63;
  for (int n = wave; n < N; n += 4) {
    float s[4];
    float mx = -INFINITY;
#pragma unroll
    for (int j = 0; j < 4; j++) {
      int m = lane + 64 * j;
      float acc = -INFINITY;
      if (m < N) {
        acc = 0.f;
#pragma unroll
        for (int c2 = 0; c2 < 8; c2++) acc += qs[c2 * 208 + n] * ks[c2 * 208 + m];
        acc *= 0.125f;  // 1/sqrt(C)
      }
      s[j] = acc;
      mx = fmaxf(mx, acc);
    }
    mx = wmax(mx);
    float sum = 0.f;
#pragma unroll
    for (int j = 0; j < 4; j++) {
      int m = lane + 64 * j;
      float e = (m < N) ? expf(s[j] - mx) : 0.f;
      s[j] = e;
      sum += e;
    }
    sum = wsum(sum);
    float inv = 1.f / sum;
    // second softmax over masked probabilities
    float mx2 = -INFINITY;
    bool ok[4];
#pragma unroll
    for (int j = 0; j < 4; j++) {
      int m = lane + 64 * j;
      float p = s[j] * inv;
      bool valid = (m < N) && (adj[n * N + m] != 0.0f);
      ok[j] = valid;
      s[j] = p;
      if (valid) mx2 = fmaxf(mx2, p);
    }
    mx2 = wmax(mx2);
    float sum2 = 0.f;
#pragma unroll
    for (int j = 0; j < 4; j++) {
      float e = ok[j] ? expf(s[j] - mx2) : 0.f;
      s[j] = e;
      sum2 += e;
    }
    sum2 = wsum(sum2);
    float inv2 = 1.f / sum2;
    float* orow = attn_out + ((size_t)g * N + n) * N;
#pragma unroll
    for (int j = 0; j < 4; j++) {
      int m = lane + 64 * j;
      if (m < N) orow[m] = s[j] * inv2;
    }
  }
}

// sp = v2 @ attn^T, residual into H. grid (g, m-chunk). 13-row register
// blocking per wave; rows stride-4 so all 13 share the same float4 phase.
__global__ __launch_bounds__(256, 3) void k_spatial_apply(
    const float* __restrict__ v, const float* __restrict__ attn,
    float* __restrict__ H) {
  __shared__ float vs[64 * 207];
  int g = blockIdx.x;
  int ms = blockIdx.y;  // 0..3
  const float* vg = v + (size_t)g * NC;
  for (int e = threadIdx.x; e < NC; e += 256) vs[e] = vg[e];  // vs[c*207+n]
  __syncthreads();
  int wave = threadIdx.x >> 6, lane = threadIdx.x & 63;
  const float* ag = attn + (size_t)g * (N * N);
  float* Hg = H + (size_t)g * NC;
  int mbeg = ms * 52;
  int mend = min(mbeg + 52, N);
  int m_w = mbeg + wave;  // first row of this wave; rows m_w+4k, k=0..12
  size_t Dg = (size_t)g * (N * N);
  int p = (int)((4 - ((Dg + (size_t)m_w * N) & 3)) & 3);
  const float* ar[13];
  int mrow[13];
#pragma unroll
  for (int r = 0; r < 13; r++) {
    int m = m_w + 4 * r;
    mrow[r] = m;
    int msafe = (m < N) ? m : m - 4;  // phase-preserving clamp
    ar[r] = ag + (size_t)msafe * N;
  }
  float acc[13];
#pragma unroll
  for (int r = 0; r < 13; r++) acc[r] = 0.f;
  const float* vrow = vs + lane * 207;
  for (int n = 0; n < p; n++) {
    float vv = vrow[n];
#pragma unroll
    for (int r = 0; r < 13; r++) acc[r] += vv * ar[r][n];
  }
  for (int n4 = 0; n4 < 51; n4++) {
    int n = p + n4 * 4;
    float v0 = vrow[n], v1 = vrow[n + 1], v2 = vrow[n + 2], v3 = vrow[n + 3];
#pragma unroll
    for (int r = 0; r < 13; r++) {
      float4 a = *(const float4*)(ar[r] + n);
      acc[r] += v0 * a.x;
      acc[r] += v1 * a.y;
      acc[r] += v2 * a.z;
      acc[r] += v3 * a.w;
    }
  }
  for (int n = p + 204; n < 207; n++) {
    float vv = vrow[n];
#pragma unroll
    for (int r = 0; r < 13; r++) acc[r] += vv * ar[r][n];
  }
#pragma unroll
  for (int r = 0; r < 13; r++) {
    int m = mrow[r];
    if (m < mend) Hg[(size_t)m * 64 + lane] += acc[r];
  }
}

// temporal MHA fused per (b,n), LN1 fused at load; residual into H.
// Weights pre-quad-packed in taq (global, L1/L2-hot): taq4[ph*1024+cq*64+o].
__global__ __launch_bounds__(256) void k_temporal(
    float* __restrict__ H, const float* __restrict__ taq,
    const float* __restrict__ qb, const float* __restrict__ kb,
    const float* __restrict__ vb, const float* __restrict__ ob,
    const float* __restrict__ lnw, const float* __restrict__ lnb, int l) {
  __shared__ float xs[24 * 68], qs[24 * 68], ks[24 * 68], vs[24 * 68];
  __shared__ float ss[96 * 25];
  int bn = blockIdx.x;
  int b = bn / N, n = bn % N;
  size_t base = ((size_t)b * T * N + n) * 64;
  int lane = threadIdx.x & 63, tg = threadIdx.x >> 6;
  // load + LN1 (h = LN1(h + sp)): xs holds hl
  float lw = lnw[l * 64 + lane], lb = lnb[l * 64 + lane];
  for (int t = tg; t < 24; t += 4) {
    float xv = H[base + (size_t)t * NC + lane];
    float mean = wsum(xv) * (1.f / 64.f);
    float d = xv - mean;
    float var = wsum(d * d) * (1.f / 64.f);
    xs[t * 68 + lane] = d / sqrtf(var + 1e-5f) * lw + lb;
  }
  __syncthreads();
  const float4* wq_all = (const float4*)taq;
  const float* Bm[3] = {qb + l * 64, kb + l * 64, vb + l * 64};
  float* Dm[3] = {qs, ks, vs};
#pragma unroll
  for (int ph = 0; ph < 3; ph++) {
    const float4* wq = wq_all + ph * 1024;
    float acc[6];
    float bv = Bm[ph][lane];
#pragma unroll
    for (int i = 0; i < 6; i++) acc[i] = bv;
#pragma unroll 4
    for (int cq = 0; cq < 16; cq++) {
      float4 w = wq[cq * 64 + lane];
#pragma unroll
      for (int i = 0; i < 6; i++) {
        float4 xv = *(const float4*)(&xs[(tg * 6 + i) * 68 + cq * 4]);
        acc[i] += xv.x * w.x + xv.y * w.y + xv.z * w.z + xv.w * w.w;
      }
    }
    float* dst = Dm[ph];
#pragma unroll
    for (int i = 0; i < 6; i++) dst[(tg * 6 + i) * 68 + lane] = acc[i];
  }
  __syncthreads();
  // scores: 4 heads x 24 x 24 (float4 fragments)
  for (int e = threadIdx.x; e < 2304; e += 256) {
    int u = e % 24, t = (e / 24) % 24, h = e / 576;
    float a = 0.f;
#pragma unroll
    for (int dq = 0; dq < 4; dq++) {
      float4 qv = *(const float4*)(&qs[t * 68 + h * 16 + dq * 4]);
      float4 kv = *(const float4*)(&ks[u * 68 + h * 16 + dq * 4]);
      a += qv.x * kv.x + qv.y * kv.y + qv.z * kv.z + qv.w * kv.w;
    }
    ss[(h * 24 + t) * 25 + u] = a * 0.25f;  // 1/sqrt(HD)
  }
  __syncthreads();
  if (threadIdx.x < 96) {
    float* row = ss + threadIdx.x * 25;
    float mx = -INFINITY;
#pragma unroll
    for (int u = 0; u < 24; u++) mx = fmaxf(mx, row[u]);
    float sum = 0.f;
#pragma unroll
    for (int u = 0; u < 24; u++) {
      float e2 = expf(row[u] - mx);
      row[u] = e2;
      sum += e2;
    }
    float inv = 1.f / sum;
#pragma unroll
    for (int u = 0; u < 24; u++) row[u] *= inv;
  }
  __syncthreads();
  // apply: att -> qs (qs dead after scores)
  {
    int h = lane >> 4;
    float acc2[6];
#pragma unroll
    for (int i = 0; i < 6; i++) acc2[i] = 0.f;
    for (int u = 0; u < 24; u++) {
      float vsv = vs[u * 68 + lane];
#pragma unroll
      for (int i = 0; i < 6; i++)
        acc2[i] += ss[(h * 24 + (tg * 6 + i)) * 25 + u] * vsv;
    }
#pragma unroll
    for (int i = 0; i < 6; i++) qs[(tg * 6 + i) * 68 + lane] = acc2[i];
  }
  __syncthreads();
  // output projection + residual
  {
    const float4* wo = wq_all + 3 * 1024;
    float acc[6];
    float bv = ob[l * 64 + lane];
#pragma unroll
    for (int i = 0; i < 6; i++) acc[i] = bv;
#pragma unroll 4
    for (int cq = 0; cq < 16; cq++) {
      float4 w = wo[cq * 64 + lane];
#pragma unroll
      for (int i = 0; i < 6; i++) {
        float4 xv = *(const float4*)(&qs[(tg * 6 + i) * 68 + cq * 4]);
        acc[i] += xv.x * w.x + xv.y * w.y + xv.z * w.z + xv.w * w.w;
      }
    }
#pragma unroll
    for (int i = 0; i < 6; i++)
      H[base + (size_t)(tg * 6 + i) * NC + lane] =
          xs[(tg * 6 + i) * 68 + lane] + acc[i];
  }
}

// Fused LN2 + FFN1(relu) + FFN2 + residual; hid lives in LDS.
// w1t: [c][j] coalesced float4 streams; w2q: quad-packed [jq][c] float4.
__global__ __launch_bounds__(256) void k_ffn(
    float* __restrict__ H, const float* __restrict__ lnw,
    const float* __restrict__ lnb, const float* __restrict__ w1t,
    const float* __restrict__ b1, const float* __restrict__ w2q,
    const float* __restrict__ b2, int l) {
  __shared__ float xs[24 * 66];
  __shared__ float hids[24 * 260];  // row stride 260 (1040B, 16B-aligned)
  int bn = blockIdx.x;
  int b = bn / N, n = bn % N;
  size_t base = ((size_t)b * T * N + n) * 64;
  int lane = threadIdx.x & 63, tg = threadIdx.x >> 6;
  for (int t = tg; t < 24; t += 4) {
    float xv = H[base + (size_t)t * NC + lane];
    float mean = wsum(xv) * (1.f / 64.f);
    float d = xv - mean;
    float var = wsum(d * d) * (1.f / 64.f);
    xs[t * 66 + lane] = d / sqrtf(var + 1e-5f) * lnw[l * 64 + lane] + lnb[l * 64 + lane];
  }
  __syncthreads();
  // GEMM1: thread covers j-quad j0=lane*4 for 6 t's
  int j0 = lane * 4;
  float4 b4 = *(const float4*)(b1 + l * 256 + j0);
  float a0[6], a1[6], a2[6], a3[6];
#pragma unroll
  for (int i = 0; i < 6; i++) { a0[i] = b4.x; a1[i] = b4.y; a2[i] = b4.z; a3[i] = b4.w; }
  for (int c = 0; c < 64; c++) {
    float4 w4 = *(const float4*)(w1t + c * 256 + j0);
#pragma unroll
    for (int i = 0; i < 6; i++) {
      float xv = xs[(tg * 6 + i) * 66 + c];
      a0[i] += xv * w4.x;
      a1[i] += xv * w4.y;
      a2[i] += xv * w4.z;
      a3[i] += xv * w4.w;
    }
  }
#pragma unroll
  for (int i = 0; i < 6; i++) {
    int t = tg * 6 + i;
    float4 r = make_float4(fmaxf(a0[i], 0.f), fmaxf(a1[i], 0.f),
                           fmaxf(a2[i], 0.f), fmaxf(a3[i], 0.f));
    *(float4*)(&hids[t * 260 + j0]) = r;
  }
  __syncthreads();
  // GEMM2: thread covers c=lane for 6 t's; w2q4 coalesced, hids broadcast
  const float4* w2q4 = (const float4*)w2q;
  float acc[6];
#pragma unroll
  for (int i = 0; i < 6; i++) acc[i] = 0.f;
  for (int jq = 0; jq < 64; jq++) {
    float4 w = w2q4[jq * 64 + lane];
#pragma unroll
    for (int i = 0; i < 6; i++) {
      float4 hv = *(const float4*)(&hids[(tg * 6 + i) * 260 + jq * 4]);
      acc[i] += hv.x * w.x + hv.y * w.y + hv.z * w.z + hv.w * w.w;
    }
  }
  float bias = b2[l * 64 + lane];
#pragma unroll
  for (int i = 0; i < 6; i++) {
    int t = tg * 6 + i;
    H[base + (size_t)t * NC + lane] = xs[t * 66 + lane] + bias + acc[i];
  }
}

// GRU input projection: xp[t,bn,g] = bih + X . wih. 16 pairs per block.
__global__ __launch_bounds__(256) void k_gru_xp(
    const float* __restrict__ X, const float* __restrict__ wih,
    const float* __restrict__ bih, float* __restrict__ xp, int l) {
  __shared__ float ws_[192 * 65];
  __shared__ float xv[16 * 64];
  int p0 = blockIdx.x * 16;
  for (int e = threadIdx.x; e < 192 * 64; e += 256) {
    int gI = e >> 6, c = e & 63;
    ws_[gI * 65 + c] = wih[l * 12288 + e];
  }
  for (int e = threadIdx.x; e < 16 * 64; e += 256) {
    int s = e >> 6, c = e & 63;
    int p = p0 + s;
    int t = p / BN, bn = p % BN;
    float val;
    if (l == 0) {
      int b = bn / N, n = bn % N;
      val = X[(((size_t)b * T + t) * N + n) * 64 + c];
    } else {
      val = X[(size_t)p * 64 + c];  // seq1[t,bn,c]
    }
    xv[e] = val;
  }
  __syncthreads();
  for (int e = threadIdx.x; e < 16 * 192; e += 256) {
    int s = e / 192, gI = e % 192;
    float acc = bih[l * 192 + gI];
#pragma unroll
    for (int c = 0; c < 64; c++) acc += xv[s * 64 + c] * ws_[gI * 65 + c];
    xp[((size_t)(p0 + s)) * 192 + gI] = acc;
  }
}

// GRU recurrence: 8 samples/block; waves 0-2 hold gate weights in registers.
__global__ __launch_bounds__(256) void k_gru_scan(
    const float* __restrict__ xp, const float* __restrict__ whh,
    const float* __restrict__ bhh, float* __restrict__ seq_out, int l) {
  constexpr int S = 8;
  __shared__ float hprev[S][64];
  __shared__ float hg[3][S][64];
  __shared__ float xpbuf[2][S * 192];
  int bn0 = blockIdx.x * S;
  int lane = threadIdx.x & 63;
  int wv = threadIdx.x >> 6;

  float4 w4[16];
  if (wv < 3) {
    const float* wr = whh + l * 12288 + (wv * 64 + lane) * 64;
#pragma unroll
    for (int j = 0; j < 16; j++) w4[j] = *(const float4*)(wr + j * 4);
  }
  float b_r = bhh[l * 192 + lane];
  float b_z = bhh[l * 192 + 64 + lane];
  float b_n = bhh[l * 192 + 128 + lane];

  for (int e = threadIdx.x; e < S * 64; e += 256) ((float*)hprev)[e] = 0.f;
  {
    const float* src = xp + (size_t)bn0 * 192;
    for (int e = threadIdx.x; e < S * 192; e += 256) xpbuf[0][e] = src[e];
  }
  __syncthreads();

  for (int t = 0; t < T; t++) {
    int cur = t & 1;
    if (wv < 3) {
      float acc[S];
#pragma unroll
      for (int s = 0; s < S; s++) acc[s] = 0.f;
#pragma unroll
      for (int j = 0; j < 16; j++) {
        float4 w = w4[j];
#pragma unroll
        for (int s = 0; s < S; s++) {
          float4 hb = *(const float4*)(&hprev[s][j * 4]);
          acc[s] += w.x * hb.x + w.y * hb.y + w.z * hb.z + w.w * hb.w;
        }
      }
#pragma unroll
      for (int s = 0; s < S; s++) hg[wv][s][lane] = acc[s];
    } else {
      if (t + 1 < T) {
        const float* src = xp + ((size_t)(t + 1) * BN + bn0) * 192;
        float* dst = xpbuf[(t + 1) & 1];
        for (int e = lane * 4; e < S * 192; e += 256) {
          *(float4*)(dst + e) = *(const float4*)(src + e);
        }
      }
    }
    __syncthreads();
#pragma unroll
    for (int ii = 0; ii < 2; ii++) {
      int s = wv + 4 * ii;
      const float* xr = &xpbuf[cur][s * 192];
      float r = 1.f / (1.f + expf(-(xr[lane] + hg[0][s][lane] + b_r)));
      float z = 1.f / (1.f + expf(-(xr[64 + lane] + hg[1][s][lane] + b_z)));
      float nn = tanhf(xr[128 + lane] + r * (hg[2][s][lane] + b_n));
      float hp = hprev[s][lane];
      float hnew = (1.f - z) * nn + z * hp;
      hprev[s][lane] = hnew;
      seq_out[((size_t)t * BN + bn0 + s) * 64 + lane] = hnew;
    }
    __syncthreads();
  }
}

// prediction head: one block per bn.
__global__ __launch_bounds__(256) void k_pred(
    const float* __restrict__ seq2, const float* __restrict__ pw,
    const float* __restrict__ pb, float* __restrict__ out) {
  __shared__ float s_[1536];
  int bn = blockIdx.x;
  int b = bn / N, n = bn % N;
  for (int e = threadIdx.x; e < 1536; e += 256) {
    int t = e >> 6, c = e & 63;
    s_[c * 24 + t] = seq2[((size_t)t * BN + bn) * 64 + c];
  }
  __syncthreads();
  int wave = threadIdx.x >> 6, lane = threadIdx.x & 63;
  for (int hor = wave; hor < 12; hor += 4) {
    const float* w = pw + hor * 1536;
    float acc = 0.f;
#pragma unroll 4
    for (int kk = lane; kk < 1536; kk += 64) acc += s_[kk] * w[kk];
    acc = wsum(acc);
    if (lane == 0) out[(size_t)b * (HOR * N) + hor * N + n] = acc + pb[hor];
  }
}

}  // namespace

extern "C" void kernel_launch(void* const* d_in, const int* in_sizes, int n_in,
                              void* d_out, int out_size, void* d_ws, size_t ws_size,
                              hipStream_t stream) {
  const float* x       = (const float*)d_in[0];
  const float* adj     = (const float*)d_in[1];
  const float* nodee   = (const float*)d_in[2];
  const float* hour_w  = (const float*)d_in[3];
  const float* hour_b  = (const float*)d_in[4];
  const float* day_w   = (const float*)d_in[5];
  const float* day_b   = (const float*)d_in[6];
  const float* wk_w    = (const float*)d_in[7];
  const float* wk_b    = (const float*)d_in[8];
  const float* in_w    = (const float*)d_in[9];
  const float* in_b    = (const float*)d_in[10];
  const float* sa_qw   = (const float*)d_in[11];
  const float* sa_qb   = (const float*)d_in[12];
  const float* sa_kw   = (const float*)d_in[13];
  const float* sa_kb   = (const float*)d_in[14];
  const float* sa_vw   = (const float*)d_in[15];
  const float* sa_vb   = (const float*)d_in[16];
  const float* ta_qw   = (const float*)d_in[17];
  const float* ta_qb   = (const float*)d_in[18];
  const float* ta_kw   = (const float*)d_in[19];
  const float* ta_kb   = (const float*)d_in[20];
  const float* ta_vw   = (const float*)d_in[21];
  const float* ta_vb   = (const float*)d_in[22];
  const float* ta_ow   = (const float*)d_in[23];
  const float* ta_ob   = (const float*)d_in[24];
  const float* ln1_w   = (const float*)d_in[25];
  const float* ln1_b   = (const float*)d_in[26];
  const float* ln2_w   = (const float*)d_in[27];
  const float* ln2_b   = (const float*)d_in[28];
  const float* ffn_w1  = (const float*)d_in[29];
  const float* ffn_b1  = (const float*)d_in[30];
  const float* ffn_w2  = (const float*)d_in[31];
  const float* ffn_b2  = (const float*)d_in[32];
  const float* gru_wih = (const float*)d_in[33];
  const float* gru_whh = (const float*)d_in[34];
  const float* gru_bih = (const float*)d_in[35];
  const float* gru_bhh = (const float*)d_in[36];
  const float* pred_w  = (const float*)d_in[37];
  const float* pred_b  = (const float*)d_in[38];

  if (ws_size < WS_FLOATS * sizeof(float)) return;  // loud failure: output stays poisoned

  float* ws   = (float*)d_ws;
  float* H    = ws + H_OFF;
  float* bufA = ws + A_OFF;   // seq1 during GRU
  float* q    = ws + Q_OFF;
  float* k    = ws + K_OFF;
  float* bufB = ws + B_OFF;   // v | xp | ep | packs

  float* out       = (float*)d_out;
  float* attn_base = out + (size_t)B * HOR * N;  // 39744 (16B aligned)

  float* v   = bufB;
  float* xp  = bufB;
  float* ep  = bufB + EP_OFF;
  float* pk  = bufB + PK_OFF;

  k_embed_pack<<<60, 256, 0, stream>>>(nodee, hour_w, hour_b, day_w, day_b,
                                       wk_w, wk_b, in_w, in_b, ep);
  k_embed<<<P / 4, 256, 0, stream>>>(x, ep, H);
  k_pack_all<<<576, 256, 0, stream>>>(ffn_w1, ffn_w2, ta_qw, ta_kw, ta_vw,
                                      ta_ow, pk);

  for (int l = 0; l < 3; l++) {
    float* attn_l = attn_base + (size_t)l * BT * N * N;
    float* w1t = pk + (size_t)l * 49152;
    float* w2q = w1t + 16384;
    float* taq = w2q + 16384;
    k_spatial_qkv<<<BT, 256, 0, stream>>>(H, sa_qw, sa_qb, sa_kw, sa_kb, sa_vw,
                                          sa_vb, q, k, v, l);
    k_spatial_attn<<<BT, 256, 0, stream>>>(q, k, adj, attn_l);
    k_spatial_apply<<<dim3(BT, 4), 256, 0, stream>>>(v, attn_l, H);
    k_temporal<<<BN, 256, 0, stream>>>(H, taq, ta_qb, ta_kb, ta_vb, ta_ob,
                                       ln1_w, ln1_b, l);
    k_ffn<<<BN, 256, 0, stream>>>(H, ln2_w, ln2_b, w1t, ffn_b1, w2q, ffn_b2, l);
  }

  k_gru_xp<<<P / 16, 256, 0, stream>>>(H, gru_wih, gru_bih, xp, 0);
  k_gru_scan<<<BN / 8, 256, 0, stream>>>(xp, gru_whh, gru_bhh, bufA, 0);
  k_gru_xp<<<P / 16, 256, 0, stream>>>(bufA, gru_wih, gru_bih, xp, 1);
  k_gru_scan<<<BN / 8, 256, 0, stream>>>(xp, gru_whh, gru_bhh, H, 1);

  k_pred<<<BN, 256, 0, stream>>>(H, pred_w, pred_b, out);
}